// Round 1
// baseline (1408.898 us; speedup 1.0000x reference)
//
#include <hip/hip_runtime.h>
#include <hip/hip_bf16.h>
#include <cstdint>
#include <cstddef>

#define I_      100
#define J_      8
#define D_IN    768
#define D_H     64
#define N_NODES 160000
#define N_HE    320000
#define N_INC   1600000
#define N_CELLS 800
#define VOCAB   30000

typedef unsigned short u16;

__device__ __forceinline__ float bf2f(u16 u) {
    union { uint32_t i; float f; } x; x.i = ((uint32_t)u) << 16; return x.f;
}
__device__ __forceinline__ u16 f2bf(float f) {
    union { float f; uint32_t i; } x; x.f = f;
    uint32_t b = x.i;
    b += 0x7FFFu + ((b >> 16) & 1u);   // round-to-nearest-even
    return (u16)(b >> 16);
}

// ---------------------------------------------------------------------------
// CSR / offsets machinery
// ---------------------------------------------------------------------------

// offsets from a sorted index array: off[b] = first i with sorted[i] >= b; off[nbins] = n
__global__ __launch_bounds__(256) void k_offsets(const int* __restrict__ sorted, int n,
                                                 int nbins, int* __restrict__ off) {
    int i = blockIdx.x * 256 + threadIdx.x;
    if (i >= n) return;
    int cur = sorted[i];
    int prev = (i == 0) ? -1 : sorted[i - 1];
    for (int b = prev + 1; b <= cur; ++b) off[b] = i;
    if (i == n - 1) {
        for (int b = cur + 1; b <= nbins; ++b) off[b] = n;
    }
}

__global__ __launch_bounds__(256) void k_hist(const int* __restrict__ idx, int n,
                                              int* __restrict__ deg) {
    int i = blockIdx.x * 256 + threadIdx.x;
    if (i < n) atomicAdd(&deg[idx[i]], 1);
}

// per-block exclusive scan (256/block); block totals to bsum
__global__ __launch_bounds__(256) void k_scan1(const int* __restrict__ deg, int n,
                                               int* __restrict__ off, int* __restrict__ bsum) {
    __shared__ int s[256];
    int tid = threadIdx.x;
    int i = blockIdx.x * 256 + tid;
    int v = (i < n) ? deg[i] : 0;
    s[tid] = v;
    __syncthreads();
    #pragma unroll
    for (int d = 1; d < 256; d <<= 1) {
        int t = (tid >= d) ? s[tid - d] : 0;
        __syncthreads();
        s[tid] += t;
        __syncthreads();
    }
    if (i < n) off[i] = s[tid] - v;           // exclusive
    if (tid == 255) bsum[blockIdx.x] = s[255];
}

// single-block exclusive scan of bsum (nb <= 1024)
__global__ __launch_bounds__(1024) void k_scan2(int* __restrict__ bsum, int nb) {
    __shared__ int s[1024];
    int tid = threadIdx.x;
    int v = (tid < nb) ? bsum[tid] : 0;
    s[tid] = v;
    __syncthreads();
    #pragma unroll
    for (int d = 1; d < 1024; d <<= 1) {
        int t = (tid >= d) ? s[tid - d] : 0;
        __syncthreads();
        s[tid] += t;
        __syncthreads();
    }
    if (tid < nb) bsum[tid] = s[tid] - v;     // exclusive
}

__global__ __launch_bounds__(256) void k_scan3(int* __restrict__ off, const int* __restrict__ bsum,
                                               int n, int total) {
    int i = blockIdx.x * 256 + threadIdx.x;
    if (i < n) off[i] += bsum[blockIdx.x];
    if (i == 0) off[n] = total;
}

__global__ __launch_bounds__(256) void k_csr_fill(const int* __restrict__ inc_node,
                                                  const int* __restrict__ inc_hedge, int n,
                                                  const int* __restrict__ node_off,
                                                  int* __restrict__ cursor,
                                                  int* __restrict__ csr) {
    int i = blockIdx.x * 256 + threadIdx.x;
    if (i >= n) return;
    int v = inc_node[i];
    int p = node_off[v] + atomicAdd(&cursor[v], 1);
    csr[p] = inc_hedge[i];
}

// ---------------------------------------------------------------------------
// GEMM: C[M,64] = A[M,K] @ B[K,64] (+bias). 64x64 tile/block, 4x4 per thread.
// ---------------------------------------------------------------------------
template <int BF16_OUT>
__global__ __launch_bounds__(256) void k_gemm64(const float* __restrict__ A,
                                                const float* __restrict__ B,
                                                const float* __restrict__ bias,
                                                void* __restrict__ C, int M, int K) {
    __shared__ float As[32][68];   // [k][m]
    __shared__ float Bs[32][68];   // [k][n]
    int tid = threadIdx.x;
    int tx = tid & 15, ty = tid >> 4;
    int row0 = blockIdx.x << 6;
    float acc[4][4] = {{0.f}};

    for (int k0 = 0; k0 < K; k0 += 32) {
        #pragma unroll
        for (int l = tid; l < 64 * 32; l += 256) {
            int m = l >> 5, k = l & 31;
            int gr = row0 + m;
            As[k][m] = (gr < M) ? A[(size_t)gr * K + (k0 + k)] : 0.f;
        }
        #pragma unroll
        for (int l = tid; l < 32 * 64; l += 256) {
            int k = l >> 6, n = l & 63;
            Bs[k][n] = B[(size_t)(k0 + k) * 64 + n];
        }
        __syncthreads();
        #pragma unroll
        for (int kk = 0; kk < 32; ++kk) {
            float4 a = *reinterpret_cast<const float4*>(&As[kk][ty << 2]);
            float4 b = *reinterpret_cast<const float4*>(&Bs[kk][tx << 2]);
            acc[0][0] = fmaf(a.x, b.x, acc[0][0]);
            acc[0][1] = fmaf(a.x, b.y, acc[0][1]);
            acc[0][2] = fmaf(a.x, b.z, acc[0][2]);
            acc[0][3] = fmaf(a.x, b.w, acc[0][3]);
            acc[1][0] = fmaf(a.y, b.x, acc[1][0]);
            acc[1][1] = fmaf(a.y, b.y, acc[1][1]);
            acc[1][2] = fmaf(a.y, b.z, acc[1][2]);
            acc[1][3] = fmaf(a.y, b.w, acc[1][3]);
            acc[2][0] = fmaf(a.z, b.x, acc[2][0]);
            acc[2][1] = fmaf(a.z, b.y, acc[2][1]);
            acc[2][2] = fmaf(a.z, b.z, acc[2][2]);
            acc[2][3] = fmaf(a.z, b.w, acc[2][3]);
            acc[3][0] = fmaf(a.w, b.x, acc[3][0]);
            acc[3][1] = fmaf(a.w, b.y, acc[3][1]);
            acc[3][2] = fmaf(a.w, b.z, acc[3][2]);
            acc[3][3] = fmaf(a.w, b.w, acc[3][3]);
        }
        __syncthreads();
    }

    float bv[4] = {0.f, 0.f, 0.f, 0.f};
    if (bias) {
        bv[0] = bias[(tx << 2) + 0];
        bv[1] = bias[(tx << 2) + 1];
        bv[2] = bias[(tx << 2) + 2];
        bv[3] = bias[(tx << 2) + 3];
    }
    #pragma unroll
    for (int r = 0; r < 4; ++r) {
        int gr = row0 + (ty << 2) + r;
        if (gr >= M) continue;
        float v0 = acc[r][0] + bv[0];
        float v1 = acc[r][1] + bv[1];
        float v2 = acc[r][2] + bv[2];
        float v3 = acc[r][3] + bv[3];
        if (BF16_OUT) {
            ushort4 u;
            u.x = f2bf(v0); u.y = f2bf(v1); u.z = f2bf(v2); u.w = f2bf(v3);
            *reinterpret_cast<ushort4*>((u16*)C + (size_t)gr * 64 + (tx << 2)) = u;
        } else {
            *reinterpret_cast<float4*>((float*)C + (size_t)gr * 64 + (tx << 2)) =
                make_float4(v0, v1, v2, v3);
        }
    }
}

// ---------------------------------------------------------------------------
// nf[n] = P[tok[n]]   (P already includes fhi_b)
// ---------------------------------------------------------------------------
__global__ __launch_bounds__(256) void k_gather_nf(const float4* __restrict__ P,
                                                   const int* __restrict__ tok,
                                                   float4* __restrict__ nf) {
    int g = blockIdx.x * 256 + threadIdx.x;
    if (g >= N_NODES * 16) return;
    int n = g >> 4, p = g & 15;
    nf[g] = P[((size_t)tok[n] << 4) + p];
}

// ---------------------------------------------------------------------------
// he[e] = (1/deg_e) * sum_{j in hedge-range} xt[inc_node[j]]    (bf16 in/out, f32 acc)
// one wave per hedge, lane = column
// ---------------------------------------------------------------------------
__global__ __launch_bounds__(256) void k_hedge_sum(const int* __restrict__ inc_node,
                                                   const int* __restrict__ he_off,
                                                   const u16* __restrict__ xt,
                                                   u16* __restrict__ he) {
    int w = (blockIdx.x * 256 + threadIdx.x) >> 6;
    int lane = threadIdx.x & 63;
    if (w >= N_HE) return;
    int s = he_off[w], e = he_off[w + 1];
    float acc = 0.f;
    for (int j = s; j < e; ++j) {
        int v = inc_node[j];
        acc += bf2f(xt[((size_t)v << 6) + lane]);
    }
    float inv = (e > s) ? 1.f / (float)(e - s) : 0.f;
    he[((size_t)w << 6) + lane] = f2bf(acc * inv);
}

// ---------------------------------------------------------------------------
// out[v] = relu((1/deg_v) * sum he[csr[j]] + bias) + nf[v]
// one wave per node, lane = column
// ---------------------------------------------------------------------------
__global__ __launch_bounds__(256) void k_node_sum(const int* __restrict__ csr,
                                                  const int* __restrict__ node_off,
                                                  const u16* __restrict__ he,
                                                  const float* __restrict__ bias,
                                                  const float* __restrict__ nf,
                                                  float* __restrict__ out) {
    int w = (blockIdx.x * 256 + threadIdx.x) >> 6;
    int lane = threadIdx.x & 63;
    if (w >= N_NODES) return;
    int s = node_off[w], e = node_off[w + 1];
    float acc = 0.f;
    for (int j = s; j < e; ++j) {
        int h = csr[j];
        acc += bf2f(he[((size_t)h << 6) + lane]);
    }
    float inv = (e > s) ? 1.f / (float)(e - s) : 0.f;
    float val = fmaxf(fmaf(acc, inv, bias[lane]), 0.f) + nf[((size_t)w << 6) + lane];
    out[((size_t)w << 6) + lane] = val;
}

// ---------------------------------------------------------------------------
// per-cell mean+max pooling, fused x_upd = x0 + 0.3*cell_emb  -> d_out part 1
// one block (4 waves) per cell; lane = column, wave strides nodes
// ---------------------------------------------------------------------------
__global__ __launch_bounds__(256) void k_pool(const float* __restrict__ gx,
                                              const int* __restrict__ cell_off,
                                              const float* __restrict__ x0,
                                              float* __restrict__ out1) {
    __shared__ float ssum[4][64];
    __shared__ float smax[4][64];
    int c = blockIdx.x;
    int lane = threadIdx.x & 63;
    int w = threadIdx.x >> 6;
    int s = cell_off[c], e = cell_off[c + 1];
    float sum = 0.f, mx = -INFINITY;
    for (int n = s + w; n < e; n += 4) {
        float v = gx[((size_t)n << 6) + lane];
        sum += v;
        mx = fmaxf(mx, v);
    }
    ssum[w][lane] = sum;
    smax[w][lane] = mx;
    __syncthreads();
    if (w == 0) {
        sum = ssum[0][lane] + ssum[1][lane] + ssum[2][lane] + ssum[3][lane];
        mx = fmaxf(fmaxf(smax[0][lane], smax[1][lane]), fmaxf(smax[2][lane], smax[3][lane]));
        int cnt = e - s;
        float mean = (cnt > 0) ? sum / (float)cnt : 0.f;
        float mp = (cnt > 0) ? mx : 0.f;
        float ce = 0.5f * (mean + mp);
        out1[((size_t)c << 6) + lane] = x0[((size_t)c << 6) + lane] + 0.3f * ce;
    }
}

// ---------------------------------------------------------------------------
// fused TCN: transpose -> 3x(conv1d k3 p1 + relu + bn) -> mean_t -> fc
// one block per sample n (100 blocks)
// ---------------------------------------------------------------------------
__global__ __launch_bounds__(256) void k_tcn(
    const float* __restrict__ xu,
    const float* __restrict__ wc1, const float* __restrict__ bc1, const float* __restrict__ g1,
    const float* __restrict__ be1, const float* __restrict__ m1, const float* __restrict__ v1,
    const float* __restrict__ wc2, const float* __restrict__ bc2, const float* __restrict__ g2,
    const float* __restrict__ be2, const float* __restrict__ m2, const float* __restrict__ v2,
    const float* __restrict__ wc3, const float* __restrict__ bc3, const float* __restrict__ g3,
    const float* __restrict__ be3, const float* __restrict__ m3, const float* __restrict__ v3,
    const float* __restrict__ fct_w, const float* __restrict__ fct_b,
    float* __restrict__ out2) {
    __shared__ float w_lds[64 * 64 * 3];
    __shared__ float hA[64][10];   // [channel][time+1], col 0 and 9 are zero pads
    __shared__ float hB[64][10];
    __shared__ float mo[64];

    int n = blockIdx.x, tid = threadIdx.x;

    if (tid < 64) {
        hA[tid][0] = 0.f; hA[tid][9] = 0.f;
        hB[tid][0] = 0.f; hB[tid][9] = 0.f;
    }
    #pragma unroll
    for (int l = tid; l < 512; l += 256) {
        int t = l >> 6, i = l & 63;
        hA[i][t + 1] = xu[(size_t)n * 512 + l];
    }

    const float* wcs[3] = {wc1, wc2, wc3};
    const float* bcs[3] = {bc1, bc2, bc3};
    const float* gs[3]  = {g1, g2, g3};
    const float* bes[3] = {be1, be2, be3};
    const float* ms[3]  = {m1, m2, m3};
    const float* vs[3]  = {v1, v2, v3};

    float (*hin)[10] = hA;
    float (*hout)[10] = hB;

    #pragma unroll
    for (int li = 0; li < 3; ++li) {
        for (int l = tid; l < 64 * 64 * 3; l += 256) w_lds[l] = wcs[li][l];
        __syncthreads();
        #pragma unroll
        for (int rep = 0; rep < 2; ++rep) {
            int idx = tid + rep * 256;
            int o = idx >> 3, t = idx & 7;
            float acc = bcs[li][o];
            #pragma unroll 8
            for (int i = 0; i < 64; ++i) {
                const float* wr = &w_lds[o * 192 + i * 3];
                acc = fmaf(hin[i][t + 0], wr[0], acc);
                acc = fmaf(hin[i][t + 1], wr[1], acc);
                acc = fmaf(hin[i][t + 2], wr[2], acc);
            }
            acc = fmaxf(acc, 0.f);
            float sc = gs[li][o] * rsqrtf(vs[li][o] + 1e-5f);
            acc = (acc - ms[li][o]) * sc + bes[li][o];
            hout[o][t + 1] = acc;
        }
        __syncthreads();
        float (*tmp)[10] = hin; hin = hout; hout = tmp;
    }

    if (tid < 64) {
        float s = 0.f;
        #pragma unroll
        for (int t = 0; t < 8; ++t) s += hin[tid][t + 1];
        mo[tid] = s * 0.125f;
    }
    __syncthreads();
    if (tid < 64) {
        float acc = fct_b[tid];
        #pragma unroll 8
        for (int o = 0; o < 64; ++o) acc = fmaf(mo[o], fct_w[o * 64 + tid], acc);
        out2[(size_t)n * 64 + tid] = acc;
    }
}

// ---------------------------------------------------------------------------
extern "C" void kernel_launch(void* const* d_in, const int* in_sizes, int n_in,
                              void* d_out, int out_size, void* d_ws, size_t ws_size,
                              hipStream_t stream) {
    (void)in_sizes; (void)n_in; (void)out_size; (void)ws_size;

    const float* x          = (const float*)d_in[0];
    const int*   node_tok   = (const int*)d_in[1];
    const int*   inc_node   = (const int*)d_in[2];
    const int*   inc_hedge  = (const int*)d_in[3];
    const int*   node2cell  = (const int*)d_in[4];
    const float* vac_emb    = (const float*)d_in[5];
    const float* fhi_w      = (const float*)d_in[6];
    const float* fhi_b      = (const float*)d_in[7];
    const float* fin_w      = (const float*)d_in[8];
    const float* fin_b      = (const float*)d_in[9];
    const float* th1        = (const float*)d_in[10];
    const float* b1         = (const float*)d_in[11];
    const float* th2        = (const float*)d_in[12];
    const float* b2         = (const float*)d_in[13];
    const float* fct_w      = (const float*)d_in[32];
    const float* fct_b      = (const float*)d_in[33];

    char* ws = (char*)d_ws;
    size_t off = 0;
    float* P        = (float*)(ws + off); off += (size_t)VOCAB * 64 * 4;        // 7,680,000
    float* nf       = (float*)(ws + off); off += (size_t)N_NODES * 64 * 4;      // 40,960,000
    float* hbuf     = (float*)(ws + off); off += (size_t)N_NODES * 64 * 4;      // 40,960,000
    u16*   xt       = (u16*)(ws + off);   off += (size_t)N_NODES * 64 * 2;      // 20,480,000
    u16*   he       = (u16*)(ws + off);   off += (size_t)N_HE * 64 * 2;         // 40,960,000
    float* x0       = (float*)(ws + off); off += (size_t)N_CELLS * 64 * 4;      // 204,800
    int*   he_off   = (int*)(ws + off);   off += ((size_t)(N_HE + 1) * 4 + 255) / 256 * 256;
    int*   node_off = (int*)(ws + off);   off += ((size_t)(N_NODES + 1) * 4 + 255) / 256 * 256;
    int*   deg_v    = (int*)(ws + off);   off += (size_t)N_NODES * 4;
    int*   cursor   = (int*)(ws + off);   off += (size_t)N_NODES * 4;           // adjacent to deg_v
    int*   csr      = (int*)(ws + off);   off += (size_t)N_INC * 4;
    int*   cell_off = (int*)(ws + off);   off += ((size_t)(N_CELLS + 1) * 4 + 255) / 256 * 256;
    int*   bsum     = (int*)(ws + off);   off += 1024 * 4;

    float* out1 = (float*)d_out;           // x_upd [100*8*64]
    float* out2 = out1 + (size_t)I_ * J_ * D_H;

    // ---- CSR / offsets build (once, reused by both hconv layers) ----
    hipMemsetAsync(deg_v, 0, 2 * (size_t)N_NODES * 4, stream);
    k_offsets<<<N_INC / 256, 256, 0, stream>>>(inc_hedge, N_INC, N_HE, he_off);
    k_offsets<<<N_NODES / 256, 256, 0, stream>>>(node2cell, N_NODES, N_CELLS, cell_off);
    k_hist<<<N_INC / 256, 256, 0, stream>>>(inc_node, N_INC, deg_v);
    k_scan1<<<N_NODES / 256, 256, 0, stream>>>(deg_v, N_NODES, node_off, bsum);
    k_scan2<<<1, 1024, 0, stream>>>(bsum, N_NODES / 256);
    k_scan3<<<N_NODES / 256, 256, 0, stream>>>(node_off, bsum, N_NODES, N_INC);
    k_csr_fill<<<N_INC / 256, 256, 0, stream>>>(inc_node, inc_hedge, N_INC, node_off, cursor, csr);

    // ---- P = vac_emb @ fhi_w + fhi_b ; nf = P[tok] ----
    k_gemm64<0><<<(VOCAB + 63) / 64, 256, 0, stream>>>(vac_emb, fhi_w, fhi_b, P, VOCAB, D_IN);
    k_gather_nf<<<(N_NODES * 16) / 256, 256, 0, stream>>>((const float4*)P, node_tok, (float4*)nf);

    // ---- hconv layer 1 ----
    k_gemm64<1><<<N_NODES / 64, 256, 0, stream>>>(nf, th1, nullptr, xt, N_NODES, 64);
    k_hedge_sum<<<N_HE / 4, 256, 0, stream>>>(inc_node, he_off, xt, he);
    k_node_sum<<<N_NODES / 4, 256, 0, stream>>>(csr, node_off, he, b1, nf, hbuf);   // hbuf = h1

    // ---- hconv layer 2 ----
    k_gemm64<1><<<N_NODES / 64, 256, 0, stream>>>(hbuf, th2, nullptr, xt, N_NODES, 64);
    k_hedge_sum<<<N_HE / 4, 256, 0, stream>>>(inc_node, he_off, xt, he);
    k_node_sum<<<N_NODES / 4, 256, 0, stream>>>(csr, node_off, he, b2, nf, hbuf);   // hbuf = gx

    // ---- x0 = x @ fin_w + fin_b ; pool + fuse x_upd -> d_out ----
    k_gemm64<0><<<(I_ * J_ + 63) / 64, 256, 0, stream>>>(x, fin_w, fin_b, x0, I_ * J_, D_IN);
    k_pool<<<N_CELLS, 256, 0, stream>>>(hbuf, cell_off, x0, out1);

    // ---- TCN + final fc -> d_out part 2 ----
    k_tcn<<<I_, 256, 0, stream>>>(out1,
        (const float*)d_in[14], (const float*)d_in[15], (const float*)d_in[16],
        (const float*)d_in[17], (const float*)d_in[18], (const float*)d_in[19],
        (const float*)d_in[20], (const float*)d_in[21], (const float*)d_in[22],
        (const float*)d_in[23], (const float*)d_in[24], (const float*)d_in[25],
        (const float*)d_in[26], (const float*)d_in[27], (const float*)d_in[28],
        (const float*)d_in[29], (const float*)d_in[30], (const float*)d_in[31],
        fct_w, fct_b, out2);
}

// Round 2
// 1077.033 us; speedup vs baseline: 1.3081x; 1.3081x over previous
//
#include <hip/hip_runtime.h>
#include <hip/hip_bf16.h>
#include <cstdint>
#include <cstddef>

#define I_      100
#define J_      8
#define D_IN    768
#define D_H     64
#define N_NODES 160000
#define N_HE    320000
#define N_INC   1600000
#define N_CELLS 800
#define VOCAB   30000

typedef unsigned short u16;

__device__ __forceinline__ float bf2f(u16 u) {
    union { uint32_t i; float f; } x; x.i = ((uint32_t)u) << 16; return x.f;
}
__device__ __forceinline__ u16 f2bf(float f) {
    union { float f; uint32_t i; } x; x.f = f;
    uint32_t b = x.i;
    b += 0x7FFFu + ((b >> 16) & 1u);   // round-to-nearest-even
    return (u16)(b >> 16);
}
__device__ __forceinline__ float lo_bf(uint32_t u) {
    union { uint32_t i; float f; } x; x.i = u << 16; return x.f;
}
__device__ __forceinline__ float hi_bf(uint32_t u) {
    union { uint32_t i; float f; } x; x.i = u & 0xFFFF0000u; return x.f;
}

// ---------------------------------------------------------------------------
// CSR / offsets machinery
// ---------------------------------------------------------------------------

__global__ __launch_bounds__(256) void k_offsets(const int* __restrict__ sorted, int n,
                                                 int nbins, int* __restrict__ off) {
    int i = blockIdx.x * 256 + threadIdx.x;
    if (i >= n) return;
    int cur = sorted[i];
    int prev = (i == 0) ? -1 : sorted[i - 1];
    for (int b = prev + 1; b <= cur; ++b) off[b] = i;
    if (i == n - 1) {
        for (int b = cur + 1; b <= nbins; ++b) off[b] = n;
    }
}

__global__ __launch_bounds__(256) void k_hist(const int* __restrict__ idx, int n,
                                              int* __restrict__ deg) {
    int i = blockIdx.x * 256 + threadIdx.x;
    if (i < n) atomicAdd(&deg[idx[i]], 1);
}

__global__ __launch_bounds__(256) void k_scan1(const int* __restrict__ deg, int n,
                                               int* __restrict__ off, int* __restrict__ bsum) {
    __shared__ int s[256];
    int tid = threadIdx.x;
    int i = blockIdx.x * 256 + tid;
    int v = (i < n) ? deg[i] : 0;
    s[tid] = v;
    __syncthreads();
    #pragma unroll
    for (int d = 1; d < 256; d <<= 1) {
        int t = (tid >= d) ? s[tid - d] : 0;
        __syncthreads();
        s[tid] += t;
        __syncthreads();
    }
    if (i < n) off[i] = s[tid] - v;
    if (tid == 255) bsum[blockIdx.x] = s[255];
}

__global__ __launch_bounds__(1024) void k_scan2(int* __restrict__ bsum, int nb) {
    __shared__ int s[1024];
    int tid = threadIdx.x;
    int v = (tid < nb) ? bsum[tid] : 0;
    s[tid] = v;
    __syncthreads();
    #pragma unroll
    for (int d = 1; d < 1024; d <<= 1) {
        int t = (tid >= d) ? s[tid - d] : 0;
        __syncthreads();
        s[tid] += t;
        __syncthreads();
    }
    if (tid < nb) bsum[tid] = s[tid] - v;
}

__global__ __launch_bounds__(256) void k_scan3(int* __restrict__ off, const int* __restrict__ bsum,
                                               int n, int total) {
    int i = blockIdx.x * 256 + threadIdx.x;
    if (i < n) off[i] += bsum[blockIdx.x];
    if (i == 0) off[n] = total;
}

__global__ __launch_bounds__(256) void k_csr_fill(const int* __restrict__ inc_node,
                                                  const int* __restrict__ inc_hedge, int n,
                                                  const int* __restrict__ node_off,
                                                  int* __restrict__ cursor,
                                                  int* __restrict__ csr) {
    int i = blockIdx.x * 256 + threadIdx.x;
    if (i >= n) return;
    int v = inc_node[i];
    int p = node_off[v] + atomicAdd(&cursor[v], 1);
    csr[p] = inc_hedge[i];
}

// ---------------------------------------------------------------------------
// GEMM: C[M,64] = A[M,K] @ B[K,64] (+bias). 64x64 tile/block, 4x4 per thread.
// ---------------------------------------------------------------------------
template <int BF16_OUT>
__global__ __launch_bounds__(256) void k_gemm64(const float* __restrict__ A,
                                                const float* __restrict__ B,
                                                const float* __restrict__ bias,
                                                void* __restrict__ C, int M, int K) {
    __shared__ float As[32][68];
    __shared__ float Bs[32][68];
    int tid = threadIdx.x;
    int tx = tid & 15, ty = tid >> 4;
    int row0 = blockIdx.x << 6;
    float acc[4][4] = {{0.f}};

    for (int k0 = 0; k0 < K; k0 += 32) {
        #pragma unroll
        for (int l = tid; l < 64 * 32; l += 256) {
            int m = l >> 5, k = l & 31;
            int gr = row0 + m;
            As[k][m] = (gr < M) ? A[(size_t)gr * K + (k0 + k)] : 0.f;
        }
        #pragma unroll
        for (int l = tid; l < 32 * 64; l += 256) {
            int k = l >> 6, n = l & 63;
            Bs[k][n] = B[(size_t)(k0 + k) * 64 + n];
        }
        __syncthreads();
        #pragma unroll
        for (int kk = 0; kk < 32; ++kk) {
            float4 a = *reinterpret_cast<const float4*>(&As[kk][ty << 2]);
            float4 b = *reinterpret_cast<const float4*>(&Bs[kk][tx << 2]);
            acc[0][0] = fmaf(a.x, b.x, acc[0][0]);
            acc[0][1] = fmaf(a.x, b.y, acc[0][1]);
            acc[0][2] = fmaf(a.x, b.z, acc[0][2]);
            acc[0][3] = fmaf(a.x, b.w, acc[0][3]);
            acc[1][0] = fmaf(a.y, b.x, acc[1][0]);
            acc[1][1] = fmaf(a.y, b.y, acc[1][1]);
            acc[1][2] = fmaf(a.y, b.z, acc[1][2]);
            acc[1][3] = fmaf(a.y, b.w, acc[1][3]);
            acc[2][0] = fmaf(a.z, b.x, acc[2][0]);
            acc[2][1] = fmaf(a.z, b.y, acc[2][1]);
            acc[2][2] = fmaf(a.z, b.z, acc[2][2]);
            acc[2][3] = fmaf(a.z, b.w, acc[2][3]);
            acc[3][0] = fmaf(a.w, b.x, acc[3][0]);
            acc[3][1] = fmaf(a.w, b.y, acc[3][1]);
            acc[3][2] = fmaf(a.w, b.z, acc[3][2]);
            acc[3][3] = fmaf(a.w, b.w, acc[3][3]);
        }
        __syncthreads();
    }

    float bv[4] = {0.f, 0.f, 0.f, 0.f};
    if (bias) {
        bv[0] = bias[(tx << 2) + 0];
        bv[1] = bias[(tx << 2) + 1];
        bv[2] = bias[(tx << 2) + 2];
        bv[3] = bias[(tx << 2) + 3];
    }
    #pragma unroll
    for (int r = 0; r < 4; ++r) {
        int gr = row0 + (ty << 2) + r;
        if (gr >= M) continue;
        float v0 = acc[r][0] + bv[0];
        float v1 = acc[r][1] + bv[1];
        float v2 = acc[r][2] + bv[2];
        float v3 = acc[r][3] + bv[3];
        if (BF16_OUT) {
            ushort4 u;
            u.x = f2bf(v0); u.y = f2bf(v1); u.z = f2bf(v2); u.w = f2bf(v3);
            *reinterpret_cast<ushort4*>((u16*)C + (size_t)gr * 64 + (tx << 2)) = u;
        } else {
            *reinterpret_cast<float4*>((float*)C + (size_t)gr * 64 + (tx << 2)) =
                make_float4(v0, v1, v2, v3);
        }
    }
}

// ---------------------------------------------------------------------------
// nf[n] = P[tok[n]]
// ---------------------------------------------------------------------------
__global__ __launch_bounds__(256) void k_gather_nf(const float4* __restrict__ P,
                                                   const int* __restrict__ tok,
                                                   float4* __restrict__ nf) {
    int g = blockIdx.x * 256 + threadIdx.x;
    if (g >= N_NODES * 16) return;
    int n = g >> 4, p = g & 15;
    nf[g] = P[((size_t)tok[n] << 4) + p];
}

// ---------------------------------------------------------------------------
// he[e] = (1/deg_e) * sum xt[inc_node[j]]  -- 4x16 sub-group version.
// Wave = 4 sub-groups of 16 lanes; each sub-group gathers a different
// incidence row with uint2 (4 bf16) per lane; shfl_xor combine at end.
// ---------------------------------------------------------------------------
__global__ __launch_bounds__(256) void k_hedge_sum(const int* __restrict__ inc_node,
                                                   const int* __restrict__ he_off,
                                                   const u16* __restrict__ xt,
                                                   u16* __restrict__ he) {
    int w = (blockIdx.x * 256 + threadIdx.x) >> 6;
    int lane = threadIdx.x & 63;
    if (w >= N_HE) return;
    int sub = lane >> 4;            // 0..3 : which incidence in the quad
    int col4 = (lane & 15) << 2;    // 4 consecutive bf16 columns
    int s = he_off[w], e = he_off[w + 1];

    float a0 = 0.f, a1 = 0.f, a2 = 0.f, a3 = 0.f;

    int jj = s + sub;
    int idx = (jj < e) ? inc_node[jj] : -1;          // prefetched indices
    for (int j0 = s; j0 < e; j0 += 4) {
        int cur = idx;
        int jn = j0 + 4 + sub;
        idx = (jn < e) ? inc_node[jn] : -1;          // prefetch next quad
        if (cur >= 0) {
            uint2 d = *reinterpret_cast<const uint2*>(xt + (((size_t)cur) << 6) + col4);
            a0 += lo_bf(d.x); a1 += hi_bf(d.x);
            a2 += lo_bf(d.y); a3 += hi_bf(d.y);
        }
    }
    // combine the 4 sub-group partials (xor 16, xor 32)
    a0 += __shfl_xor(a0, 16, 64); a1 += __shfl_xor(a1, 16, 64);
    a2 += __shfl_xor(a2, 16, 64); a3 += __shfl_xor(a3, 16, 64);
    a0 += __shfl_xor(a0, 32, 64); a1 += __shfl_xor(a1, 32, 64);
    a2 += __shfl_xor(a2, 32, 64); a3 += __shfl_xor(a3, 32, 64);

    if (sub == 0) {   // lanes 0..15 write 4 bf16 each (coalesced 128 B)
        float inv = (e > s) ? 1.f / (float)(e - s) : 0.f;
        uint2 o;
        o.x = (uint32_t)f2bf(a0 * inv) | ((uint32_t)f2bf(a1 * inv) << 16);
        o.y = (uint32_t)f2bf(a2 * inv) | ((uint32_t)f2bf(a3 * inv) << 16);
        *reinterpret_cast<uint2*>(he + (((size_t)w) << 6) + col4) = o;
    }
}

// ---------------------------------------------------------------------------
// out[v] = relu((1/deg_v) * sum he[csr[j]] + bias) + nf[v]  -- 4x16 version
// ---------------------------------------------------------------------------
__global__ __launch_bounds__(256) void k_node_sum(const int* __restrict__ csr,
                                                  const int* __restrict__ node_off,
                                                  const u16* __restrict__ he,
                                                  const float* __restrict__ bias,
                                                  const float* __restrict__ nf,
                                                  float* __restrict__ out) {
    int w = (blockIdx.x * 256 + threadIdx.x) >> 6;
    int lane = threadIdx.x & 63;
    if (w >= N_NODES) return;
    int sub = lane >> 4;
    int col4 = (lane & 15) << 2;
    int s = node_off[w], e = node_off[w + 1];

    float a0 = 0.f, a1 = 0.f, a2 = 0.f, a3 = 0.f;

    int jj = s + sub;
    int idx = (jj < e) ? csr[jj] : -1;
    for (int j0 = s; j0 < e; j0 += 4) {
        int cur = idx;
        int jn = j0 + 4 + sub;
        idx = (jn < e) ? csr[jn] : -1;
        if (cur >= 0) {
            uint2 d = *reinterpret_cast<const uint2*>(he + (((size_t)cur) << 6) + col4);
            a0 += lo_bf(d.x); a1 += hi_bf(d.x);
            a2 += lo_bf(d.y); a3 += hi_bf(d.y);
        }
    }
    a0 += __shfl_xor(a0, 16, 64); a1 += __shfl_xor(a1, 16, 64);
    a2 += __shfl_xor(a2, 16, 64); a3 += __shfl_xor(a3, 16, 64);
    a0 += __shfl_xor(a0, 32, 64); a1 += __shfl_xor(a1, 32, 64);
    a2 += __shfl_xor(a2, 32, 64); a3 += __shfl_xor(a3, 32, 64);

    if (sub == 0) {
        float inv = (e > s) ? 1.f / (float)(e - s) : 0.f;
        float4 nv = *reinterpret_cast<const float4*>(nf + (((size_t)w) << 6) + col4);
        float4 o;
        o.x = fmaxf(fmaf(a0, inv, bias[col4 + 0]), 0.f) + nv.x;
        o.y = fmaxf(fmaf(a1, inv, bias[col4 + 1]), 0.f) + nv.y;
        o.z = fmaxf(fmaf(a2, inv, bias[col4 + 2]), 0.f) + nv.z;
        o.w = fmaxf(fmaf(a3, inv, bias[col4 + 3]), 0.f) + nv.w;
        *reinterpret_cast<float4*>(out + (((size_t)w) << 6) + col4) = o;
    }
}

// ---------------------------------------------------------------------------
// per-cell mean+max pooling, fused x_upd = x0 + 0.3*cell_emb
// ---------------------------------------------------------------------------
__global__ __launch_bounds__(256) void k_pool(const float* __restrict__ gx,
                                              const int* __restrict__ cell_off,
                                              const float* __restrict__ x0,
                                              float* __restrict__ out1) {
    __shared__ float ssum[4][64];
    __shared__ float smax[4][64];
    int c = blockIdx.x;
    int lane = threadIdx.x & 63;
    int w = threadIdx.x >> 6;
    int s = cell_off[c], e = cell_off[c + 1];
    float sum = 0.f, mx = -INFINITY;
    for (int n = s + w; n < e; n += 4) {
        float v = gx[((size_t)n << 6) + lane];
        sum += v;
        mx = fmaxf(mx, v);
    }
    ssum[w][lane] = sum;
    smax[w][lane] = mx;
    __syncthreads();
    if (w == 0) {
        sum = ssum[0][lane] + ssum[1][lane] + ssum[2][lane] + ssum[3][lane];
        mx = fmaxf(fmaxf(smax[0][lane], smax[1][lane]), fmaxf(smax[2][lane], smax[3][lane]));
        int cnt = e - s;
        float mean = (cnt > 0) ? sum / (float)cnt : 0.f;
        float mp = (cnt > 0) ? mx : 0.f;
        float ce = 0.5f * (mean + mp);
        out1[((size_t)c << 6) + lane] = x0[((size_t)c << 6) + lane] + 0.3f * ce;
    }
}

// ---------------------------------------------------------------------------
// fused TCN
// ---------------------------------------------------------------------------
__global__ __launch_bounds__(256) void k_tcn(
    const float* __restrict__ xu,
    const float* __restrict__ wc1, const float* __restrict__ bc1, const float* __restrict__ g1,
    const float* __restrict__ be1, const float* __restrict__ m1, const float* __restrict__ v1,
    const float* __restrict__ wc2, const float* __restrict__ bc2, const float* __restrict__ g2,
    const float* __restrict__ be2, const float* __restrict__ m2, const float* __restrict__ v2,
    const float* __restrict__ wc3, const float* __restrict__ bc3, const float* __restrict__ g3,
    const float* __restrict__ be3, const float* __restrict__ m3, const float* __restrict__ v3,
    const float* __restrict__ fct_w, const float* __restrict__ fct_b,
    float* __restrict__ out2) {
    __shared__ float w_lds[64 * 64 * 3];
    __shared__ float hA[64][10];
    __shared__ float hB[64][10];
    __shared__ float mo[64];

    int n = blockIdx.x, tid = threadIdx.x;

    if (tid < 64) {
        hA[tid][0] = 0.f; hA[tid][9] = 0.f;
        hB[tid][0] = 0.f; hB[tid][9] = 0.f;
    }
    #pragma unroll
    for (int l = tid; l < 512; l += 256) {
        int t = l >> 6, i = l & 63;
        hA[i][t + 1] = xu[(size_t)n * 512 + l];
    }

    const float* wcs[3] = {wc1, wc2, wc3};
    const float* bcs[3] = {bc1, bc2, bc3};
    const float* gs[3]  = {g1, g2, g3};
    const float* bes[3] = {be1, be2, be3};
    const float* ms[3]  = {m1, m2, m3};
    const float* vs[3]  = {v1, v2, v3};

    float (*hin)[10] = hA;
    float (*hout)[10] = hB;

    #pragma unroll
    for (int li = 0; li < 3; ++li) {
        for (int l = tid; l < 64 * 64 * 3; l += 256) w_lds[l] = wcs[li][l];
        __syncthreads();
        #pragma unroll
        for (int rep = 0; rep < 2; ++rep) {
            int idx = tid + rep * 256;
            int o = idx >> 3, t = idx & 7;
            float acc = bcs[li][o];
            #pragma unroll 8
            for (int i = 0; i < 64; ++i) {
                const float* wr = &w_lds[o * 192 + i * 3];
                acc = fmaf(hin[i][t + 0], wr[0], acc);
                acc = fmaf(hin[i][t + 1], wr[1], acc);
                acc = fmaf(hin[i][t + 2], wr[2], acc);
            }
            acc = fmaxf(acc, 0.f);
            float sc = gs[li][o] * rsqrtf(vs[li][o] + 1e-5f);
            acc = (acc - ms[li][o]) * sc + bes[li][o];
            hout[o][t + 1] = acc;
        }
        __syncthreads();
        float (*tmp)[10] = hin; hin = hout; hout = tmp;
    }

    if (tid < 64) {
        float s = 0.f;
        #pragma unroll
        for (int t = 0; t < 8; ++t) s += hin[tid][t + 1];
        mo[tid] = s * 0.125f;
    }
    __syncthreads();
    if (tid < 64) {
        float acc = fct_b[tid];
        #pragma unroll 8
        for (int o = 0; o < 64; ++o) acc = fmaf(mo[o], fct_w[o * 64 + tid], acc);
        out2[(size_t)n * 64 + tid] = acc;
    }
}

// ---------------------------------------------------------------------------
extern "C" void kernel_launch(void* const* d_in, const int* in_sizes, int n_in,
                              void* d_out, int out_size, void* d_ws, size_t ws_size,
                              hipStream_t stream) {
    (void)in_sizes; (void)n_in; (void)out_size; (void)ws_size;

    const float* x          = (const float*)d_in[0];
    const int*   node_tok   = (const int*)d_in[1];
    const int*   inc_node   = (const int*)d_in[2];
    const int*   inc_hedge  = (const int*)d_in[3];
    const int*   node2cell  = (const int*)d_in[4];
    const float* vac_emb    = (const float*)d_in[5];
    const float* fhi_w      = (const float*)d_in[6];
    const float* fhi_b      = (const float*)d_in[7];
    const float* fin_w      = (const float*)d_in[8];
    const float* fin_b      = (const float*)d_in[9];
    const float* th1        = (const float*)d_in[10];
    const float* b1         = (const float*)d_in[11];
    const float* th2        = (const float*)d_in[12];
    const float* b2         = (const float*)d_in[13];
    const float* fct_w      = (const float*)d_in[32];
    const float* fct_b      = (const float*)d_in[33];

    char* ws = (char*)d_ws;
    size_t off = 0;
    float* P        = (float*)(ws + off); off += (size_t)VOCAB * 64 * 4;
    float* nf       = (float*)(ws + off); off += (size_t)N_NODES * 64 * 4;
    float* hbuf     = (float*)(ws + off); off += (size_t)N_NODES * 64 * 4;
    u16*   xt       = (u16*)(ws + off);   off += (size_t)N_NODES * 64 * 2;
    u16*   he       = (u16*)(ws + off);   off += (size_t)N_HE * 64 * 2;
    float* x0       = (float*)(ws + off); off += (size_t)N_CELLS * 64 * 4;
    int*   he_off   = (int*)(ws + off);   off += ((size_t)(N_HE + 1) * 4 + 255) / 256 * 256;
    int*   node_off = (int*)(ws + off);   off += ((size_t)(N_NODES + 1) * 4 + 255) / 256 * 256;
    int*   deg_v    = (int*)(ws + off);   off += (size_t)N_NODES * 4;
    int*   cursor   = (int*)(ws + off);   off += (size_t)N_NODES * 4;
    int*   csr      = (int*)(ws + off);   off += (size_t)N_INC * 4;
    int*   cell_off = (int*)(ws + off);   off += ((size_t)(N_CELLS + 1) * 4 + 255) / 256 * 256;
    int*   bsum     = (int*)(ws + off);   off += 1024 * 4;

    float* out1 = (float*)d_out;
    float* out2 = out1 + (size_t)I_ * J_ * D_H;

    // ---- CSR / offsets build ----
    hipMemsetAsync(deg_v, 0, 2 * (size_t)N_NODES * 4, stream);
    k_offsets<<<N_INC / 256, 256, 0, stream>>>(inc_hedge, N_INC, N_HE, he_off);
    k_offsets<<<N_NODES / 256, 256, 0, stream>>>(node2cell, N_NODES, N_CELLS, cell_off);
    k_hist<<<N_INC / 256, 256, 0, stream>>>(inc_node, N_INC, deg_v);
    k_scan1<<<N_NODES / 256, 256, 0, stream>>>(deg_v, N_NODES, node_off, bsum);
    k_scan2<<<1, 1024, 0, stream>>>(bsum, N_NODES / 256);
    k_scan3<<<N_NODES / 256, 256, 0, stream>>>(node_off, bsum, N_NODES, N_INC);
    k_csr_fill<<<N_INC / 256, 256, 0, stream>>>(inc_node, inc_hedge, N_INC, node_off, cursor, csr);

    // ---- P = vac_emb @ fhi_w + fhi_b ; nf = P[tok] ----
    k_gemm64<0><<<(VOCAB + 63) / 64, 256, 0, stream>>>(vac_emb, fhi_w, fhi_b, P, VOCAB, D_IN);
    k_gather_nf<<<(N_NODES * 16) / 256, 256, 0, stream>>>((const float4*)P, node_tok, (float4*)nf);

    // ---- hconv layer 1 ----
    k_gemm64<1><<<N_NODES / 64, 256, 0, stream>>>(nf, th1, nullptr, xt, N_NODES, 64);
    k_hedge_sum<<<N_HE / 4, 256, 0, stream>>>(inc_node, he_off, xt, he);
    k_node_sum<<<N_NODES / 4, 256, 0, stream>>>(csr, node_off, he, b1, nf, hbuf);

    // ---- hconv layer 2 ----
    k_gemm64<1><<<N_NODES / 64, 256, 0, stream>>>(hbuf, th2, nullptr, xt, N_NODES, 64);
    k_hedge_sum<<<N_HE / 4, 256, 0, stream>>>(inc_node, he_off, xt, he);
    k_node_sum<<<N_NODES / 4, 256, 0, stream>>>(csr, node_off, he, b2, nf, hbuf);

    // ---- x0 = x @ fin_w + fin_b ; pool + fuse ----
    k_gemm64<0><<<(I_ * J_ + 63) / 64, 256, 0, stream>>>(x, fin_w, fin_b, x0, I_ * J_, D_IN);
    k_pool<<<N_CELLS, 256, 0, stream>>>(hbuf, cell_off, x0, out1);

    // ---- TCN ----
    k_tcn<<<I_, 256, 0, stream>>>(out1,
        (const float*)d_in[14], (const float*)d_in[15], (const float*)d_in[16],
        (const float*)d_in[17], (const float*)d_in[18], (const float*)d_in[19],
        (const float*)d_in[20], (const float*)d_in[21], (const float*)d_in[22],
        (const float*)d_in[23], (const float*)d_in[24], (const float*)d_in[25],
        (const float*)d_in[26], (const float*)d_in[27], (const float*)d_in[28],
        (const float*)d_in[29], (const float*)d_in[30], (const float*)d_in[31],
        fct_w, fct_b, out2);
}

// Round 3
// 869.422 us; speedup vs baseline: 1.6205x; 1.2388x over previous
//
#include <hip/hip_runtime.h>
#include <hip/hip_bf16.h>
#include <cstdint>
#include <cstddef>

#define I_      100
#define J_      8
#define D_IN    768
#define D_H     64
#define N_NODES 160000
#define N_HE    320000
#define N_INC   1600000
#define N_CELLS 800
#define VOCAB   30000

typedef unsigned short u16;
using short8 = __attribute__((ext_vector_type(8))) short;
using f32x4  = __attribute__((ext_vector_type(4))) float;

__device__ __forceinline__ float bf2f(u16 u) {
    union { uint32_t i; float f; } x; x.i = ((uint32_t)u) << 16; return x.f;
}
__device__ __forceinline__ u16 f2bf(float f) {
    union { float f; uint32_t i; } x; x.f = f;
    uint32_t b = x.i;
    b += 0x7FFFu + ((b >> 16) & 1u);   // round-to-nearest-even
    return (u16)(b >> 16);
}
__device__ __forceinline__ float lo_bf(uint32_t u) {
    union { uint32_t i; float f; } x; x.i = u << 16; return x.f;
}
__device__ __forceinline__ float hi_bf(uint32_t u) {
    union { uint32_t i; float f; } x; x.i = u & 0xFFFF0000u; return x.f;
}

// ---------------------------------------------------------------------------
// CSR / offsets machinery
// ---------------------------------------------------------------------------

__global__ __launch_bounds__(256) void k_offsets(const int* __restrict__ sorted, int n,
                                                 int nbins, int* __restrict__ off) {
    int i = blockIdx.x * 256 + threadIdx.x;
    if (i >= n) return;
    int cur = sorted[i];
    int prev = (i == 0) ? -1 : sorted[i - 1];
    for (int b = prev + 1; b <= cur; ++b) off[b] = i;
    if (i == n - 1) {
        for (int b = cur + 1; b <= nbins; ++b) off[b] = n;
    }
}

__global__ __launch_bounds__(256) void k_hist(const int* __restrict__ idx, int n,
                                              int* __restrict__ deg) {
    int i = blockIdx.x * 256 + threadIdx.x;
    if (i < n) atomicAdd(&deg[idx[i]], 1);
}

__global__ __launch_bounds__(256) void k_scan1(const int* __restrict__ deg, int n,
                                               int* __restrict__ off, int* __restrict__ bsum) {
    __shared__ int s[256];
    int tid = threadIdx.x;
    int i = blockIdx.x * 256 + tid;
    int v = (i < n) ? deg[i] : 0;
    s[tid] = v;
    __syncthreads();
    #pragma unroll
    for (int d = 1; d < 256; d <<= 1) {
        int t = (tid >= d) ? s[tid - d] : 0;
        __syncthreads();
        s[tid] += t;
        __syncthreads();
    }
    if (i < n) off[i] = s[tid] - v;
    if (tid == 255) bsum[blockIdx.x] = s[255];
}

__global__ __launch_bounds__(1024) void k_scan2(int* __restrict__ bsum, int nb) {
    __shared__ int s[1024];
    int tid = threadIdx.x;
    int v = (tid < nb) ? bsum[tid] : 0;
    s[tid] = v;
    __syncthreads();
    #pragma unroll
    for (int d = 1; d < 1024; d <<= 1) {
        int t = (tid >= d) ? s[tid - d] : 0;
        __syncthreads();
        s[tid] += t;
        __syncthreads();
    }
    if (tid < nb) bsum[tid] = s[tid] - v;
}

__global__ __launch_bounds__(256) void k_scan3(int* __restrict__ off, const int* __restrict__ bsum,
                                               int n, int total) {
    int i = blockIdx.x * 256 + threadIdx.x;
    if (i < n) off[i] += bsum[blockIdx.x];
    if (i == 0) off[n] = total;
}

__global__ __launch_bounds__(256) void k_csr_fill(const int* __restrict__ inc_node,
                                                  const int* __restrict__ inc_hedge, int n,
                                                  const int* __restrict__ node_off,
                                                  int* __restrict__ cursor,
                                                  int* __restrict__ csr) {
    int i = blockIdx.x * 256 + threadIdx.x;
    if (i >= n) return;
    int v = inc_node[i];
    int p = node_off[v] + atomicAdd(&cursor[v], 1);
    csr[p] = inc_hedge[i];
}

// ---------------------------------------------------------------------------
// Weight convert + transpose: B[K][64] f32 -> Bt[64][K] bf16
// ---------------------------------------------------------------------------
__global__ __launch_bounds__(256) void k_convT(const float* __restrict__ B,
                                               u16* __restrict__ Bt, int K) {
    int g = blockIdx.x * 256 + threadIdx.x;
    if (g >= K * 64) return;
    int k = g >> 6, n = g & 63;
    Bt[(size_t)n * K + k] = f2bf(B[g]);
}

// ---------------------------------------------------------------------------
// MFMA GEMM: C[M,64] = A[M,K](f32, converted to bf16) @ Bt[64,K](bf16) (+bias)
// block: 64 M-rows, 4 waves x 16 rows each; K-step 32 via mfma_f32_16x16x32_bf16.
// A-frag: lane holds A[m=lane&15][k=(lane>>4)*8+j]; B-frag: B[k][n=lane&15];
// C/D: col=lane&15, row=(lane>>4)*4+reg  [per cdna_hip_programming.md §3]
// ---------------------------------------------------------------------------
template <int BF16_OUT>
__global__ __launch_bounds__(256) void k_mfma_gemm(const float* __restrict__ A,
                                                   const u16* __restrict__ Bt,
                                                   const float* __restrict__ bias,
                                                   void* __restrict__ C, int M, int K) {
    __shared__ u16 Alds[64 * 40];   // 64 rows x 32 k, padded to 40 (80 B = 5x16B, aligned)
    int tid = threadIdx.x;
    int wave = tid >> 6, lane = tid & 63;
    int m16 = lane & 15, q = lane >> 4;
    int row0 = blockIdx.x << 6;

    f32x4 acc0 = {0.f, 0.f, 0.f, 0.f};
    f32x4 acc1 = {0.f, 0.f, 0.f, 0.f};
    f32x4 acc2 = {0.f, 0.f, 0.f, 0.f};
    f32x4 acc3 = {0.f, 0.f, 0.f, 0.f};

    for (int kt = 0; kt < K; kt += 32) {
        #pragma unroll
        for (int it = 0; it < 2; ++it) {
            int l = tid + it * 256;
            int r = l >> 3, c4 = (l & 7) << 2;
            int gr = row0 + r;
            float4 av = make_float4(0.f, 0.f, 0.f, 0.f);
            if (gr < M)
                av = *reinterpret_cast<const float4*>(A + (size_t)gr * K + kt + c4);
            ushort4 u;
            u.x = f2bf(av.x); u.y = f2bf(av.y); u.z = f2bf(av.z); u.w = f2bf(av.w);
            *reinterpret_cast<ushort4*>(&Alds[r * 40 + c4]) = u;
        }
        __syncthreads();

        short8 a = *reinterpret_cast<const short8*>(&Alds[(wave * 16 + m16) * 40 + q * 8]);
        const u16* bp = Bt + (size_t)m16 * K + kt + q * 8;
        short8 b0 = *reinterpret_cast<const short8*>(bp);
        short8 b1 = *reinterpret_cast<const short8*>(bp + (size_t)16 * K);
        short8 b2 = *reinterpret_cast<const short8*>(bp + (size_t)32 * K);
        short8 b3 = *reinterpret_cast<const short8*>(bp + (size_t)48 * K);

        acc0 = __builtin_amdgcn_mfma_f32_16x16x32_bf16(a, b0, acc0, 0, 0, 0);
        acc1 = __builtin_amdgcn_mfma_f32_16x16x32_bf16(a, b1, acc1, 0, 0, 0);
        acc2 = __builtin_amdgcn_mfma_f32_16x16x32_bf16(a, b2, acc2, 0, 0, 0);
        acc3 = __builtin_amdgcn_mfma_f32_16x16x32_bf16(a, b3, acc3, 0, 0, 0);
        __syncthreads();
    }

    // epilogue: rows = row0 + wave*16 + q*4 + r ; cols = j*16 + m16
    f32x4 accs[4] = {acc0, acc1, acc2, acc3};
    #pragma unroll
    for (int r = 0; r < 4; ++r) {
        int gr = row0 + wave * 16 + q * 4 + r;
        if (gr >= M) continue;
        #pragma unroll
        for (int j = 0; j < 4; ++j) {
            int col = j * 16 + m16;
            float v = accs[j][r];
            if (!BF16_OUT) v += bias[col];
            if (BF16_OUT)
                ((u16*)C)[(size_t)gr * 64 + col] = f2bf(v);
            else
                ((float*)C)[(size_t)gr * 64 + col] = v;
        }
    }
}

// ---------------------------------------------------------------------------
// nf[n] = P[tok[n]]
// ---------------------------------------------------------------------------
__global__ __launch_bounds__(256) void k_gather_nf(const float4* __restrict__ P,
                                                   const int* __restrict__ tok,
                                                   float4* __restrict__ nf) {
    int g = blockIdx.x * 256 + threadIdx.x;
    if (g >= N_NODES * 16) return;
    int n = g >> 4, p = g & 15;
    nf[g] = P[((size_t)tok[n] << 4) + p];
}

// ---------------------------------------------------------------------------
// he[e] = (1/deg_e) * sum xt[inc_node[j]]  -- 4x16 sub-group gather
// ---------------------------------------------------------------------------
__global__ __launch_bounds__(256) void k_hedge_sum(const int* __restrict__ inc_node,
                                                   const int* __restrict__ he_off,
                                                   const u16* __restrict__ xt,
                                                   u16* __restrict__ he) {
    int w = (blockIdx.x * 256 + threadIdx.x) >> 6;
    int lane = threadIdx.x & 63;
    if (w >= N_HE) return;
    int sub = lane >> 4;
    int col4 = (lane & 15) << 2;
    int s = he_off[w], e = he_off[w + 1];

    float a0 = 0.f, a1 = 0.f, a2 = 0.f, a3 = 0.f;

    int jj = s + sub;
    int idx = (jj < e) ? inc_node[jj] : -1;
    for (int j0 = s; j0 < e; j0 += 4) {
        int cur = idx;
        int jn = j0 + 4 + sub;
        idx = (jn < e) ? inc_node[jn] : -1;
        if (cur >= 0) {
            uint2 d = *reinterpret_cast<const uint2*>(xt + (((size_t)cur) << 6) + col4);
            a0 += lo_bf(d.x); a1 += hi_bf(d.x);
            a2 += lo_bf(d.y); a3 += hi_bf(d.y);
        }
    }
    a0 += __shfl_xor(a0, 16, 64); a1 += __shfl_xor(a1, 16, 64);
    a2 += __shfl_xor(a2, 16, 64); a3 += __shfl_xor(a3, 16, 64);
    a0 += __shfl_xor(a0, 32, 64); a1 += __shfl_xor(a1, 32, 64);
    a2 += __shfl_xor(a2, 32, 64); a3 += __shfl_xor(a3, 32, 64);

    if (sub == 0) {
        float inv = (e > s) ? 1.f / (float)(e - s) : 0.f;
        uint2 o;
        o.x = (uint32_t)f2bf(a0 * inv) | ((uint32_t)f2bf(a1 * inv) << 16);
        o.y = (uint32_t)f2bf(a2 * inv) | ((uint32_t)f2bf(a3 * inv) << 16);
        *reinterpret_cast<uint2*>(he + (((size_t)w) << 6) + col4) = o;
    }
}

// ---------------------------------------------------------------------------
// out[v] = relu((1/deg_v) * sum he[csr[j]] + bias) + nf[v]  -- 4x16 version
// ---------------------------------------------------------------------------
__global__ __launch_bounds__(256) void k_node_sum(const int* __restrict__ csr,
                                                  const int* __restrict__ node_off,
                                                  const u16* __restrict__ he,
                                                  const float* __restrict__ bias,
                                                  const float* __restrict__ nf,
                                                  float* __restrict__ out) {
    int w = (blockIdx.x * 256 + threadIdx.x) >> 6;
    int lane = threadIdx.x & 63;
    if (w >= N_NODES) return;
    int sub = lane >> 4;
    int col4 = (lane & 15) << 2;
    int s = node_off[w], e = node_off[w + 1];

    float a0 = 0.f, a1 = 0.f, a2 = 0.f, a3 = 0.f;

    int jj = s + sub;
    int idx = (jj < e) ? csr[jj] : -1;
    for (int j0 = s; j0 < e; j0 += 4) {
        int cur = idx;
        int jn = j0 + 4 + sub;
        idx = (jn < e) ? csr[jn] : -1;
        if (cur >= 0) {
            uint2 d = *reinterpret_cast<const uint2*>(he + (((size_t)cur) << 6) + col4);
            a0 += lo_bf(d.x); a1 += hi_bf(d.x);
            a2 += lo_bf(d.y); a3 += hi_bf(d.y);
        }
    }
    a0 += __shfl_xor(a0, 16, 64); a1 += __shfl_xor(a1, 16, 64);
    a2 += __shfl_xor(a2, 16, 64); a3 += __shfl_xor(a3, 16, 64);
    a0 += __shfl_xor(a0, 32, 64); a1 += __shfl_xor(a1, 32, 64);
    a2 += __shfl_xor(a2, 32, 64); a3 += __shfl_xor(a3, 32, 64);

    if (sub == 0) {
        float inv = (e > s) ? 1.f / (float)(e - s) : 0.f;
        float4 nv = *reinterpret_cast<const float4*>(nf + (((size_t)w) << 6) + col4);
        float4 o;
        o.x = fmaxf(fmaf(a0, inv, bias[col4 + 0]), 0.f) + nv.x;
        o.y = fmaxf(fmaf(a1, inv, bias[col4 + 1]), 0.f) + nv.y;
        o.z = fmaxf(fmaf(a2, inv, bias[col4 + 2]), 0.f) + nv.z;
        o.w = fmaxf(fmaf(a3, inv, bias[col4 + 3]), 0.f) + nv.w;
        *reinterpret_cast<float4*>(out + (((size_t)w) << 6) + col4) = o;
    }
}

// ---------------------------------------------------------------------------
// per-cell mean+max pooling, fused x_upd = x0 + 0.3*cell_emb
// ---------------------------------------------------------------------------
__global__ __launch_bounds__(256) void k_pool(const float* __restrict__ gx,
                                              const int* __restrict__ cell_off,
                                              const float* __restrict__ x0,
                                              float* __restrict__ out1) {
    __shared__ float ssum[4][64];
    __shared__ float smax[4][64];
    int c = blockIdx.x;
    int lane = threadIdx.x & 63;
    int w = threadIdx.x >> 6;
    int s = cell_off[c], e = cell_off[c + 1];
    float sum = 0.f, mx = -INFINITY;
    for (int n = s + w; n < e; n += 4) {
        float v = gx[((size_t)n << 6) + lane];
        sum += v;
        mx = fmaxf(mx, v);
    }
    ssum[w][lane] = sum;
    smax[w][lane] = mx;
    __syncthreads();
    if (w == 0) {
        sum = ssum[0][lane] + ssum[1][lane] + ssum[2][lane] + ssum[3][lane];
        mx = fmaxf(fmaxf(smax[0][lane], smax[1][lane]), fmaxf(smax[2][lane], smax[3][lane]));
        int cnt = e - s;
        float mean = (cnt > 0) ? sum / (float)cnt : 0.f;
        float mp = (cnt > 0) ? mx : 0.f;
        float ce = 0.5f * (mean + mp);
        out1[((size_t)c << 6) + lane] = x0[((size_t)c << 6) + lane] + 0.3f * ce;
    }
}

// ---------------------------------------------------------------------------
// fused TCN
// ---------------------------------------------------------------------------
__global__ __launch_bounds__(256) void k_tcn(
    const float* __restrict__ xu,
    const float* __restrict__ wc1, const float* __restrict__ bc1, const float* __restrict__ g1,
    const float* __restrict__ be1, const float* __restrict__ m1, const float* __restrict__ v1,
    const float* __restrict__ wc2, const float* __restrict__ bc2, const float* __restrict__ g2,
    const float* __restrict__ be2, const float* __restrict__ m2, const float* __restrict__ v2,
    const float* __restrict__ wc3, const float* __restrict__ bc3, const float* __restrict__ g3,
    const float* __restrict__ be3, const float* __restrict__ m3, const float* __restrict__ v3,
    const float* __restrict__ fct_w, const float* __restrict__ fct_b,
    float* __restrict__ out2) {
    __shared__ float w_lds[64 * 64 * 3];
    __shared__ float hA[64][10];
    __shared__ float hB[64][10];
    __shared__ float mo[64];

    int n = blockIdx.x, tid = threadIdx.x;

    if (tid < 64) {
        hA[tid][0] = 0.f; hA[tid][9] = 0.f;
        hB[tid][0] = 0.f; hB[tid][9] = 0.f;
    }
    #pragma unroll
    for (int l = tid; l < 512; l += 256) {
        int t = l >> 6, i = l & 63;
        hA[i][t + 1] = xu[(size_t)n * 512 + l];
    }

    const float* wcs[3] = {wc1, wc2, wc3};
    const float* bcs[3] = {bc1, bc2, bc3};
    const float* gs[3]  = {g1, g2, g3};
    const float* bes[3] = {be1, be2, be3};
    const float* ms[3]  = {m1, m2, m3};
    const float* vs[3]  = {v1, v2, v3};

    float (*hin)[10] = hA;
    float (*hout)[10] = hB;

    #pragma unroll
    for (int li = 0; li < 3; ++li) {
        for (int l = tid; l < 64 * 64 * 3; l += 256) w_lds[l] = wcs[li][l];
        __syncthreads();
        #pragma unroll
        for (int rep = 0; rep < 2; ++rep) {
            int idx = tid + rep * 256;
            int o = idx >> 3, t = idx & 7;
            float acc = bcs[li][o];
            #pragma unroll 8
            for (int i = 0; i < 64; ++i) {
                const float* wr = &w_lds[o * 192 + i * 3];
                acc = fmaf(hin[i][t + 0], wr[0], acc);
                acc = fmaf(hin[i][t + 1], wr[1], acc);
                acc = fmaf(hin[i][t + 2], wr[2], acc);
            }
            acc = fmaxf(acc, 0.f);
            float sc = gs[li][o] * rsqrtf(vs[li][o] + 1e-5f);
            acc = (acc - ms[li][o]) * sc + bes[li][o];
            hout[o][t + 1] = acc;
        }
        __syncthreads();
        float (*tmp)[10] = hin; hin = hout; hout = tmp;
    }

    if (tid < 64) {
        float s = 0.f;
        #pragma unroll
        for (int t = 0; t < 8; ++t) s += hin[tid][t + 1];
        mo[tid] = s * 0.125f;
    }
    __syncthreads();
    if (tid < 64) {
        float acc = fct_b[tid];
        #pragma unroll 8
        for (int o = 0; o < 64; ++o) acc = fmaf(mo[o], fct_w[o * 64 + tid], acc);
        out2[(size_t)n * 64 + tid] = acc;
    }
}

// ---------------------------------------------------------------------------
extern "C" void kernel_launch(void* const* d_in, const int* in_sizes, int n_in,
                              void* d_out, int out_size, void* d_ws, size_t ws_size,
                              hipStream_t stream) {
    (void)in_sizes; (void)n_in; (void)out_size; (void)ws_size;

    const float* x          = (const float*)d_in[0];
    const int*   node_tok   = (const int*)d_in[1];
    const int*   inc_node   = (const int*)d_in[2];
    const int*   inc_hedge  = (const int*)d_in[3];
    const int*   node2cell  = (const int*)d_in[4];
    const float* vac_emb    = (const float*)d_in[5];
    const float* fhi_w      = (const float*)d_in[6];
    const float* fhi_b      = (const float*)d_in[7];
    const float* fin_w      = (const float*)d_in[8];
    const float* fin_b      = (const float*)d_in[9];
    const float* th1        = (const float*)d_in[10];
    const float* b1         = (const float*)d_in[11];
    const float* th2        = (const float*)d_in[12];
    const float* b2         = (const float*)d_in[13];
    const float* fct_w      = (const float*)d_in[32];
    const float* fct_b      = (const float*)d_in[33];

    char* ws = (char*)d_ws;
    size_t off = 0;
    float* P        = (float*)(ws + off); off += (size_t)VOCAB * 64 * 4;
    float* nf       = (float*)(ws + off); off += (size_t)N_NODES * 64 * 4;
    float* hbuf     = (float*)(ws + off); off += (size_t)N_NODES * 64 * 4;
    u16*   xt       = (u16*)(ws + off);   off += (size_t)N_NODES * 64 * 2;
    u16*   he       = (u16*)(ws + off);   off += (size_t)N_HE * 64 * 2;
    float* x0       = (float*)(ws + off); off += (size_t)N_CELLS * 64 * 4;
    u16*   Bt_fhi   = (u16*)(ws + off);   off += (size_t)64 * D_IN * 2;
    u16*   Bt_fin   = (u16*)(ws + off);   off += (size_t)64 * D_IN * 2;
    u16*   Bt_th1   = (u16*)(ws + off);   off += (size_t)64 * 64 * 2;
    u16*   Bt_th2   = (u16*)(ws + off);   off += (size_t)64 * 64 * 2;
    int*   he_off   = (int*)(ws + off);   off += ((size_t)(N_HE + 1) * 4 + 255) / 256 * 256;
    int*   node_off = (int*)(ws + off);   off += ((size_t)(N_NODES + 1) * 4 + 255) / 256 * 256;
    int*   deg_v    = (int*)(ws + off);   off += (size_t)N_NODES * 4;
    int*   cursor   = (int*)(ws + off);   off += (size_t)N_NODES * 4;
    int*   csr      = (int*)(ws + off);   off += (size_t)N_INC * 4;
    int*   cell_off = (int*)(ws + off);   off += ((size_t)(N_CELLS + 1) * 4 + 255) / 256 * 256;
    int*   bsum     = (int*)(ws + off);   off += 1024 * 4;

    float* out1 = (float*)d_out;
    float* out2 = out1 + (size_t)I_ * J_ * D_H;

    // ---- CSR / offsets build ----
    hipMemsetAsync(deg_v, 0, 2 * (size_t)N_NODES * 4, stream);
    k_offsets<<<N_INC / 256, 256, 0, stream>>>(inc_hedge, N_INC, N_HE, he_off);
    k_offsets<<<N_NODES / 256, 256, 0, stream>>>(node2cell, N_NODES, N_CELLS, cell_off);
    k_hist<<<N_INC / 256, 256, 0, stream>>>(inc_node, N_INC, deg_v);
    k_scan1<<<N_NODES / 256, 256, 0, stream>>>(deg_v, N_NODES, node_off, bsum);
    k_scan2<<<1, 1024, 0, stream>>>(bsum, N_NODES / 256);
    k_scan3<<<N_NODES / 256, 256, 0, stream>>>(node_off, bsum, N_NODES, N_INC);
    k_csr_fill<<<N_INC / 256, 256, 0, stream>>>(inc_node, inc_hedge, N_INC, node_off, cursor, csr);

    // ---- weight convert+transpose (bf16) ----
    k_convT<<<(D_IN * 64 + 255) / 256, 256, 0, stream>>>(fhi_w, Bt_fhi, D_IN);
    k_convT<<<(D_IN * 64 + 255) / 256, 256, 0, stream>>>(fin_w, Bt_fin, D_IN);
    k_convT<<<(64 * 64 + 255) / 256, 256, 0, stream>>>(th1, Bt_th1, 64);
    k_convT<<<(64 * 64 + 255) / 256, 256, 0, stream>>>(th2, Bt_th2, 64);

    // ---- P = vac_emb @ fhi_w + fhi_b (MFMA) ; nf = P[tok] ----
    k_mfma_gemm<0><<<(VOCAB + 63) / 64, 256, 0, stream>>>(vac_emb, Bt_fhi, fhi_b, P, VOCAB, D_IN);
    k_gather_nf<<<(N_NODES * 16) / 256, 256, 0, stream>>>((const float4*)P, node_tok, (float4*)nf);

    // ---- hconv layer 1 ----
    k_mfma_gemm<1><<<N_NODES / 64, 256, 0, stream>>>(nf, Bt_th1, nullptr, xt, N_NODES, 64);
    k_hedge_sum<<<N_HE / 4, 256, 0, stream>>>(inc_node, he_off, xt, he);
    k_node_sum<<<N_NODES / 4, 256, 0, stream>>>(csr, node_off, he, b1, nf, hbuf);

    // ---- hconv layer 2 ----
    k_mfma_gemm<1><<<N_NODES / 64, 256, 0, stream>>>(hbuf, Bt_th2, nullptr, xt, N_NODES, 64);
    k_hedge_sum<<<N_HE / 4, 256, 0, stream>>>(inc_node, he_off, xt, he);
    k_node_sum<<<N_NODES / 4, 256, 0, stream>>>(csr, node_off, he, b2, nf, hbuf);

    // ---- x0 = x @ fin_w + fin_b (MFMA) ; pool + fuse ----
    k_mfma_gemm<0><<<(I_ * J_ + 63) / 64, 256, 0, stream>>>(x, Bt_fin, fin_b, x0, I_ * J_, D_IN);
    k_pool<<<N_CELLS, 256, 0, stream>>>(hbuf, cell_off, x0, out1);

    // ---- TCN ----
    k_tcn<<<I_, 256, 0, stream>>>(out1,
        (const float*)d_in[14], (const float*)d_in[15], (const float*)d_in[16],
        (const float*)d_in[17], (const float*)d_in[18], (const float*)d_in[19],
        (const float*)d_in[20], (const float*)d_in[21], (const float*)d_in[22],
        (const float*)d_in[23], (const float*)d_in[24], (const float*)d_in[25],
        (const float*)d_in[26], (const float*)d_in[27], (const float*)d_in[28],
        (const float*)d_in[29], (const float*)d_in[30], (const float*)d_in[31],
        fct_w, fct_b, out2);
}

// Round 4
// 837.996 us; speedup vs baseline: 1.6813x; 1.0375x over previous
//
#include <hip/hip_runtime.h>
#include <hip/hip_bf16.h>
#include <cstdint>
#include <cstddef>

#define I_      100
#define J_      8
#define D_IN    768
#define D_H     64
#define N_NODES 160000
#define N_HE    320000
#define N_INC   1600000
#define N_CELLS 800
#define VOCAB   30000

typedef unsigned short u16;
using short8 = __attribute__((ext_vector_type(8))) short;
using f32x4  = __attribute__((ext_vector_type(4))) float;

__device__ __forceinline__ float bf2f(u16 u) {
    union { uint32_t i; float f; } x; x.i = ((uint32_t)u) << 16; return x.f;
}
__device__ __forceinline__ u16 f2bf(float f) {
    union { float f; uint32_t i; } x; x.f = f;
    uint32_t b = x.i;
    b += 0x7FFFu + ((b >> 16) & 1u);   // round-to-nearest-even
    return (u16)(b >> 16);
}
__device__ __forceinline__ float lo_bf(uint32_t u) {
    union { uint32_t i; float f; } x; x.i = u << 16; return x.f;
}
__device__ __forceinline__ float hi_bf(uint32_t u) {
    union { uint32_t i; float f; } x; x.i = u & 0xFFFF0000u; return x.f;
}

// grid-partition constants
#define G_OFF_HE   (N_INC / 256)     // 6250
#define G_OFF_CELL (N_NODES / 256)   // 625
#define G_HIST     (N_INC / 256)     // 6250
#define G_CONV_BIG ((D_IN * 64) / 256)  // 192
#define G_CONV_SM  ((64 * 64) / 256)    // 16
#define G_SCAN     (N_NODES / 256)   // 625
#define G_PGEMM    ((VOCAB + 63) / 64)   // 469
#define G_GATHER   ((N_NODES * 16) / 256) // 10000
#define G_XTGEMM   (N_NODES / 64)    // 2500
#define G_X0GEMM   ((I_ * J_ + 63) / 64) // 13
#define G_CSR      (N_INC / 256)     // 6250
#define G_HEDGE    (N_HE / 4)        // 80000
#define G_NODE     (N_NODES / 4)     // 40000

// ---------------------------------------------------------------------------
// device pieces
// ---------------------------------------------------------------------------
__device__ __forceinline__ void dev_offsets(int bid, const int* __restrict__ sorted,
                                            int n, int nbins, int* __restrict__ off) {
    int i = bid * 256 + threadIdx.x;
    if (i >= n) return;
    int cur = sorted[i];
    int prev = (i == 0) ? -1 : sorted[i - 1];
    for (int b = prev + 1; b <= cur; ++b) off[b] = i;
    if (i == n - 1) {
        for (int b = cur + 1; b <= nbins; ++b) off[b] = n;
    }
}

__device__ __forceinline__ void dev_hist(int bid, const int* __restrict__ idx, int n,
                                         int* __restrict__ deg) {
    int i = bid * 256 + threadIdx.x;
    if (i < n) atomicAdd(&deg[idx[i]], 1);
}

__device__ __forceinline__ void dev_convT(int bid, const float* __restrict__ B,
                                          u16* __restrict__ Bt, int K) {
    int g = bid * 256 + threadIdx.x;
    if (g >= K * 64) return;
    int k = g >> 6, n = g & 63;
    Bt[(size_t)n * K + k] = f2bf(B[g]);
}

__device__ __forceinline__ void dev_scan1(int bid, int* __restrict__ s,
                                          const int* __restrict__ deg, int n,
                                          int* __restrict__ off, int* __restrict__ bsum) {
    int tid = threadIdx.x;
    int i = bid * 256 + tid;
    int v = (i < n) ? deg[i] : 0;
    s[tid] = v;
    __syncthreads();
    #pragma unroll
    for (int d = 1; d < 256; d <<= 1) {
        int t = (tid >= d) ? s[tid - d] : 0;
        __syncthreads();
        s[tid] += t;
        __syncthreads();
    }
    if (i < n) off[i] = s[tid] - v;
    if (tid == 255) bsum[bid] = s[255];
}

// one-wave exclusive scan over n (<= 64*16) elements
__device__ __forceinline__ void dev_scan2_wave(int* __restrict__ bsum, int n) {
    int lane = threadIdx.x;
    if (lane >= 64) return;
    const int CH = (n + 63) / 64;
    int base = lane * CH;
    int v[16];
    int cnt = n - base;
    if (cnt < 0) cnt = 0;
    if (cnt > CH) cnt = CH;
    int sum = 0;
    for (int k = 0; k < cnt; ++k) { v[k] = bsum[base + k]; sum += v[k]; }
    int inc = sum;
    #pragma unroll
    for (int d = 1; d < 64; d <<= 1) {
        int t = __shfl_up(inc, d, 64);
        if (lane >= d) inc += t;
    }
    int run = inc - sum;
    for (int k = 0; k < cnt; ++k) { int t = v[k]; bsum[base + k] = run; run += t; }
}

__device__ __forceinline__ void dev_scan3(int bid, int* __restrict__ off,
                                          const int* __restrict__ bsum, int n, int total) {
    int i = bid * 256 + threadIdx.x;
    if (i < n) off[i] += bsum[bid];
    if (i == 0) off[n] = total;
}

__device__ __forceinline__ void dev_csr_fill(int bid, const int* __restrict__ inc_node,
                                             const int* __restrict__ inc_hedge, int n,
                                             const int* __restrict__ node_off,
                                             int* __restrict__ cursor, int* __restrict__ csr) {
    int i = bid * 256 + threadIdx.x;
    if (i >= n) return;
    int v = inc_node[i];
    int p = node_off[v] + atomicAdd(&cursor[v], 1);
    csr[p] = inc_hedge[i];
}

__device__ __forceinline__ void dev_gather_nf(int bid, const float4* __restrict__ P,
                                              const int* __restrict__ tok,
                                              float4* __restrict__ nf) {
    int g = bid * 256 + threadIdx.x;
    if (g >= N_NODES * 16) return;
    int n = g >> 4, p = g & 15;
    nf[g] = P[((size_t)tok[n] << 4) + p];
}

// MFMA GEMM: C[M,64] = A[M,K](f32->bf16) @ Bt[64,K](bf16) (+bias for f32 out)
template <int BF16_OUT>
__device__ __forceinline__ void dev_mfma_gemm(int bid, char* smem,
                                              const float* __restrict__ A,
                                              const u16* __restrict__ Bt,
                                              const float* __restrict__ bias,
                                              void* __restrict__ C, int M, int K) {
    u16* Alds = (u16*)smem;          // 64 rows x 32 k, padded to 40
    int tid = threadIdx.x;
    int wave = tid >> 6, lane = tid & 63;
    int m16 = lane & 15, q = lane >> 4;
    int row0 = bid << 6;

    f32x4 acc0 = {0.f, 0.f, 0.f, 0.f};
    f32x4 acc1 = {0.f, 0.f, 0.f, 0.f};
    f32x4 acc2 = {0.f, 0.f, 0.f, 0.f};
    f32x4 acc3 = {0.f, 0.f, 0.f, 0.f};

    for (int kt = 0; kt < K; kt += 32) {
        #pragma unroll
        for (int it = 0; it < 2; ++it) {
            int l = tid + it * 256;
            int r = l >> 3, c4 = (l & 7) << 2;
            int gr = row0 + r;
            float4 av = make_float4(0.f, 0.f, 0.f, 0.f);
            if (gr < M)
                av = *reinterpret_cast<const float4*>(A + (size_t)gr * K + kt + c4);
            ushort4 u;
            u.x = f2bf(av.x); u.y = f2bf(av.y); u.z = f2bf(av.z); u.w = f2bf(av.w);
            *reinterpret_cast<ushort4*>(&Alds[r * 40 + c4]) = u;
        }
        __syncthreads();

        short8 a = *reinterpret_cast<const short8*>(&Alds[(wave * 16 + m16) * 40 + q * 8]);
        const u16* bp = Bt + (size_t)m16 * K + kt + q * 8;
        short8 b0 = *reinterpret_cast<const short8*>(bp);
        short8 b1 = *reinterpret_cast<const short8*>(bp + (size_t)16 * K);
        short8 b2 = *reinterpret_cast<const short8*>(bp + (size_t)32 * K);
        short8 b3 = *reinterpret_cast<const short8*>(bp + (size_t)48 * K);

        acc0 = __builtin_amdgcn_mfma_f32_16x16x32_bf16(a, b0, acc0, 0, 0, 0);
        acc1 = __builtin_amdgcn_mfma_f32_16x16x32_bf16(a, b1, acc1, 0, 0, 0);
        acc2 = __builtin_amdgcn_mfma_f32_16x16x32_bf16(a, b2, acc2, 0, 0, 0);
        acc3 = __builtin_amdgcn_mfma_f32_16x16x32_bf16(a, b3, acc3, 0, 0, 0);
        __syncthreads();
    }

    f32x4 accs[4] = {acc0, acc1, acc2, acc3};
    #pragma unroll
    for (int r = 0; r < 4; ++r) {
        int gr = row0 + wave * 16 + q * 4 + r;
        if (gr >= M) continue;
        #pragma unroll
        for (int j = 0; j < 4; ++j) {
            int col = j * 16 + m16;
            float v = accs[j][r];
            if (!BF16_OUT) v += bias[col];
            if (BF16_OUT)
                ((u16*)C)[(size_t)gr * 64 + col] = f2bf(v);
            else
                ((float*)C)[(size_t)gr * 64 + col] = v;
        }
    }
}

// he[e] = (1/deg_e) * sum xt[inc_node[j]]  -- 4x16 sub-group gather
__device__ __forceinline__ void dev_hedge_sum(int bid, const int* __restrict__ inc_node,
                                              const int* __restrict__ he_off,
                                              const u16* __restrict__ xt,
                                              u16* __restrict__ he) {
    int w = (bid * 256 + (int)threadIdx.x) >> 6;
    int lane = threadIdx.x & 63;
    if (w >= N_HE) return;
    int sub = lane >> 4;
    int col4 = (lane & 15) << 2;
    int s = he_off[w], e = he_off[w + 1];

    float a0 = 0.f, a1 = 0.f, a2 = 0.f, a3 = 0.f;

    int jj = s + sub;
    int idx = (jj < e) ? inc_node[jj] : -1;
    for (int j0 = s; j0 < e; j0 += 4) {
        int cur = idx;
        int jn = j0 + 4 + sub;
        idx = (jn < e) ? inc_node[jn] : -1;
        if (cur >= 0) {
            uint2 d = *reinterpret_cast<const uint2*>(xt + (((size_t)cur) << 6) + col4);
            a0 += lo_bf(d.x); a1 += hi_bf(d.x);
            a2 += lo_bf(d.y); a3 += hi_bf(d.y);
        }
    }
    a0 += __shfl_xor(a0, 16, 64); a1 += __shfl_xor(a1, 16, 64);
    a2 += __shfl_xor(a2, 16, 64); a3 += __shfl_xor(a3, 16, 64);
    a0 += __shfl_xor(a0, 32, 64); a1 += __shfl_xor(a1, 32, 64);
    a2 += __shfl_xor(a2, 32, 64); a3 += __shfl_xor(a3, 32, 64);

    if (sub == 0) {
        float inv = (e > s) ? 1.f / (float)(e - s) : 0.f;
        uint2 o;
        o.x = (uint32_t)f2bf(a0 * inv) | ((uint32_t)f2bf(a1 * inv) << 16);
        o.y = (uint32_t)f2bf(a2 * inv) | ((uint32_t)f2bf(a3 * inv) << 16);
        *reinterpret_cast<uint2*>(he + (((size_t)w) << 6) + col4) = o;
    }
}

// ---------------------------------------------------------------------------
// phase mega-kernels (block-range dispatch; roles are mutually independent)
// ---------------------------------------------------------------------------
__global__ __launch_bounds__(256) void k_p1(const int* __restrict__ inc_hedge,
                                            const int* __restrict__ node2cell,
                                            const int* __restrict__ inc_node,
                                            int* __restrict__ he_off, int* __restrict__ cell_off,
                                            int* __restrict__ deg_v,
                                            const float* __restrict__ fhi_w, const float* __restrict__ fin_w,
                                            const float* __restrict__ th1, const float* __restrict__ th2,
                                            u16* __restrict__ Bt_fhi, u16* __restrict__ Bt_fin,
                                            u16* __restrict__ Bt_th1, u16* __restrict__ Bt_th2) {
    int bid = blockIdx.x;
    if (bid < G_OFF_HE) { dev_offsets(bid, inc_hedge, N_INC, N_HE, he_off); return; }
    bid -= G_OFF_HE;
    if (bid < G_OFF_CELL) { dev_offsets(bid, node2cell, N_NODES, N_CELLS, cell_off); return; }
    bid -= G_OFF_CELL;
    if (bid < G_HIST) { dev_hist(bid, inc_node, N_INC, deg_v); return; }
    bid -= G_HIST;
    if (bid < G_CONV_BIG) { dev_convT(bid, fhi_w, Bt_fhi, D_IN); return; }
    bid -= G_CONV_BIG;
    if (bid < G_CONV_BIG) { dev_convT(bid, fin_w, Bt_fin, D_IN); return; }
    bid -= G_CONV_BIG;
    if (bid < G_CONV_SM) { dev_convT(bid, th1, Bt_th1, 64); return; }
    bid -= G_CONV_SM;
    dev_convT(bid, th2, Bt_th2, 64);
}

__global__ __launch_bounds__(256) void k_p2(const int* __restrict__ deg_v,
                                            int* __restrict__ node_off, int* __restrict__ bsum,
                                            const float* __restrict__ vac_emb,
                                            const u16* __restrict__ Bt_fhi,
                                            const float* __restrict__ fhi_b, float* __restrict__ P) {
    __shared__ __align__(16) char smem[64 * 40 * 2];
    int bid = blockIdx.x;
    if (bid < G_SCAN) { dev_scan1(bid, (int*)smem, deg_v, N_NODES, node_off, bsum); return; }
    bid -= G_SCAN;
    dev_mfma_gemm<0>(bid, smem, vac_emb, Bt_fhi, fhi_b, P, VOCAB, D_IN);
}

__global__ __launch_bounds__(256) void k_p3(int* __restrict__ bsum,
                                            const float4* __restrict__ P,
                                            const int* __restrict__ tok, float4* __restrict__ nf) {
    int bid = blockIdx.x;
    if (bid == 0) { dev_scan2_wave(bsum, G_SCAN); return; }
    bid -= 1;
    dev_gather_nf(bid, P, tok, nf);
}

__global__ __launch_bounds__(256) void k_p4(int* __restrict__ node_off, const int* __restrict__ bsum,
                                            const float* __restrict__ nf, const u16* __restrict__ Bt_th1,
                                            u16* __restrict__ xt,
                                            const float* __restrict__ x, const u16* __restrict__ Bt_fin,
                                            const float* __restrict__ fin_b, float* __restrict__ x0) {
    __shared__ __align__(16) char smem[64 * 40 * 2];
    int bid = blockIdx.x;
    if (bid < G_SCAN) { dev_scan3(bid, node_off, bsum, N_NODES, N_INC); return; }
    bid -= G_SCAN;
    if (bid < G_XTGEMM) { dev_mfma_gemm<1>(bid, smem, nf, Bt_th1, nullptr, xt, N_NODES, 64); return; }
    bid -= G_XTGEMM;
    dev_mfma_gemm<0>(bid, smem, x, Bt_fin, fin_b, x0, I_ * J_, D_IN);
}

__global__ __launch_bounds__(256) void k_p5(const int* __restrict__ inc_node,
                                            const int* __restrict__ inc_hedge,
                                            const int* __restrict__ node_off,
                                            int* __restrict__ cursor, int* __restrict__ csr,
                                            const int* __restrict__ he_off,
                                            const u16* __restrict__ xt, u16* __restrict__ he) {
    int bid = blockIdx.x;
    if (bid < G_CSR) { dev_csr_fill(bid, inc_node, inc_hedge, N_INC, node_off, cursor, csr); return; }
    bid -= G_CSR;
    dev_hedge_sum(bid, inc_node, he_off, xt, he);
}

// standalone wrappers
template <int BF16_OUT>
__global__ __launch_bounds__(256) void k_mfma_gemm(const float* __restrict__ A,
                                                   const u16* __restrict__ Bt,
                                                   const float* __restrict__ bias,
                                                   void* __restrict__ C, int M, int K) {
    __shared__ __align__(16) char smem[64 * 40 * 2];
    dev_mfma_gemm<BF16_OUT>(blockIdx.x, smem, A, Bt, bias, C, M, K);
}

__global__ __launch_bounds__(256) void k_hedge_sum(const int* __restrict__ inc_node,
                                                   const int* __restrict__ he_off,
                                                   const u16* __restrict__ xt,
                                                   u16* __restrict__ he) {
    dev_hedge_sum(blockIdx.x, inc_node, he_off, xt, he);
}

// out[v] = relu((1/deg_v) * sum he[csr[j]] + bias) + nf[v]  -- 4x16 version
__global__ __launch_bounds__(256) void k_node_sum(const int* __restrict__ csr,
                                                  const int* __restrict__ node_off,
                                                  const u16* __restrict__ he,
                                                  const float* __restrict__ bias,
                                                  const float* __restrict__ nf,
                                                  float* __restrict__ out) {
    int w = (blockIdx.x * 256 + threadIdx.x) >> 6;
    int lane = threadIdx.x & 63;
    if (w >= N_NODES) return;
    int sub = lane >> 4;
    int col4 = (lane & 15) << 2;
    int s = node_off[w], e = node_off[w + 1];

    float a0 = 0.f, a1 = 0.f, a2 = 0.f, a3 = 0.f;

    int jj = s + sub;
    int idx = (jj < e) ? csr[jj] : -1;
    for (int j0 = s; j0 < e; j0 += 4) {
        int cur = idx;
        int jn = j0 + 4 + sub;
        idx = (jn < e) ? csr[jn] : -1;
        if (cur >= 0) {
            uint2 d = *reinterpret_cast<const uint2*>(he + (((size_t)cur) << 6) + col4);
            a0 += lo_bf(d.x); a1 += hi_bf(d.x);
            a2 += lo_bf(d.y); a3 += hi_bf(d.y);
        }
    }
    a0 += __shfl_xor(a0, 16, 64); a1 += __shfl_xor(a1, 16, 64);
    a2 += __shfl_xor(a2, 16, 64); a3 += __shfl_xor(a3, 16, 64);
    a0 += __shfl_xor(a0, 32, 64); a1 += __shfl_xor(a1, 32, 64);
    a2 += __shfl_xor(a2, 32, 64); a3 += __shfl_xor(a3, 32, 64);

    if (sub == 0) {
        float inv = (e > s) ? 1.f / (float)(e - s) : 0.f;
        float4 nv = *reinterpret_cast<const float4*>(nf + (((size_t)w) << 6) + col4);
        float4 o;
        o.x = fmaxf(fmaf(a0, inv, bias[col4 + 0]), 0.f) + nv.x;
        o.y = fmaxf(fmaf(a1, inv, bias[col4 + 1]), 0.f) + nv.y;
        o.z = fmaxf(fmaf(a2, inv, bias[col4 + 2]), 0.f) + nv.z;
        o.w = fmaxf(fmaf(a3, inv, bias[col4 + 3]), 0.f) + nv.w;
        *reinterpret_cast<float4*>(out + (((size_t)w) << 6) + col4) = o;
    }
}

// ---------------------------------------------------------------------------
// per-cell mean+max pooling, fused x_upd = x0 + 0.3*cell_emb
// ---------------------------------------------------------------------------
__global__ __launch_bounds__(256) void k_pool(const float* __restrict__ gx,
                                              const int* __restrict__ cell_off,
                                              const float* __restrict__ x0,
                                              float* __restrict__ out1) {
    __shared__ float ssum[4][64];
    __shared__ float smax[4][64];
    int c = blockIdx.x;
    int lane = threadIdx.x & 63;
    int w = threadIdx.x >> 6;
    int s = cell_off[c], e = cell_off[c + 1];
    float sum = 0.f, mx = -INFINITY;
    for (int n = s + w; n < e; n += 4) {
        float v = gx[((size_t)n << 6) + lane];
        sum += v;
        mx = fmaxf(mx, v);
    }
    ssum[w][lane] = sum;
    smax[w][lane] = mx;
    __syncthreads();
    if (w == 0) {
        sum = ssum[0][lane] + ssum[1][lane] + ssum[2][lane] + ssum[3][lane];
        mx = fmaxf(fmaxf(smax[0][lane], smax[1][lane]), fmaxf(smax[2][lane], smax[3][lane]));
        int cnt = e - s;
        float mean = (cnt > 0) ? sum / (float)cnt : 0.f;
        float mp = (cnt > 0) ? mx : 0.f;
        float ce = 0.5f * (mean + mp);
        out1[((size_t)c << 6) + lane] = x0[((size_t)c << 6) + lane] + 0.3f * ce;
    }
}

// ---------------------------------------------------------------------------
// fused TCN
// ---------------------------------------------------------------------------
__global__ __launch_bounds__(256) void k_tcn(
    const float* __restrict__ xu,
    const float* __restrict__ wc1, const float* __restrict__ bc1, const float* __restrict__ g1,
    const float* __restrict__ be1, const float* __restrict__ m1, const float* __restrict__ v1,
    const float* __restrict__ wc2, const float* __restrict__ bc2, const float* __restrict__ g2,
    const float* __restrict__ be2, const float* __restrict__ m2, const float* __restrict__ v2,
    const float* __restrict__ wc3, const float* __restrict__ bc3, const float* __restrict__ g3,
    const float* __restrict__ be3, const float* __restrict__ m3, const float* __restrict__ v3,
    const float* __restrict__ fct_w, const float* __restrict__ fct_b,
    float* __restrict__ out2) {
    __shared__ float w_lds[64 * 64 * 3];
    __shared__ float hA[64][10];
    __shared__ float hB[64][10];
    __shared__ float mo[64];

    int n = blockIdx.x, tid = threadIdx.x;

    if (tid < 64) {
        hA[tid][0] = 0.f; hA[tid][9] = 0.f;
        hB[tid][0] = 0.f; hB[tid][9] = 0.f;
    }
    #pragma unroll
    for (int l = tid; l < 512; l += 256) {
        int t = l >> 6, i = l & 63;
        hA[i][t + 1] = xu[(size_t)n * 512 + l];
    }

    const float* wcs[3] = {wc1, wc2, wc3};
    const float* bcs[3] = {bc1, bc2, bc3};
    const float* gs[3]  = {g1, g2, g3};
    const float* bes[3] = {be1, be2, be3};
    const float* ms[3]  = {m1, m2, m3};
    const float* vs[3]  = {v1, v2, v3};

    float (*hin)[10] = hA;
    float (*hout)[10] = hB;

    #pragma unroll
    for (int li = 0; li < 3; ++li) {
        for (int l = tid; l < 64 * 64 * 3; l += 256) w_lds[l] = wcs[li][l];
        __syncthreads();
        #pragma unroll
        for (int rep = 0; rep < 2; ++rep) {
            int idx = tid + rep * 256;
            int o = idx >> 3, t = idx & 7;
            float acc = bcs[li][o];
            #pragma unroll 8
            for (int i = 0; i < 64; ++i) {
                const float* wr = &w_lds[o * 192 + i * 3];
                acc = fmaf(hin[i][t + 0], wr[0], acc);
                acc = fmaf(hin[i][t + 1], wr[1], acc);
                acc = fmaf(hin[i][t + 2], wr[2], acc);
            }
            acc = fmaxf(acc, 0.f);
            float sc = gs[li][o] * rsqrtf(vs[li][o] + 1e-5f);
            acc = (acc - ms[li][o]) * sc + bes[li][o];
            hout[o][t + 1] = acc;
        }
        __syncthreads();
        float (*tmp)[10] = hin; hin = hout; hout = tmp;
    }

    if (tid < 64) {
        float s = 0.f;
        #pragma unroll
        for (int t = 0; t < 8; ++t) s += hin[tid][t + 1];
        mo[tid] = s * 0.125f;
    }
    __syncthreads();
    if (tid < 64) {
        float acc = fct_b[tid];
        #pragma unroll 8
        for (int o = 0; o < 64; ++o) acc = fmaf(mo[o], fct_w[o * 64 + tid], acc);
        out2[(size_t)n * 64 + tid] = acc;
    }
}

// ---------------------------------------------------------------------------
extern "C" void kernel_launch(void* const* d_in, const int* in_sizes, int n_in,
                              void* d_out, int out_size, void* d_ws, size_t ws_size,
                              hipStream_t stream) {
    (void)in_sizes; (void)n_in; (void)out_size; (void)ws_size;

    const float* x          = (const float*)d_in[0];
    const int*   node_tok   = (const int*)d_in[1];
    const int*   inc_node   = (const int*)d_in[2];
    const int*   inc_hedge  = (const int*)d_in[3];
    const int*   node2cell  = (const int*)d_in[4];
    const float* vac_emb    = (const float*)d_in[5];
    const float* fhi_w      = (const float*)d_in[6];
    const float* fhi_b      = (const float*)d_in[7];
    const float* fin_w      = (const float*)d_in[8];
    const float* fin_b      = (const float*)d_in[9];
    const float* th1        = (const float*)d_in[10];
    const float* b1         = (const float*)d_in[11];
    const float* th2        = (const float*)d_in[12];
    const float* b2         = (const float*)d_in[13];
    const float* fct_w      = (const float*)d_in[32];
    const float* fct_b      = (const float*)d_in[33];

    char* ws = (char*)d_ws;
    size_t off = 0;
    float* P        = (float*)(ws + off); off += (size_t)VOCAB * 64 * 4;
    float* nf       = (float*)(ws + off); off += (size_t)N_NODES * 64 * 4;
    float* hbuf     = (float*)(ws + off); off += (size_t)N_NODES * 64 * 4;
    u16*   xt       = (u16*)(ws + off);   off += (size_t)N_NODES * 64 * 2;
    u16*   he       = (u16*)(ws + off);   off += (size_t)N_HE * 64 * 2;
    float* x0       = (float*)(ws + off); off += (size_t)N_CELLS * 64 * 4;
    u16*   Bt_fhi   = (u16*)(ws + off);   off += (size_t)64 * D_IN * 2;
    u16*   Bt_fin   = (u16*)(ws + off);   off += (size_t)64 * D_IN * 2;
    u16*   Bt_th1   = (u16*)(ws + off);   off += (size_t)64 * 64 * 2;
    u16*   Bt_th2   = (u16*)(ws + off);   off += (size_t)64 * 64 * 2;
    int*   he_off   = (int*)(ws + off);   off += ((size_t)(N_HE + 1) * 4 + 255) / 256 * 256;
    int*   node_off = (int*)(ws + off);   off += ((size_t)(N_NODES + 1) * 4 + 255) / 256 * 256;
    int*   deg_v    = (int*)(ws + off);   off += (size_t)N_NODES * 4;
    int*   cursor   = (int*)(ws + off);   off += (size_t)N_NODES * 4;
    int*   csr      = (int*)(ws + off);   off += (size_t)N_INC * 4;
    int*   cell_off = (int*)(ws + off);   off += ((size_t)(N_CELLS + 1) * 4 + 255) / 256 * 256;
    int*   bsum     = (int*)(ws + off);   off += 1024 * 4;

    float* out1 = (float*)d_out;
    float* out2 = out1 + (size_t)I_ * J_ * D_H;

    // deg_v and cursor are adjacent -> single memset
    hipMemsetAsync(deg_v, 0, 2 * (size_t)N_NODES * 4, stream);

    // P1: offsets(hedge) + offsets(cell) + hist + 4x convT
    k_p1<<<G_OFF_HE + G_OFF_CELL + G_HIST + 2 * G_CONV_BIG + 2 * G_CONV_SM, 256, 0, stream>>>(
        inc_hedge, node2cell, inc_node, he_off, cell_off, deg_v,
        fhi_w, fin_w, th1, th2, Bt_fhi, Bt_fin, Bt_th1, Bt_th2);

    // P2: scan1 + P-GEMM
    k_p2<<<G_SCAN + G_PGEMM, 256, 0, stream>>>(deg_v, node_off, bsum, vac_emb, Bt_fhi, fhi_b, P);

    // P3: scan2 + gather_nf
    k_p3<<<1 + G_GATHER, 256, 0, stream>>>(bsum, (const float4*)P, node_tok, (float4*)nf);

    // P4: scan3 + xt-GEMM L1 + x0-GEMM
    k_p4<<<G_SCAN + G_XTGEMM + G_X0GEMM, 256, 0, stream>>>(node_off, bsum, nf, Bt_th1, xt,
                                                           x, Bt_fin, fin_b, x0);

    // P5: csr_fill + hedge_sum L1
    k_p5<<<G_CSR + G_HEDGE, 256, 0, stream>>>(inc_node, inc_hedge, node_off, cursor, csr,
                                              he_off, xt, he);

    // P6: node_sum L1 -> hbuf = h1
    k_node_sum<<<G_NODE, 256, 0, stream>>>(csr, node_off, he, b1, nf, hbuf);

    // P7: xt-GEMM L2
    k_mfma_gemm<1><<<G_XTGEMM, 256, 0, stream>>>(hbuf, Bt_th2, nullptr, xt, N_NODES, 64);

    // P8: hedge_sum L2
    k_hedge_sum<<<G_HEDGE, 256, 0, stream>>>(inc_node, he_off, xt, he);

    // P9: node_sum L2 -> hbuf = gx
    k_node_sum<<<G_NODE, 256, 0, stream>>>(csr, node_off, he, b2, nf, hbuf);

    // P10: pool + fuse -> out1
    k_pool<<<N_CELLS, 256, 0, stream>>>(hbuf, cell_off, x0, out1);

    // P11: TCN -> out2
    k_tcn<<<I_, 256, 0, stream>>>(out1,
        (const float*)d_in[14], (const float*)d_in[15], (const float*)d_in[16],
        (const float*)d_in[17], (const float*)d_in[18], (const float*)d_in[19],
        (const float*)d_in[20], (const float*)d_in[21], (const float*)d_in[22],
        (const float*)d_in[23], (const float*)d_in[24], (const float*)d_in[25],
        (const float*)d_in[26], (const float*)d_in[27], (const float*)d_in[28],
        (const float*)d_in[29], (const float*)d_in[30], (const float*)d_in[31],
        fct_w, fct_b, out2);
}

// Round 5
// 821.218 us; speedup vs baseline: 1.7156x; 1.0204x over previous
//
#include <hip/hip_runtime.h>
#include <hip/hip_bf16.h>
#include <cstdint>
#include <cstddef>

#define I_      100
#define J_      8
#define D_IN    768
#define D_H     64
#define N_NODES 160000
#define N_HE    320000
#define N_INC   1600000
#define N_CELLS 800
#define VOCAB   30000

typedef unsigned short u16;
using short8 = __attribute__((ext_vector_type(8))) short;
using f32x4  = __attribute__((ext_vector_type(4))) float;

__device__ __forceinline__ float bf2f(u16 u) {
    union { uint32_t i; float f; } x; x.i = ((uint32_t)u) << 16; return x.f;
}
__device__ __forceinline__ u16 f2bf(float f) {
    union { float f; uint32_t i; } x; x.f = f;
    uint32_t b = x.i;
    b += 0x7FFFu + ((b >> 16) & 1u);   // round-to-nearest-even
    return (u16)(b >> 16);
}
__device__ __forceinline__ float lo_bf(uint32_t u) {
    union { uint32_t i; float f; } x; x.i = u << 16; return x.f;
}
__device__ __forceinline__ float hi_bf(uint32_t u) {
    union { uint32_t i; float f; } x; x.i = u & 0xFFFF0000u; return x.f;
}
__device__ __forceinline__ uint32_t pack_bf2(float a, float b) {
    return (uint32_t)f2bf(a) | ((uint32_t)f2bf(b) << 16);
}

// grid-partition constants
#define G_OFF_HE   (N_INC / 256)     // 6250
#define G_OFF_CELL (N_NODES / 256)   // 625
#define G_HIST     (N_INC / 256)     // 6250
#define G_CONV_BIG ((D_IN * 64) / 256)  // 192
#define G_CONV_SM  ((64 * 64) / 256)    // 16
#define G_SCAN     (N_NODES / 256)   // 625
#define G_PGEMM    ((VOCAB + 63) / 64)   // 469
#define G_GATHER   ((N_NODES * 16) / 256) // 10000
#define G_XTGEMM   (N_NODES / 64)    // 2500
#define G_X0GEMM   ((I_ * J_ + 63) / 64) // 13
#define G_CSR      (N_INC / 256)     // 6250
#define G_HEDGE    (N_HE / 4)        // 80000
#define G_NODE     (N_NODES / 4)     // 40000

// ---------------------------------------------------------------------------
// device pieces
// ---------------------------------------------------------------------------
__device__ __forceinline__ void dev_offsets(int bid, const int* __restrict__ sorted,
                                            int n, int nbins, int* __restrict__ off) {
    int i = bid * 256 + threadIdx.x;
    if (i >= n) return;
    int cur = sorted[i];
    int prev = (i == 0) ? -1 : sorted[i - 1];
    for (int b = prev + 1; b <= cur; ++b) off[b] = i;
    if (i == n - 1) {
        for (int b = cur + 1; b <= nbins; ++b) off[b] = n;
    }
}

__device__ __forceinline__ void dev_hist(int bid, const int* __restrict__ idx, int n,
                                         int* __restrict__ deg) {
    int i = bid * 256 + threadIdx.x;
    if (i < n) atomicAdd(&deg[idx[i]], 1);
}

__device__ __forceinline__ void dev_convT(int bid, const float* __restrict__ B,
                                          u16* __restrict__ Bt, int K) {
    int g = bid * 256 + threadIdx.x;
    if (g >= K * 64) return;
    int k = g >> 6, n = g & 63;
    Bt[(size_t)n * K + k] = f2bf(B[g]);
}

__device__ __forceinline__ void dev_scan1(int bid, int* __restrict__ s,
                                          const int* __restrict__ deg, int n,
                                          int* __restrict__ off, int* __restrict__ bsum) {
    int tid = threadIdx.x;
    int i = bid * 256 + tid;
    int v = (i < n) ? deg[i] : 0;
    s[tid] = v;
    __syncthreads();
    #pragma unroll
    for (int d = 1; d < 256; d <<= 1) {
        int t = (tid >= d) ? s[tid - d] : 0;
        __syncthreads();
        s[tid] += t;
        __syncthreads();
    }
    if (i < n) off[i] = s[tid] - v;
    if (tid == 255) bsum[bid] = s[255];
}

// one-wave exclusive scan over n (<= 64*16) elements
__device__ __forceinline__ void dev_scan2_wave(int* __restrict__ bsum, int n) {
    int lane = threadIdx.x;
    if (lane >= 64) return;
    const int CH = (n + 63) / 64;
    int base = lane * CH;
    int v[16];
    int cnt = n - base;
    if (cnt < 0) cnt = 0;
    if (cnt > CH) cnt = CH;
    int sum = 0;
    for (int k = 0; k < cnt; ++k) { v[k] = bsum[base + k]; sum += v[k]; }
    int inc = sum;
    #pragma unroll
    for (int d = 1; d < 64; d <<= 1) {
        int t = __shfl_up(inc, d, 64);
        if (lane >= d) inc += t;
    }
    int run = inc - sum;
    for (int k = 0; k < cnt; ++k) { int t = v[k]; bsum[base + k] = run; run += t; }
}

__device__ __forceinline__ void dev_scan3(int bid, int* __restrict__ off,
                                          const int* __restrict__ bsum, int n, int total) {
    int i = bid * 256 + threadIdx.x;
    if (i < n) off[i] += bsum[bid];
    if (i == 0) off[n] = total;
}

__device__ __forceinline__ void dev_csr_fill(int bid, const int* __restrict__ inc_node,
                                             const int* __restrict__ inc_hedge, int n,
                                             const int* __restrict__ node_off,
                                             int* __restrict__ cursor, int* __restrict__ csr) {
    int i = bid * 256 + threadIdx.x;
    if (i >= n) return;
    int v = inc_node[i];
    int p = node_off[v] + atomicAdd(&cursor[v], 1);
    csr[p] = inc_hedge[i];
}

__device__ __forceinline__ void dev_gather_nf(int bid, const float4* __restrict__ P,
                                              const int* __restrict__ tok,
                                              float4* __restrict__ nf) {
    int g = bid * 256 + threadIdx.x;
    if (g >= N_NODES * 16) return;
    int n = g >> 4, p = g & 15;
    nf[g] = P[((size_t)tok[n] << 4) + p];
}

// MFMA GEMM: C[M,64] = A[M,K](f32->bf16) @ Bt[64,K](bf16) (+bias for f32 out)
template <int BF16_OUT>
__device__ __forceinline__ void dev_mfma_gemm(int bid, char* smem,
                                              const float* __restrict__ A,
                                              const u16* __restrict__ Bt,
                                              const float* __restrict__ bias,
                                              void* __restrict__ C, int M, int K) {
    u16* Alds = (u16*)smem;          // 64 rows x 32 k, padded to 40
    int tid = threadIdx.x;
    int wave = tid >> 6, lane = tid & 63;
    int m16 = lane & 15, q = lane >> 4;
    int row0 = bid << 6;

    f32x4 acc0 = {0.f, 0.f, 0.f, 0.f};
    f32x4 acc1 = {0.f, 0.f, 0.f, 0.f};
    f32x4 acc2 = {0.f, 0.f, 0.f, 0.f};
    f32x4 acc3 = {0.f, 0.f, 0.f, 0.f};

    for (int kt = 0; kt < K; kt += 32) {
        #pragma unroll
        for (int it = 0; it < 2; ++it) {
            int l = tid + it * 256;
            int r = l >> 3, c4 = (l & 7) << 2;
            int gr = row0 + r;
            float4 av = make_float4(0.f, 0.f, 0.f, 0.f);
            if (gr < M)
                av = *reinterpret_cast<const float4*>(A + (size_t)gr * K + kt + c4);
            ushort4 u;
            u.x = f2bf(av.x); u.y = f2bf(av.y); u.z = f2bf(av.z); u.w = f2bf(av.w);
            *reinterpret_cast<ushort4*>(&Alds[r * 40 + c4]) = u;
        }
        __syncthreads();

        short8 a = *reinterpret_cast<const short8*>(&Alds[(wave * 16 + m16) * 40 + q * 8]);
        const u16* bp = Bt + (size_t)m16 * K + kt + q * 8;
        short8 b0 = *reinterpret_cast<const short8*>(bp);
        short8 b1 = *reinterpret_cast<const short8*>(bp + (size_t)16 * K);
        short8 b2 = *reinterpret_cast<const short8*>(bp + (size_t)32 * K);
        short8 b3 = *reinterpret_cast<const short8*>(bp + (size_t)48 * K);

        acc0 = __builtin_amdgcn_mfma_f32_16x16x32_bf16(a, b0, acc0, 0, 0, 0);
        acc1 = __builtin_amdgcn_mfma_f32_16x16x32_bf16(a, b1, acc1, 0, 0, 0);
        acc2 = __builtin_amdgcn_mfma_f32_16x16x32_bf16(a, b2, acc2, 0, 0, 0);
        acc3 = __builtin_amdgcn_mfma_f32_16x16x32_bf16(a, b3, acc3, 0, 0, 0);
        __syncthreads();
    }

    f32x4 accs[4] = {acc0, acc1, acc2, acc3};
    #pragma unroll
    for (int r = 0; r < 4; ++r) {
        int gr = row0 + wave * 16 + q * 4 + r;
        if (gr >= M) continue;
        #pragma unroll
        for (int j = 0; j < 4; ++j) {
            int col = j * 16 + m16;
            float v = accs[j][r];
            if (!BF16_OUT) v += bias[col];
            if (BF16_OUT)
                ((u16*)C)[(size_t)gr * 64 + col] = f2bf(v);
            else
                ((float*)C)[(size_t)gr * 64 + col] = v;
        }
    }
}

// he[e] = (1/deg_e) * sum xt[inc_node[j]]  -- 8x8 sub-group gather (16 B/lane)
__device__ __forceinline__ void dev_hedge_sum(int bid, const int* __restrict__ inc_node,
                                              const int* __restrict__ he_off,
                                              const u16* __restrict__ xt,
                                              u16* __restrict__ he) {
    int w = (bid * 256 + (int)threadIdx.x) >> 6;
    int lane = threadIdx.x & 63;
    if (w >= N_HE) return;
    int sub = lane >> 3;            // 0..7 : which incidence in the octet
    int col8 = (lane & 7) << 3;     // 8 consecutive bf16 columns (16 B)
    int s = he_off[w], e = he_off[w + 1];

    float a0 = 0.f, a1 = 0.f, a2 = 0.f, a3 = 0.f;
    float a4 = 0.f, a5 = 0.f, a6 = 0.f, a7 = 0.f;

    int jj = s + sub;
    int idx = (jj < e) ? inc_node[jj] : -1;
    for (int j0 = s; j0 < e; j0 += 8) {
        int cur = idx;
        int jn = j0 + 8 + sub;
        idx = (jn < e) ? inc_node[jn] : -1;
        if (cur >= 0) {
            uint4 d = *reinterpret_cast<const uint4*>(xt + (((size_t)cur) << 6) + col8);
            a0 += lo_bf(d.x); a1 += hi_bf(d.x);
            a2 += lo_bf(d.y); a3 += hi_bf(d.y);
            a4 += lo_bf(d.z); a5 += hi_bf(d.z);
            a6 += lo_bf(d.w); a7 += hi_bf(d.w);
        }
    }
    #pragma unroll
    for (int d = 8; d < 64; d <<= 1) {
        a0 += __shfl_xor(a0, d, 64); a1 += __shfl_xor(a1, d, 64);
        a2 += __shfl_xor(a2, d, 64); a3 += __shfl_xor(a3, d, 64);
        a4 += __shfl_xor(a4, d, 64); a5 += __shfl_xor(a5, d, 64);
        a6 += __shfl_xor(a6, d, 64); a7 += __shfl_xor(a7, d, 64);
    }

    if (sub == 0) {   // lanes 0..7 write 8 bf16 each (coalesced 128 B)
        float inv = (e > s) ? 1.f / (float)(e - s) : 0.f;
        uint4 o;
        o.x = pack_bf2(a0 * inv, a1 * inv);
        o.y = pack_bf2(a2 * inv, a3 * inv);
        o.z = pack_bf2(a4 * inv, a5 * inv);
        o.w = pack_bf2(a6 * inv, a7 * inv);
        *reinterpret_cast<uint4*>(he + (((size_t)w) << 6) + col8) = o;
    }
}

// out[v] = relu((1/deg_v) * sum he[csr[j]] + bias) + nf[v]  -- 8x8 version
__device__ __forceinline__ void dev_node_sum(int bid, const int* __restrict__ csr,
                                             const int* __restrict__ node_off,
                                             const u16* __restrict__ he,
                                             const float* __restrict__ bias,
                                             const float* __restrict__ nf,
                                             float* __restrict__ out) {
    int w = (bid * 256 + (int)threadIdx.x) >> 6;
    int lane = threadIdx.x & 63;
    if (w >= N_NODES) return;
    int sub = lane >> 3;
    int col8 = (lane & 7) << 3;
    int s = node_off[w], e = node_off[w + 1];

    float a0 = 0.f, a1 = 0.f, a2 = 0.f, a3 = 0.f;
    float a4 = 0.f, a5 = 0.f, a6 = 0.f, a7 = 0.f;

    int jj = s + sub;
    int idx = (jj < e) ? csr[jj] : -1;
    for (int j0 = s; j0 < e; j0 += 8) {
        int cur = idx;
        int jn = j0 + 8 + sub;
        idx = (jn < e) ? csr[jn] : -1;
        if (cur >= 0) {
            uint4 d = *reinterpret_cast<const uint4*>(he + (((size_t)cur) << 6) + col8);
            a0 += lo_bf(d.x); a1 += hi_bf(d.x);
            a2 += lo_bf(d.y); a3 += hi_bf(d.y);
            a4 += lo_bf(d.z); a5 += hi_bf(d.z);
            a6 += lo_bf(d.w); a7 += hi_bf(d.w);
        }
    }
    #pragma unroll
    for (int d = 8; d < 64; d <<= 1) {
        a0 += __shfl_xor(a0, d, 64); a1 += __shfl_xor(a1, d, 64);
        a2 += __shfl_xor(a2, d, 64); a3 += __shfl_xor(a3, d, 64);
        a4 += __shfl_xor(a4, d, 64); a5 += __shfl_xor(a5, d, 64);
        a6 += __shfl_xor(a6, d, 64); a7 += __shfl_xor(a7, d, 64);
    }

    if (sub == 0) {   // lanes 0..7: 8 floats each (32 B) -> 256 B row
        float inv = (e > s) ? 1.f / (float)(e - s) : 0.f;
        const float* nfp = nf + (((size_t)w) << 6) + col8;
        float4 nv0 = *reinterpret_cast<const float4*>(nfp);
        float4 nv1 = *reinterpret_cast<const float4*>(nfp + 4);
        float4 o0, o1;
        o0.x = fmaxf(fmaf(a0, inv, bias[col8 + 0]), 0.f) + nv0.x;
        o0.y = fmaxf(fmaf(a1, inv, bias[col8 + 1]), 0.f) + nv0.y;
        o0.z = fmaxf(fmaf(a2, inv, bias[col8 + 2]), 0.f) + nv0.z;
        o0.w = fmaxf(fmaf(a3, inv, bias[col8 + 3]), 0.f) + nv0.w;
        o1.x = fmaxf(fmaf(a4, inv, bias[col8 + 4]), 0.f) + nv1.x;
        o1.y = fmaxf(fmaf(a5, inv, bias[col8 + 5]), 0.f) + nv1.y;
        o1.z = fmaxf(fmaf(a6, inv, bias[col8 + 6]), 0.f) + nv1.z;
        o1.w = fmaxf(fmaf(a7, inv, bias[col8 + 7]), 0.f) + nv1.w;
        float* op = out + (((size_t)w) << 6) + col8;
        *reinterpret_cast<float4*>(op) = o0;
        *reinterpret_cast<float4*>(op + 4) = o1;
    }
}

// ---------------------------------------------------------------------------
// phase mega-kernels (block-range dispatch; roles are mutually independent)
// ---------------------------------------------------------------------------
__global__ __launch_bounds__(256) void k_p1(const int* __restrict__ inc_hedge,
                                            const int* __restrict__ node2cell,
                                            const int* __restrict__ inc_node,
                                            int* __restrict__ he_off, int* __restrict__ cell_off,
                                            int* __restrict__ deg_v,
                                            const float* __restrict__ fhi_w, const float* __restrict__ fin_w,
                                            const float* __restrict__ th1, const float* __restrict__ th2,
                                            u16* __restrict__ Bt_fhi, u16* __restrict__ Bt_fin,
                                            u16* __restrict__ Bt_th1, u16* __restrict__ Bt_th2) {
    int bid = blockIdx.x;
    if (bid < G_OFF_HE) { dev_offsets(bid, inc_hedge, N_INC, N_HE, he_off); return; }
    bid -= G_OFF_HE;
    if (bid < G_OFF_CELL) { dev_offsets(bid, node2cell, N_NODES, N_CELLS, cell_off); return; }
    bid -= G_OFF_CELL;
    if (bid < G_HIST) { dev_hist(bid, inc_node, N_INC, deg_v); return; }
    bid -= G_HIST;
    if (bid < G_CONV_BIG) { dev_convT(bid, fhi_w, Bt_fhi, D_IN); return; }
    bid -= G_CONV_BIG;
    if (bid < G_CONV_BIG) { dev_convT(bid, fin_w, Bt_fin, D_IN); return; }
    bid -= G_CONV_BIG;
    if (bid < G_CONV_SM) { dev_convT(bid, th1, Bt_th1, 64); return; }
    bid -= G_CONV_SM;
    dev_convT(bid, th2, Bt_th2, 64);
}

__global__ __launch_bounds__(256) void k_p2(const int* __restrict__ deg_v,
                                            int* __restrict__ node_off, int* __restrict__ bsum,
                                            const float* __restrict__ vac_emb,
                                            const u16* __restrict__ Bt_fhi,
                                            const float* __restrict__ fhi_b, float* __restrict__ P) {
    __shared__ __align__(16) char smem[64 * 40 * 2];
    int bid = blockIdx.x;
    if (bid < G_SCAN) { dev_scan1(bid, (int*)smem, deg_v, N_NODES, node_off, bsum); return; }
    bid -= G_SCAN;
    dev_mfma_gemm<0>(bid, smem, vac_emb, Bt_fhi, fhi_b, P, VOCAB, D_IN);
}

__global__ __launch_bounds__(256) void k_p3(int* __restrict__ bsum,
                                            const float4* __restrict__ P,
                                            const int* __restrict__ tok, float4* __restrict__ nf) {
    int bid = blockIdx.x;
    if (bid == 0) { dev_scan2_wave(bsum, G_SCAN); return; }
    bid -= 1;
    dev_gather_nf(bid, P, tok, nf);
}

__global__ __launch_bounds__(256) void k_p4(int* __restrict__ node_off, const int* __restrict__ bsum,
                                            const float* __restrict__ nf, const u16* __restrict__ Bt_th1,
                                            u16* __restrict__ xt,
                                            const float* __restrict__ x, const u16* __restrict__ Bt_fin,
                                            const float* __restrict__ fin_b, float* __restrict__ x0) {
    __shared__ __align__(16) char smem[64 * 40 * 2];
    int bid = blockIdx.x;
    if (bid < G_SCAN) { dev_scan3(bid, node_off, bsum, N_NODES, N_INC); return; }
    bid -= G_SCAN;
    if (bid < G_XTGEMM) { dev_mfma_gemm<1>(bid, smem, nf, Bt_th1, nullptr, xt, N_NODES, 64); return; }
    bid -= G_XTGEMM;
    dev_mfma_gemm<0>(bid, smem, x, Bt_fin, fin_b, x0, I_ * J_, D_IN);
}

// P5: hedge_sum L1 blocks first (long-latency gathers start immediately), csr_fill after
__global__ __launch_bounds__(256) void k_p5(const int* __restrict__ inc_node,
                                            const int* __restrict__ inc_hedge,
                                            const int* __restrict__ node_off,
                                            int* __restrict__ cursor, int* __restrict__ csr,
                                            const int* __restrict__ he_off,
                                            const u16* __restrict__ xt, u16* __restrict__ he) {
    int bid = blockIdx.x;
    if (bid < G_HEDGE) { dev_hedge_sum(bid, inc_node, he_off, xt, he); return; }
    bid -= G_HEDGE;
    dev_csr_fill(bid, inc_node, inc_hedge, N_INC, node_off, cursor, csr);
}

// standalone wrappers
template <int BF16_OUT>
__global__ __launch_bounds__(256) void k_mfma_gemm(const float* __restrict__ A,
                                                   const u16* __restrict__ Bt,
                                                   const float* __restrict__ bias,
                                                   void* __restrict__ C, int M, int K) {
    __shared__ __align__(16) char smem[64 * 40 * 2];
    dev_mfma_gemm<BF16_OUT>(blockIdx.x, smem, A, Bt, bias, C, M, K);
}

__global__ __launch_bounds__(256) void k_hedge_sum(const int* __restrict__ inc_node,
                                                   const int* __restrict__ he_off,
                                                   const u16* __restrict__ xt,
                                                   u16* __restrict__ he) {
    dev_hedge_sum(blockIdx.x, inc_node, he_off, xt, he);
}

__global__ __launch_bounds__(256) void k_node_sum(const int* __restrict__ csr,
                                                  const int* __restrict__ node_off,
                                                  const u16* __restrict__ he,
                                                  const float* __restrict__ bias,
                                                  const float* __restrict__ nf,
                                                  float* __restrict__ out) {
    dev_node_sum(blockIdx.x, csr, node_off, he, bias, nf, out);
}

// ---------------------------------------------------------------------------
// per-cell mean+max pooling, fused x_upd = x0 + 0.3*cell_emb
// ---------------------------------------------------------------------------
__global__ __launch_bounds__(256) void k_pool(const float* __restrict__ gx,
                                              const int* __restrict__ cell_off,
                                              const float* __restrict__ x0,
                                              float* __restrict__ out1) {
    __shared__ float ssum[4][64];
    __shared__ float smax[4][64];
    int c = blockIdx.x;
    int lane = threadIdx.x & 63;
    int w = threadIdx.x >> 6;
    int s = cell_off[c], e = cell_off[c + 1];
    float sum = 0.f, mx = -INFINITY;
    for (int n = s + w; n < e; n += 4) {
        float v = gx[((size_t)n << 6) + lane];
        sum += v;
        mx = fmaxf(mx, v);
    }
    ssum[w][lane] = sum;
    smax[w][lane] = mx;
    __syncthreads();
    if (w == 0) {
        sum = ssum[0][lane] + ssum[1][lane] + ssum[2][lane] + ssum[3][lane];
        mx = fmaxf(fmaxf(smax[0][lane], smax[1][lane]), fmaxf(smax[2][lane], smax[3][lane]));
        int cnt = e - s;
        float mean = (cnt > 0) ? sum / (float)cnt : 0.f;
        float mp = (cnt > 0) ? mx : 0.f;
        float ce = 0.5f * (mean + mp);
        out1[((size_t)c << 6) + lane] = x0[((size_t)c << 6) + lane] + 0.3f * ce;
    }
}

// ---------------------------------------------------------------------------
// fused TCN
// ---------------------------------------------------------------------------
__global__ __launch_bounds__(256) void k_tcn(
    const float* __restrict__ xu,
    const float* __restrict__ wc1, const float* __restrict__ bc1, const float* __restrict__ g1,
    const float* __restrict__ be1, const float* __restrict__ m1, const float* __restrict__ v1,
    const float* __restrict__ wc2, const float* __restrict__ bc2, const float* __restrict__ g2,
    const float* __restrict__ be2, const float* __restrict__ m2, const float* __restrict__ v2,
    const float* __restrict__ wc3, const float* __restrict__ bc3, const float* __restrict__ g3,
    const float* __restrict__ be3, const float* __restrict__ m3, const float* __restrict__ v3,
    const float* __restrict__ fct_w, const float* __restrict__ fct_b,
    float* __restrict__ out2) {
    __shared__ float w_lds[64 * 64 * 3];
    __shared__ float hA[64][10];
    __shared__ float hB[64][10];
    __shared__ float mo[64];

    int n = blockIdx.x, tid = threadIdx.x;

    if (tid < 64) {
        hA[tid][0] = 0.f; hA[tid][9] = 0.f;
        hB[tid][0] = 0.f; hB[tid][9] = 0.f;
    }
    #pragma unroll
    for (int l = tid; l < 512; l += 256) {
        int t = l >> 6, i = l & 63;
        hA[i][t + 1] = xu[(size_t)n * 512 + l];
    }

    const float* wcs[3] = {wc1, wc2, wc3};
    const float* bcs[3] = {bc1, bc2, bc3};
    const float* gs[3]  = {g1, g2, g3};
    const float* bes[3] = {be1, be2, be3};
    const float* ms[3]  = {m1, m2, m3};
    const float* vs[3]  = {v1, v2, v3};

    float (*hin)[10] = hA;
    float (*hout)[10] = hB;

    #pragma unroll
    for (int li = 0; li < 3; ++li) {
        for (int l = tid; l < 64 * 64 * 3; l += 256) w_lds[l] = wcs[li][l];
        __syncthreads();
        #pragma unroll
        for (int rep = 0; rep < 2; ++rep) {
            int idx = tid + rep * 256;
            int o = idx >> 3, t = idx & 7;
            float acc = bcs[li][o];
            #pragma unroll 8
            for (int i = 0; i < 64; ++i) {
                const float* wr = &w_lds[o * 192 + i * 3];
                acc = fmaf(hin[i][t + 0], wr[0], acc);
                acc = fmaf(hin[i][t + 1], wr[1], acc);
                acc = fmaf(hin[i][t + 2], wr[2], acc);
            }
            acc = fmaxf(acc, 0.f);
            float sc = gs[li][o] * rsqrtf(vs[li][o] + 1e-5f);
            acc = (acc - ms[li][o]) * sc + bes[li][o];
            hout[o][t + 1] = acc;
        }
        __syncthreads();
        float (*tmp)[10] = hin; hin = hout; hout = tmp;
    }

    if (tid < 64) {
        float s = 0.f;
        #pragma unroll
        for (int t = 0; t < 8; ++t) s += hin[tid][t + 1];
        mo[tid] = s * 0.125f;
    }
    __syncthreads();
    if (tid < 64) {
        float acc = fct_b[tid];
        #pragma unroll 8
        for (int o = 0; o < 64; ++o) acc = fmaf(mo[o], fct_w[o * 64 + tid], acc);
        out2[(size_t)n * 64 + tid] = acc;
    }
}

// ---------------------------------------------------------------------------
extern "C" void kernel_launch(void* const* d_in, const int* in_sizes, int n_in,
                              void* d_out, int out_size, void* d_ws, size_t ws_size,
                              hipStream_t stream) {
    (void)in_sizes; (void)n_in; (void)out_size; (void)ws_size;

    const float* x          = (const float*)d_in[0];
    const int*   node_tok   = (const int*)d_in[1];
    const int*   inc_node   = (const int*)d_in[2];
    const int*   inc_hedge  = (const int*)d_in[3];
    const int*   node2cell  = (const int*)d_in[4];
    const float* vac_emb    = (const float*)d_in[5];
    const float* fhi_w      = (const float*)d_in[6];
    const float* fhi_b      = (const float*)d_in[7];
    const float* fin_w      = (const float*)d_in[8];
    const float* fin_b      = (const float*)d_in[9];
    const float* th1        = (const float*)d_in[10];
    const float* b1         = (const float*)d_in[11];
    const float* th2        = (const float*)d_in[12];
    const float* b2         = (const float*)d_in[13];
    const float* fct_w      = (const float*)d_in[32];
    const float* fct_b      = (const float*)d_in[33];

    char* ws = (char*)d_ws;
    size_t off = 0;
    float* P        = (float*)(ws + off); off += (size_t)VOCAB * 64 * 4;
    float* nf       = (float*)(ws + off); off += (size_t)N_NODES * 64 * 4;
    float* hbuf     = (float*)(ws + off); off += (size_t)N_NODES * 64 * 4;
    u16*   xt       = (u16*)(ws + off);   off += (size_t)N_NODES * 64 * 2;
    u16*   he       = (u16*)(ws + off);   off += (size_t)N_HE * 64 * 2;
    float* x0       = (float*)(ws + off); off += (size_t)N_CELLS * 64 * 4;
    u16*   Bt_fhi   = (u16*)(ws + off);   off += (size_t)64 * D_IN * 2;
    u16*   Bt_fin   = (u16*)(ws + off);   off += (size_t)64 * D_IN * 2;
    u16*   Bt_th1   = (u16*)(ws + off);   off += (size_t)64 * 64 * 2;
    u16*   Bt_th2   = (u16*)(ws + off);   off += (size_t)64 * 64 * 2;
    int*   he_off   = (int*)(ws + off);   off += ((size_t)(N_HE + 1) * 4 + 255) / 256 * 256;
    int*   node_off = (int*)(ws + off);   off += ((size_t)(N_NODES + 1) * 4 + 255) / 256 * 256;
    int*   deg_v    = (int*)(ws + off);   off += (size_t)N_NODES * 4;
    int*   cursor   = (int*)(ws + off);   off += (size_t)N_NODES * 4;
    int*   csr      = (int*)(ws + off);   off += (size_t)N_INC * 4;
    int*   cell_off = (int*)(ws + off);   off += ((size_t)(N_CELLS + 1) * 4 + 255) / 256 * 256;
    int*   bsum     = (int*)(ws + off);   off += 1024 * 4;

    float* out1 = (float*)d_out;
    float* out2 = out1 + (size_t)I_ * J_ * D_H;

    // deg_v and cursor are adjacent -> single memset
    hipMemsetAsync(deg_v, 0, 2 * (size_t)N_NODES * 4, stream);

    // P1: offsets(hedge) + offsets(cell) + hist + 4x convT
    k_p1<<<G_OFF_HE + G_OFF_CELL + G_HIST + 2 * G_CONV_BIG + 2 * G_CONV_SM, 256, 0, stream>>>(
        inc_hedge, node2cell, inc_node, he_off, cell_off, deg_v,
        fhi_w, fin_w, th1, th2, Bt_fhi, Bt_fin, Bt_th1, Bt_th2);

    // P2: scan1 + P-GEMM
    k_p2<<<G_SCAN + G_PGEMM, 256, 0, stream>>>(deg_v, node_off, bsum, vac_emb, Bt_fhi, fhi_b, P);

    // P3: scan2 + gather_nf
    k_p3<<<1 + G_GATHER, 256, 0, stream>>>(bsum, (const float4*)P, node_tok, (float4*)nf);

    // P4: scan3 + xt-GEMM L1 + x0-GEMM
    k_p4<<<G_SCAN + G_XTGEMM + G_X0GEMM, 256, 0, stream>>>(node_off, bsum, nf, Bt_th1, xt,
                                                           x, Bt_fin, fin_b, x0);

    // P5: hedge_sum L1 + csr_fill
    k_p5<<<G_HEDGE + G_CSR, 256, 0, stream>>>(inc_node, inc_hedge, node_off, cursor, csr,
                                              he_off, xt, he);

    // P6: node_sum L1 -> hbuf = h1
    k_node_sum<<<G_NODE, 256, 0, stream>>>(csr, node_off, he, b1, nf, hbuf);

    // P7: xt-GEMM L2
    k_mfma_gemm<1><<<G_XTGEMM, 256, 0, stream>>>(hbuf, Bt_th2, nullptr, xt, N_NODES, 64);

    // P8: hedge_sum L2
    k_hedge_sum<<<G_HEDGE, 256, 0, stream>>>(inc_node, he_off, xt, he);

    // P9: node_sum L2 -> hbuf = gx
    k_node_sum<<<G_NODE, 256, 0, stream>>>(csr, node_off, he, b2, nf, hbuf);

    // P10: pool + fuse -> out1
    k_pool<<<N_CELLS, 256, 0, stream>>>(hbuf, cell_off, x0, out1);

    // P11: TCN -> out2
    k_tcn<<<I_, 256, 0, stream>>>(out1,
        (const float*)d_in[14], (const float*)d_in[15], (const float*)d_in[16],
        (const float*)d_in[17], (const float*)d_in[18], (const float*)d_in[19],
        (const float*)d_in[20], (const float*)d_in[21], (const float*)d_in[22],
        (const float*)d_in[23], (const float*)d_in[24], (const float*)d_in[25],
        (const float*)d_in[26], (const float*)d_in[27], (const float*)d_in[28],
        (const float*)d_in[29], (const float*)d_in[30], (const float*)d_in[31],
        fct_w, fct_b, out2);
}

// Round 6
// 734.502 us; speedup vs baseline: 1.9182x; 1.1181x over previous
//
#include <hip/hip_runtime.h>
#include <hip/hip_bf16.h>
#include <cstdint>
#include <cstddef>

#define I_      100
#define J_      8
#define D_IN    768
#define D_H     64
#define N_NODES 160000
#define N_HE    320000
#define N_INC   1600000
#define N_CELLS 800
#define VOCAB   30000

#define NRANGE   256            // node ranges for bucket sort
#define NPR      625            // nodes per range (256*625 = 160000)
#define EPB      (N_INC / 256)  // elements per Ka/Kc block = 6250

typedef unsigned short u16;
using short8 = __attribute__((ext_vector_type(8))) short;
using f32x4  = __attribute__((ext_vector_type(4))) float;

__device__ __forceinline__ float bf2f(u16 u) {
    union { uint32_t i; float f; } x; x.i = ((uint32_t)u) << 16; return x.f;
}
__device__ __forceinline__ u16 f2bf(float f) {
    union { float f; uint32_t i; } x; x.f = f;
    uint32_t b = x.i;
    b += 0x7FFFu + ((b >> 16) & 1u);   // round-to-nearest-even
    return (u16)(b >> 16);
}
__device__ __forceinline__ float lo_bf(uint32_t u) {
    union { uint32_t i; float f; } x; x.i = u << 16; return x.f;
}
__device__ __forceinline__ float hi_bf(uint32_t u) {
    union { uint32_t i; float f; } x; x.i = u & 0xFFFF0000u; return x.f;
}
__device__ __forceinline__ uint32_t pack_bf2(float a, float b) {
    return (uint32_t)f2bf(a) | ((uint32_t)f2bf(b) << 16);
}

// grid-partition constants
#define G_OFF_HE   (N_INC / 256)     // 6250
#define G_OFF_CELL (N_NODES / 256)   // 625
#define G_CONV_BIG ((D_IN * 64) / 256)  // 192
#define G_CONV_SM  ((64 * 64) / 256)    // 16
#define G_KA       256
#define G_KC       256
#define G_KD       256
#define G_PGEMM    ((VOCAB + 63) / 64)   // 469
#define G_GATHER   ((N_NODES * 16) / 256) // 10000
#define G_XTGEMM   (N_NODES / 64)    // 2500
#define G_X0GEMM   ((I_ * J_ + 63) / 64) // 13
#define G_HEDGE    (N_HE / 4)        // 80000
#define G_NODE     (N_NODES / 4)     // 40000

// ---------------------------------------------------------------------------
// offsets from sorted index array
// ---------------------------------------------------------------------------
__device__ __forceinline__ void dev_offsets(int bid, const int* __restrict__ sorted,
                                            int n, int nbins, int* __restrict__ off) {
    int i = bid * 256 + threadIdx.x;
    if (i >= n) return;
    int cur = sorted[i];
    int prev = (i == 0) ? -1 : sorted[i - 1];
    for (int b = prev + 1; b <= cur; ++b) off[b] = i;
    if (i == n - 1) {
        for (int b = cur + 1; b <= nbins; ++b) off[b] = n;
    }
}

__device__ __forceinline__ void dev_convT(int bid, const float* __restrict__ B,
                                          u16* __restrict__ Bt, int K) {
    int g = bid * 256 + threadIdx.x;
    if (g >= K * 64) return;
    int k = g >> 6, n = g & 63;
    Bt[(size_t)n * K + k] = f2bf(B[g]);
}

// ---------------------------------------------------------------------------
// bucket-sort CSR build (no global random scatter)
// ---------------------------------------------------------------------------
// Ka: per-block histogram of node ranges
__device__ __forceinline__ void dev_ka(int bid, const int* __restrict__ inc_node,
                                       int* __restrict__ counts, int* __restrict__ lds) {
    int tid = threadIdx.x;
    lds[tid] = 0;
    __syncthreads();
    int s = bid * EPB, e = s + EPB;
    for (int i = s + tid; i < e; i += 256)
        atomicAdd(&lds[(unsigned)inc_node[i] / NPR], 1);
    __syncthreads();
    counts[bid * NRANGE + tid] = lds[tid];
}

// Kb: chunk offsets (range-major) + range bases. 1 block, 256 threads.
__device__ __forceinline__ void dev_kb(const int* __restrict__ counts,
                                       int* __restrict__ chunk_off,
                                       int* __restrict__ range_base,
                                       int* __restrict__ lds) {
    int r = threadIdx.x;
    int run = 0;
    for (int b = 0; b < 256; ++b) {
        chunk_off[b * NRANGE + r] = run;
        run += counts[b * NRANGE + r];
    }
    lds[r] = run;
    __syncthreads();
    int s = run;
    #pragma unroll
    for (int d = 1; d < 256; d <<= 1) {
        int t = (r >= d) ? lds[r - d] : 0;
        __syncthreads();
        lds[r] += t;
        __syncthreads();
    }
    int base = lds[r] - s;
    range_base[r] = base;
    if (r == 255) range_base[256] = lds[255];  // = N_INC
    for (int b = 0; b < 256; ++b) chunk_off[b * NRANGE + r] += base;
}

// Kc: scatter pairs into range-major buckets (chunk-contiguous writes)
__device__ __forceinline__ void dev_kc(int bid, const int* __restrict__ inc_node,
                                       const int* __restrict__ inc_hedge,
                                       const int* __restrict__ chunk_off,
                                       int2* __restrict__ bucket, int* __restrict__ lds) {
    int tid = threadIdx.x;
    lds[tid] = 0;
    __syncthreads();
    int s = bid * EPB, e = s + EPB;
    const int* co = chunk_off + bid * NRANGE;
    for (int i = s + tid; i < e; i += 256) {
        int v = inc_node[i];
        int h = inc_hedge[i];
        int rg = (unsigned)v / NPR;
        int rank = atomicAdd(&lds[rg], 1);
        bucket[co[rg] + rank] = make_int2(v, h);
    }
}

// Kd: per-range exact CSR placement (single-block 25KB region -> full lines)
// lds layout: hist[768] | tsum[256] | cur[768]  (7168 B)
__device__ __forceinline__ void dev_kd(int r, const int2* __restrict__ bucket,
                                       const int* __restrict__ range_base,
                                       int* __restrict__ node_off, int* __restrict__ csr,
                                       int* __restrict__ lds) {
    int tid = threadIdx.x;
    int* hist = lds;
    int* tsum = lds + 768;
    int* cur  = lds + 1024;
    for (int i = tid; i < 768; i += 256) { hist[i] = 0; cur[i] = 0; }
    __syncthreads();
    int lo = r * NPR;
    int pb = range_base[r], pe = range_base[r + 1];
    for (int i = pb + tid; i < pe; i += 256)
        atomicAdd(&hist[bucket[i].x - lo], 1);
    __syncthreads();
    // exclusive scan of hist[0..624] (3 elements per thread)
    int b3 = tid * 3;
    int a0 = hist[b3], a1 = hist[b3 + 1], a2 = hist[b3 + 2];
    int s = a0 + a1 + a2;
    tsum[tid] = s;
    __syncthreads();
    #pragma unroll
    for (int d = 1; d < 256; d <<= 1) {
        int t = (tid >= d) ? tsum[tid - d] : 0;
        __syncthreads();
        tsum[tid] += t;
        __syncthreads();
    }
    int excl = tsum[tid] - s;
    hist[b3]     = excl;
    hist[b3 + 1] = excl + a0;
    hist[b3 + 2] = excl + a0 + a1;
    __syncthreads();
    for (int v = tid; v < NPR; v += 256) node_off[lo + v] = pb + hist[v];
    if (r == NRANGE - 1 && tid == 0) node_off[N_NODES] = N_INC;
    // scatter hedges to exact csr slots (LDS cursors)
    for (int i = pb + tid; i < pe; i += 256) {
        int2 p = bucket[i];
        int l = p.x - lo;
        int k = atomicAdd(&cur[l], 1);
        csr[pb + hist[l] + k] = p.y;
    }
}

__device__ __forceinline__ void dev_gather_nf(int bid, const float4* __restrict__ P,
                                              const int* __restrict__ tok,
                                              float4* __restrict__ nf) {
    int g = bid * 256 + threadIdx.x;
    if (g >= N_NODES * 16) return;
    int n = g >> 4, p = g & 15;
    nf[g] = P[((size_t)tok[n] << 4) + p];
}

// MFMA GEMM: C[M,64] = A[M,K](f32->bf16) @ Bt[64,K](bf16) (+bias for f32 out)
template <int BF16_OUT>
__device__ __forceinline__ void dev_mfma_gemm(int bid, char* smem,
                                              const float* __restrict__ A,
                                              const u16* __restrict__ Bt,
                                              const float* __restrict__ bias,
                                              void* __restrict__ C, int M, int K) {
    u16* Alds = (u16*)smem;          // 64 rows x 32 k, padded to 40
    int tid = threadIdx.x;
    int wave = tid >> 6, lane = tid & 63;
    int m16 = lane & 15, q = lane >> 4;
    int row0 = bid << 6;

    f32x4 acc0 = {0.f, 0.f, 0.f, 0.f};
    f32x4 acc1 = {0.f, 0.f, 0.f, 0.f};
    f32x4 acc2 = {0.f, 0.f, 0.f, 0.f};
    f32x4 acc3 = {0.f, 0.f, 0.f, 0.f};

    for (int kt = 0; kt < K; kt += 32) {
        #pragma unroll
        for (int it = 0; it < 2; ++it) {
            int l = tid + it * 256;
            int r = l >> 3, c4 = (l & 7) << 2;
            int gr = row0 + r;
            float4 av = make_float4(0.f, 0.f, 0.f, 0.f);
            if (gr < M)
                av = *reinterpret_cast<const float4*>(A + (size_t)gr * K + kt + c4);
            ushort4 u;
            u.x = f2bf(av.x); u.y = f2bf(av.y); u.z = f2bf(av.z); u.w = f2bf(av.w);
            *reinterpret_cast<ushort4*>(&Alds[r * 40 + c4]) = u;
        }
        __syncthreads();

        short8 a = *reinterpret_cast<const short8*>(&Alds[(wave * 16 + m16) * 40 + q * 8]);
        const u16* bp = Bt + (size_t)m16 * K + kt + q * 8;
        short8 b0 = *reinterpret_cast<const short8*>(bp);
        short8 b1 = *reinterpret_cast<const short8*>(bp + (size_t)16 * K);
        short8 b2 = *reinterpret_cast<const short8*>(bp + (size_t)32 * K);
        short8 b3 = *reinterpret_cast<const short8*>(bp + (size_t)48 * K);

        acc0 = __builtin_amdgcn_mfma_f32_16x16x32_bf16(a, b0, acc0, 0, 0, 0);
        acc1 = __builtin_amdgcn_mfma_f32_16x16x32_bf16(a, b1, acc1, 0, 0, 0);
        acc2 = __builtin_amdgcn_mfma_f32_16x16x32_bf16(a, b2, acc2, 0, 0, 0);
        acc3 = __builtin_amdgcn_mfma_f32_16x16x32_bf16(a, b3, acc3, 0, 0, 0);
        __syncthreads();
    }

    f32x4 accs[4] = {acc0, acc1, acc2, acc3};
    #pragma unroll
    for (int r = 0; r < 4; ++r) {
        int gr = row0 + wave * 16 + q * 4 + r;
        if (gr >= M) continue;
        #pragma unroll
        for (int j = 0; j < 4; ++j) {
            int col = j * 16 + m16;
            float v = accs[j][r];
            if (!BF16_OUT) v += bias[col];
            if (BF16_OUT)
                ((u16*)C)[(size_t)gr * 64 + col] = f2bf(v);
            else
                ((float*)C)[(size_t)gr * 64 + col] = v;
        }
    }
}

// he[e] = (1/deg_e) * sum xt[inc_node[j]]  -- 8x8 sub-group gather (16 B/lane)
__device__ __forceinline__ void dev_hedge_sum(int bid, const int* __restrict__ inc_node,
                                              const int* __restrict__ he_off,
                                              const u16* __restrict__ xt,
                                              u16* __restrict__ he) {
    int w = (bid * 256 + (int)threadIdx.x) >> 6;
    int lane = threadIdx.x & 63;
    if (w >= N_HE) return;
    int sub = lane >> 3;
    int col8 = (lane & 7) << 3;
    int s = he_off[w], e = he_off[w + 1];

    float a0 = 0.f, a1 = 0.f, a2 = 0.f, a3 = 0.f;
    float a4 = 0.f, a5 = 0.f, a6 = 0.f, a7 = 0.f;

    int jj = s + sub;
    int idx = (jj < e) ? inc_node[jj] : -1;
    for (int j0 = s; j0 < e; j0 += 8) {
        int cur = idx;
        int jn = j0 + 8 + sub;
        idx = (jn < e) ? inc_node[jn] : -1;
        if (cur >= 0) {
            uint4 d = *reinterpret_cast<const uint4*>(xt + (((size_t)cur) << 6) + col8);
            a0 += lo_bf(d.x); a1 += hi_bf(d.x);
            a2 += lo_bf(d.y); a3 += hi_bf(d.y);
            a4 += lo_bf(d.z); a5 += hi_bf(d.z);
            a6 += lo_bf(d.w); a7 += hi_bf(d.w);
        }
    }
    #pragma unroll
    for (int d = 8; d < 64; d <<= 1) {
        a0 += __shfl_xor(a0, d, 64); a1 += __shfl_xor(a1, d, 64);
        a2 += __shfl_xor(a2, d, 64); a3 += __shfl_xor(a3, d, 64);
        a4 += __shfl_xor(a4, d, 64); a5 += __shfl_xor(a5, d, 64);
        a6 += __shfl_xor(a6, d, 64); a7 += __shfl_xor(a7, d, 64);
    }

    if (sub == 0) {
        float inv = (e > s) ? 1.f / (float)(e - s) : 0.f;
        uint4 o;
        o.x = pack_bf2(a0 * inv, a1 * inv);
        o.y = pack_bf2(a2 * inv, a3 * inv);
        o.z = pack_bf2(a4 * inv, a5 * inv);
        o.w = pack_bf2(a6 * inv, a7 * inv);
        *reinterpret_cast<uint4*>(he + (((size_t)w) << 6) + col8) = o;
    }
}

// out[v] = relu((1/deg_v) * sum he[csr[j]] + bias) + nf[v]  -- 8x8 version
__device__ __forceinline__ void dev_node_sum(int bid, const int* __restrict__ csr,
                                             const int* __restrict__ node_off,
                                             const u16* __restrict__ he,
                                             const float* __restrict__ bias,
                                             const float* __restrict__ nf,
                                             float* __restrict__ out) {
    int w = (bid * 256 + (int)threadIdx.x) >> 6;
    int lane = threadIdx.x & 63;
    if (w >= N_NODES) return;
    int sub = lane >> 3;
    int col8 = (lane & 7) << 3;
    int s = node_off[w], e = node_off[w + 1];

    float a0 = 0.f, a1 = 0.f, a2 = 0.f, a3 = 0.f;
    float a4 = 0.f, a5 = 0.f, a6 = 0.f, a7 = 0.f;

    int jj = s + sub;
    int idx = (jj < e) ? csr[jj] : -1;
    for (int j0 = s; j0 < e; j0 += 8) {
        int cur = idx;
        int jn = j0 + 8 + sub;
        idx = (jn < e) ? csr[jn] : -1;
        if (cur >= 0) {
            uint4 d = *reinterpret_cast<const uint4*>(he + (((size_t)cur) << 6) + col8);
            a0 += lo_bf(d.x); a1 += hi_bf(d.x);
            a2 += lo_bf(d.y); a3 += hi_bf(d.y);
            a4 += lo_bf(d.z); a5 += hi_bf(d.z);
            a6 += lo_bf(d.w); a7 += hi_bf(d.w);
        }
    }
    #pragma unroll
    for (int d = 8; d < 64; d <<= 1) {
        a0 += __shfl_xor(a0, d, 64); a1 += __shfl_xor(a1, d, 64);
        a2 += __shfl_xor(a2, d, 64); a3 += __shfl_xor(a3, d, 64);
        a4 += __shfl_xor(a4, d, 64); a5 += __shfl_xor(a5, d, 64);
        a6 += __shfl_xor(a6, d, 64); a7 += __shfl_xor(a7, d, 64);
    }

    if (sub == 0) {
        float inv = (e > s) ? 1.f / (float)(e - s) : 0.f;
        const float* nfp = nf + (((size_t)w) << 6) + col8;
        float4 nv0 = *reinterpret_cast<const float4*>(nfp);
        float4 nv1 = *reinterpret_cast<const float4*>(nfp + 4);
        float4 o0, o1;
        o0.x = fmaxf(fmaf(a0, inv, bias[col8 + 0]), 0.f) + nv0.x;
        o0.y = fmaxf(fmaf(a1, inv, bias[col8 + 1]), 0.f) + nv0.y;
        o0.z = fmaxf(fmaf(a2, inv, bias[col8 + 2]), 0.f) + nv0.z;
        o0.w = fmaxf(fmaf(a3, inv, bias[col8 + 3]), 0.f) + nv0.w;
        o1.x = fmaxf(fmaf(a4, inv, bias[col8 + 4]), 0.f) + nv1.x;
        o1.y = fmaxf(fmaf(a5, inv, bias[col8 + 5]), 0.f) + nv1.y;
        o1.z = fmaxf(fmaf(a6, inv, bias[col8 + 6]), 0.f) + nv1.z;
        o1.w = fmaxf(fmaf(a7, inv, bias[col8 + 7]), 0.f) + nv1.w;
        float* op = out + (((size_t)w) << 6) + col8;
        *reinterpret_cast<float4*>(op) = o0;
        *reinterpret_cast<float4*>(op + 4) = o1;
    }
}

// ---------------------------------------------------------------------------
// phase mega-kernels
// ---------------------------------------------------------------------------
__global__ __launch_bounds__(256) void k_p1(const int* __restrict__ inc_hedge,
                                            const int* __restrict__ node2cell,
                                            const int* __restrict__ inc_node,
                                            int* __restrict__ he_off, int* __restrict__ cell_off,
                                            int* __restrict__ counts,
                                            const float* __restrict__ fhi_w, const float* __restrict__ fin_w,
                                            const float* __restrict__ th1, const float* __restrict__ th2,
                                            u16* __restrict__ Bt_fhi, u16* __restrict__ Bt_fin,
                                            u16* __restrict__ Bt_th1, u16* __restrict__ Bt_th2) {
    __shared__ int lds[256];
    int bid = blockIdx.x;
    if (bid < G_OFF_HE) { dev_offsets(bid, inc_hedge, N_INC, N_HE, he_off); return; }
    bid -= G_OFF_HE;
    if (bid < G_KA) { dev_ka(bid, inc_node, counts, lds); return; }
    bid -= G_KA;
    if (bid < G_OFF_CELL) { dev_offsets(bid, node2cell, N_NODES, N_CELLS, cell_off); return; }
    bid -= G_OFF_CELL;
    if (bid < G_CONV_BIG) { dev_convT(bid, fhi_w, Bt_fhi, D_IN); return; }
    bid -= G_CONV_BIG;
    if (bid < G_CONV_BIG) { dev_convT(bid, fin_w, Bt_fin, D_IN); return; }
    bid -= G_CONV_BIG;
    if (bid < G_CONV_SM) { dev_convT(bid, th1, Bt_th1, 64); return; }
    bid -= G_CONV_SM;
    dev_convT(bid, th2, Bt_th2, 64);
}

__global__ __launch_bounds__(256) void k_p2(const int* __restrict__ counts,
                                            int* __restrict__ chunk_off, int* __restrict__ range_base,
                                            const float* __restrict__ vac_emb,
                                            const u16* __restrict__ Bt_fhi,
                                            const float* __restrict__ fhi_b, float* __restrict__ P) {
    __shared__ __align__(16) char smem[8192];
    int bid = blockIdx.x;
    if (bid < G_PGEMM) { dev_mfma_gemm<0>(bid, smem, vac_emb, Bt_fhi, fhi_b, P, VOCAB, D_IN); return; }
    dev_kb(counts, chunk_off, range_base, (int*)smem);
}

__global__ __launch_bounds__(256) void k_p3(const int* __restrict__ inc_node,
                                            const int* __restrict__ inc_hedge,
                                            const int* __restrict__ chunk_off,
                                            int2* __restrict__ bucket,
                                            const float4* __restrict__ P,
                                            const int* __restrict__ tok, float4* __restrict__ nf) {
    __shared__ int lds[256];
    int bid = blockIdx.x;
    if (bid < G_GATHER) { dev_gather_nf(bid, P, tok, nf); return; }
    bid -= G_GATHER;
    dev_kc(bid, inc_node, inc_hedge, chunk_off, bucket, lds);
}

__global__ __launch_bounds__(256) void k_p4(const int2* __restrict__ bucket,
                                            const int* __restrict__ range_base,
                                            int* __restrict__ node_off, int* __restrict__ csr,
                                            const float* __restrict__ nf, const u16* __restrict__ Bt_th1,
                                            u16* __restrict__ xt,
                                            const float* __restrict__ x, const u16* __restrict__ Bt_fin,
                                            const float* __restrict__ fin_b, float* __restrict__ x0) {
    __shared__ __align__(16) char smem[8192];
    int bid = blockIdx.x;
    if (bid < G_KD) { dev_kd(bid, bucket, range_base, node_off, csr, (int*)smem); return; }
    bid -= G_KD;
    if (bid < G_XTGEMM) { dev_mfma_gemm<1>(bid, smem, nf, Bt_th1, nullptr, xt, N_NODES, 64); return; }
    bid -= G_XTGEMM;
    dev_mfma_gemm<0>(bid, smem, x, Bt_fin, fin_b, x0, I_ * J_, D_IN);
}

// standalone wrappers
template <int BF16_OUT>
__global__ __launch_bounds__(256) void k_mfma_gemm(const float* __restrict__ A,
                                                   const u16* __restrict__ Bt,
                                                   const float* __restrict__ bias,
                                                   void* __restrict__ C, int M, int K) {
    __shared__ __align__(16) char smem[8192];
    dev_mfma_gemm<BF16_OUT>(blockIdx.x, smem, A, Bt, bias, C, M, K);
}

__global__ __launch_bounds__(256) void k_hedge_sum(const int* __restrict__ inc_node,
                                                   const int* __restrict__ he_off,
                                                   const u16* __restrict__ xt,
                                                   u16* __restrict__ he) {
    dev_hedge_sum(blockIdx.x, inc_node, he_off, xt, he);
}

__global__ __launch_bounds__(256) void k_node_sum(const int* __restrict__ csr,
                                                  const int* __restrict__ node_off,
                                                  const u16* __restrict__ he,
                                                  const float* __restrict__ bias,
                                                  const float* __restrict__ nf,
                                                  float* __restrict__ out) {
    dev_node_sum(blockIdx.x, csr, node_off, he, bias, nf, out);
}

// ---------------------------------------------------------------------------
// per-cell mean+max pooling, fused x_upd = x0 + 0.3*cell_emb
// ---------------------------------------------------------------------------
__global__ __launch_bounds__(256) void k_pool(const float* __restrict__ gx,
                                              const int* __restrict__ cell_off,
                                              const float* __restrict__ x0,
                                              float* __restrict__ out1) {
    __shared__ float ssum[4][64];
    __shared__ float smax[4][64];
    int c = blockIdx.x;
    int lane = threadIdx.x & 63;
    int w = threadIdx.x >> 6;
    int s = cell_off[c], e = cell_off[c + 1];
    float sum = 0.f, mx = -INFINITY;
    for (int n = s + w; n < e; n += 4) {
        float v = gx[((size_t)n << 6) + lane];
        sum += v;
        mx = fmaxf(mx, v);
    }
    ssum[w][lane] = sum;
    smax[w][lane] = mx;
    __syncthreads();
    if (w == 0) {
        sum = ssum[0][lane] + ssum[1][lane] + ssum[2][lane] + ssum[3][lane];
        mx = fmaxf(fmaxf(smax[0][lane], smax[1][lane]), fmaxf(smax[2][lane], smax[3][lane]));
        int cnt = e - s;
        float mean = (cnt > 0) ? sum / (float)cnt : 0.f;
        float mp = (cnt > 0) ? mx : 0.f;
        float ce = 0.5f * (mean + mp);
        out1[((size_t)c << 6) + lane] = x0[((size_t)c << 6) + lane] + 0.3f * ce;
    }
}

// ---------------------------------------------------------------------------
// fused TCN
// ---------------------------------------------------------------------------
__global__ __launch_bounds__(256) void k_tcn(
    const float* __restrict__ xu,
    const float* __restrict__ wc1, const float* __restrict__ bc1, const float* __restrict__ g1,
    const float* __restrict__ be1, const float* __restrict__ m1, const float* __restrict__ v1,
    const float* __restrict__ wc2, const float* __restrict__ bc2, const float* __restrict__ g2,
    const float* __restrict__ be2, const float* __restrict__ m2, const float* __restrict__ v2,
    const float* __restrict__ wc3, const float* __restrict__ bc3, const float* __restrict__ g3,
    const float* __restrict__ be3, const float* __restrict__ m3, const float* __restrict__ v3,
    const float* __restrict__ fct_w, const float* __restrict__ fct_b,
    float* __restrict__ out2) {
    __shared__ float w_lds[64 * 64 * 3];
    __shared__ float hA[64][10];
    __shared__ float hB[64][10];
    __shared__ float mo[64];

    int n = blockIdx.x, tid = threadIdx.x;

    if (tid < 64) {
        hA[tid][0] = 0.f; hA[tid][9] = 0.f;
        hB[tid][0] = 0.f; hB[tid][9] = 0.f;
    }
    #pragma unroll
    for (int l = tid; l < 512; l += 256) {
        int t = l >> 6, i = l & 63;
        hA[i][t + 1] = xu[(size_t)n * 512 + l];
    }

    const float* wcs[3] = {wc1, wc2, wc3};
    const float* bcs[3] = {bc1, bc2, bc3};
    const float* gs[3]  = {g1, g2, g3};
    const float* bes[3] = {be1, be2, be3};
    const float* ms[3]  = {m1, m2, m3};
    const float* vs[3]  = {v1, v2, v3};

    float (*hin)[10] = hA;
    float (*hout)[10] = hB;

    #pragma unroll
    for (int li = 0; li < 3; ++li) {
        for (int l = tid; l < 64 * 64 * 3; l += 256) w_lds[l] = wcs[li][l];
        __syncthreads();
        #pragma unroll
        for (int rep = 0; rep < 2; ++rep) {
            int idx = tid + rep * 256;
            int o = idx >> 3, t = idx & 7;
            float acc = bcs[li][o];
            #pragma unroll 8
            for (int i = 0; i < 64; ++i) {
                const float* wr = &w_lds[o * 192 + i * 3];
                acc = fmaf(hin[i][t + 0], wr[0], acc);
                acc = fmaf(hin[i][t + 1], wr[1], acc);
                acc = fmaf(hin[i][t + 2], wr[2], acc);
            }
            acc = fmaxf(acc, 0.f);
            float sc = gs[li][o] * rsqrtf(vs[li][o] + 1e-5f);
            acc = (acc - ms[li][o]) * sc + bes[li][o];
            hout[o][t + 1] = acc;
        }
        __syncthreads();
        float (*tmp)[10] = hin; hin = hout; hout = tmp;
    }

    if (tid < 64) {
        float s = 0.f;
        #pragma unroll
        for (int t = 0; t < 8; ++t) s += hin[tid][t + 1];
        mo[tid] = s * 0.125f;
    }
    __syncthreads();
    if (tid < 64) {
        float acc = fct_b[tid];
        #pragma unroll 8
        for (int o = 0; o < 64; ++o) acc = fmaf(mo[o], fct_w[o * 64 + tid], acc);
        out2[(size_t)n * 64 + tid] = acc;
    }
}

// ---------------------------------------------------------------------------
extern "C" void kernel_launch(void* const* d_in, const int* in_sizes, int n_in,
                              void* d_out, int out_size, void* d_ws, size_t ws_size,
                              hipStream_t stream) {
    (void)in_sizes; (void)n_in; (void)out_size; (void)ws_size;

    const float* x          = (const float*)d_in[0];
    const int*   node_tok   = (const int*)d_in[1];
    const int*   inc_node   = (const int*)d_in[2];
    const int*   inc_hedge  = (const int*)d_in[3];
    const int*   node2cell  = (const int*)d_in[4];
    const float* vac_emb    = (const float*)d_in[5];
    const float* fhi_w      = (const float*)d_in[6];
    const float* fhi_b      = (const float*)d_in[7];
    const float* fin_w      = (const float*)d_in[8];
    const float* fin_b      = (const float*)d_in[9];
    const float* th1        = (const float*)d_in[10];
    const float* b1         = (const float*)d_in[11];
    const float* th2        = (const float*)d_in[12];
    const float* b2         = (const float*)d_in[13];
    const float* fct_w      = (const float*)d_in[32];
    const float* fct_b      = (const float*)d_in[33];

    char* ws = (char*)d_ws;
    size_t off = 0;
    float* P        = (float*)(ws + off); off += (size_t)VOCAB * 64 * 4;
    float* nf       = (float*)(ws + off); off += (size_t)N_NODES * 64 * 4;
    float* hbuf     = (float*)(ws + off); off += (size_t)N_NODES * 64 * 4;
    u16*   xt       = (u16*)(ws + off);   off += (size_t)N_NODES * 64 * 2;
    u16*   he       = (u16*)(ws + off);   off += (size_t)N_HE * 64 * 2;
    float* x0       = (float*)(ws + off); off += (size_t)N_CELLS * 64 * 4;
    u16*   Bt_fhi   = (u16*)(ws + off);   off += (size_t)64 * D_IN * 2;
    u16*   Bt_fin   = (u16*)(ws + off);   off += (size_t)64 * D_IN * 2;
    u16*   Bt_th1   = (u16*)(ws + off);   off += (size_t)64 * 64 * 2;
    u16*   Bt_th2   = (u16*)(ws + off);   off += (size_t)64 * 64 * 2;
    int*   he_off   = (int*)(ws + off);   off += ((size_t)(N_HE + 1) * 4 + 255) / 256 * 256;
    int*   node_off = (int*)(ws + off);   off += ((size_t)(N_NODES + 1) * 4 + 255) / 256 * 256;
    int*   csr      = (int*)(ws + off);   off += (size_t)N_INC * 4;
    int*   cell_off = (int*)(ws + off);   off += ((size_t)(N_CELLS + 1) * 4 + 255) / 256 * 256;

    // aliases (lifetimes verified):
    //   bucket (12.8 MB) aliases he (first written in P5, bucket dead after P4)
    //   counts/chunk_off/range_base alias hbuf (first written in P6; dead after P4)
    int2* bucket     = (int2*)he;
    int*  counts     = (int*)hbuf;                       // 256*256 ints
    int*  chunk_off  = counts + 256 * 256;               // 256*256 ints
    int*  range_base = chunk_off + 256 * 256;            // 257 ints

    float* out1 = (float*)d_out;
    float* out2 = out1 + (size_t)I_ * J_ * D_H;

    // P1: offsets(hedge) + Ka + offsets(cell) + 4x convT
    k_p1<<<G_OFF_HE + G_KA + G_OFF_CELL + 2 * G_CONV_BIG + 2 * G_CONV_SM, 256, 0, stream>>>(
        inc_hedge, node2cell, inc_node, he_off, cell_off, counts,
        fhi_w, fin_w, th1, th2, Bt_fhi, Bt_fin, Bt_th1, Bt_th2);

    // P2: P-GEMM + Kb
    k_p2<<<G_PGEMM + 1, 256, 0, stream>>>(counts, chunk_off, range_base, vac_emb, Bt_fhi, fhi_b, P);

    // P3: gather_nf + Kc
    k_p3<<<G_GATHER + G_KC, 256, 0, stream>>>(inc_node, inc_hedge, chunk_off, bucket,
                                              (const float4*)P, node_tok, (float4*)nf);

    // P4: Kd (csr + node_off) + xt-GEMM L1 + x0-GEMM
    k_p4<<<G_KD + G_XTGEMM + G_X0GEMM, 256, 0, stream>>>(bucket, range_base, node_off, csr,
                                                         nf, Bt_th1, xt, x, Bt_fin, fin_b, x0);

    // P5: hedge_sum L1 (overwrites he/bucket -- bucket dead)
    k_hedge_sum<<<G_HEDGE, 256, 0, stream>>>(inc_node, he_off, xt, he);

    // P6: node_sum L1 -> hbuf = h1 (overwrites counts/chunk_off -- dead)
    k_node_sum<<<G_NODE, 256, 0, stream>>>(csr, node_off, he, b1, nf, hbuf);

    // P7: xt-GEMM L2
    k_mfma_gemm<1><<<G_XTGEMM, 256, 0, stream>>>(hbuf, Bt_th2, nullptr, xt, N_NODES, 64);

    // P8: hedge_sum L2
    k_hedge_sum<<<G_HEDGE, 256, 0, stream>>>(inc_node, he_off, xt, he);

    // P9: node_sum L2 -> hbuf = gx
    k_node_sum<<<G_NODE, 256, 0, stream>>>(csr, node_off, he, b2, nf, hbuf);

    // P10: pool + fuse -> out1
    k_pool<<<N_CELLS, 256, 0, stream>>>(hbuf, cell_off, x0, out1);

    // P11: TCN -> out2
    k_tcn<<<I_, 256, 0, stream>>>(out1,
        (const float*)d_in[14], (const float*)d_in[15], (const float*)d_in[16],
        (const float*)d_in[17], (const float*)d_in[18], (const float*)d_in[19],
        (const float*)d_in[20], (const float*)d_in[21], (const float*)d_in[22],
        (const float*)d_in[23], (const float*)d_in[24], (const float*)d_in[25],
        (const float*)d_in[26], (const float*)d_in[27], (const float*)d_in[28],
        (const float*)d_in[29], (const float*)d_in[30], (const float*)d_in[31],
        fct_w, fct_b, out2);
}

// Round 7
// 604.247 us; speedup vs baseline: 2.3317x; 1.2156x over previous
//
#include <hip/hip_runtime.h>
#include <hip/hip_bf16.h>
#include <cstdint>
#include <cstddef>

#define I_      100
#define J_      8
#define D_IN    768
#define D_H     64
#define N_NODES 160000
#define N_HE    320000
#define N_INC   1600000
#define N_CELLS 800
#define VOCAB   30000

#define NRANGE   256            // node ranges for bucket sort
#define NPR      625            // nodes per range (256*625 = 160000)
#define EPB      (N_INC / 256)  // elements per Ka/Kc block = 6250

typedef unsigned short u16;
using short8 = __attribute__((ext_vector_type(8))) short;
using f32x4  = __attribute__((ext_vector_type(4))) float;

__device__ __forceinline__ float bf2f(u16 u) {
    union { uint32_t i; float f; } x; x.i = ((uint32_t)u) << 16; return x.f;
}
__device__ __forceinline__ u16 f2bf(float f) {
    union { float f; uint32_t i; } x; x.f = f;
    uint32_t b = x.i;
    b += 0x7FFFu + ((b >> 16) & 1u);   // round-to-nearest-even
    return (u16)(b >> 16);
}
__device__ __forceinline__ float lo_bf(uint32_t u) {
    union { uint32_t i; float f; } x; x.i = u << 16; return x.f;
}
__device__ __forceinline__ float hi_bf(uint32_t u) {
    union { uint32_t i; float f; } x; x.i = u & 0xFFFF0000u; return x.f;
}
__device__ __forceinline__ uint32_t pack_bf2(float a, float b) {
    return (uint32_t)f2bf(a) | ((uint32_t)f2bf(b) << 16);
}

// grid-partition constants
#define G_OFF_HE   (N_INC / 256)     // 6250
#define G_OFF_CELL (N_NODES / 256)   // 625
#define G_CONV_BIG ((D_IN * 64) / 256)  // 192
#define G_CONV_SM  ((64 * 64) / 256)    // 16
#define G_KA       256
#define G_KC       256
#define G_KD       256
#define G_PGEMM    ((VOCAB + 63) / 64)   // 469
#define G_GATHER   ((N_NODES * 16) / 256) // 10000
#define G_XTGEMM   (N_NODES / 64)    // 2500
#define G_X0GEMM   ((I_ * J_ + 63) / 64) // 13
#define G_HEDGE    (N_HE / 32)       // 10000 (8 hedges/wave, 4 waves/block)
#define G_NODE     (N_NODES / 32)    // 5000

// ---------------------------------------------------------------------------
// offsets from sorted index array
// ---------------------------------------------------------------------------
__device__ __forceinline__ void dev_offsets(int bid, const int* __restrict__ sorted,
                                            int n, int nbins, int* __restrict__ off) {
    int i = bid * 256 + threadIdx.x;
    if (i >= n) return;
    int cur = sorted[i];
    int prev = (i == 0) ? -1 : sorted[i - 1];
    for (int b = prev + 1; b <= cur; ++b) off[b] = i;
    if (i == n - 1) {
        for (int b = cur + 1; b <= nbins; ++b) off[b] = n;
    }
}

__device__ __forceinline__ void dev_convT(int bid, const float* __restrict__ B,
                                          u16* __restrict__ Bt, int K) {
    int g = bid * 256 + threadIdx.x;
    if (g >= K * 64) return;
    int k = g >> 6, n = g & 63;
    Bt[(size_t)n * K + k] = f2bf(B[g]);
}

// ---------------------------------------------------------------------------
// bucket-sort CSR build (no global random scatter)
// ---------------------------------------------------------------------------
__device__ __forceinline__ void dev_ka(int bid, const int* __restrict__ inc_node,
                                       int* __restrict__ counts, int* __restrict__ lds) {
    int tid = threadIdx.x;
    lds[tid] = 0;
    __syncthreads();
    int s = bid * EPB, e = s + EPB;
    for (int i = s + tid; i < e; i += 256)
        atomicAdd(&lds[(unsigned)inc_node[i] / NPR], 1);
    __syncthreads();
    counts[bid * NRANGE + tid] = lds[tid];
}

__device__ __forceinline__ void dev_kb(const int* __restrict__ counts,
                                       int* __restrict__ chunk_off,
                                       int* __restrict__ range_base,
                                       int* __restrict__ lds) {
    int r = threadIdx.x;
    int run = 0;
    for (int b = 0; b < 256; ++b) {
        chunk_off[b * NRANGE + r] = run;
        run += counts[b * NRANGE + r];
    }
    lds[r] = run;
    __syncthreads();
    int s = run;
    #pragma unroll
    for (int d = 1; d < 256; d <<= 1) {
        int t = (r >= d) ? lds[r - d] : 0;
        __syncthreads();
        lds[r] += t;
        __syncthreads();
    }
    int base = lds[r] - s;
    range_base[r] = base;
    if (r == 255) range_base[256] = lds[255];
    for (int b = 0; b < 256; ++b) chunk_off[b * NRANGE + r] += base;
}

__device__ __forceinline__ void dev_kc(int bid, const int* __restrict__ inc_node,
                                       const int* __restrict__ inc_hedge,
                                       const int* __restrict__ chunk_off,
                                       int2* __restrict__ bucket, int* __restrict__ lds) {
    int tid = threadIdx.x;
    lds[tid] = 0;
    __syncthreads();
    int s = bid * EPB, e = s + EPB;
    const int* co = chunk_off + bid * NRANGE;
    for (int i = s + tid; i < e; i += 256) {
        int v = inc_node[i];
        int h = inc_hedge[i];
        int rg = (unsigned)v / NPR;
        int rank = atomicAdd(&lds[rg], 1);
        bucket[co[rg] + rank] = make_int2(v, h);
    }
}

// lds layout: hist[768] | tsum[256] | cur[768]
__device__ __forceinline__ void dev_kd(int r, const int2* __restrict__ bucket,
                                       const int* __restrict__ range_base,
                                       int* __restrict__ node_off, int* __restrict__ csr,
                                       int* __restrict__ lds) {
    int tid = threadIdx.x;
    int* hist = lds;
    int* tsum = lds + 768;
    int* cur  = lds + 1024;
    for (int i = tid; i < 768; i += 256) { hist[i] = 0; cur[i] = 0; }
    __syncthreads();
    int lo = r * NPR;
    int pb = range_base[r], pe = range_base[r + 1];
    for (int i = pb + tid; i < pe; i += 256)
        atomicAdd(&hist[bucket[i].x - lo], 1);
    __syncthreads();
    int b3 = tid * 3;
    int a0 = hist[b3], a1 = hist[b3 + 1], a2 = hist[b3 + 2];
    int s = a0 + a1 + a2;
    tsum[tid] = s;
    __syncthreads();
    #pragma unroll
    for (int d = 1; d < 256; d <<= 1) {
        int t = (tid >= d) ? tsum[tid - d] : 0;
        __syncthreads();
        tsum[tid] += t;
        __syncthreads();
    }
    int excl = tsum[tid] - s;
    hist[b3]     = excl;
    hist[b3 + 1] = excl + a0;
    hist[b3 + 2] = excl + a0 + a1;
    __syncthreads();
    for (int v = tid; v < NPR; v += 256) node_off[lo + v] = pb + hist[v];
    if (r == NRANGE - 1 && tid == 0) node_off[N_NODES] = N_INC;
    for (int i = pb + tid; i < pe; i += 256) {
        int2 p = bucket[i];
        int l = p.x - lo;
        int k = atomicAdd(&cur[l], 1);
        csr[pb + hist[l] + k] = p.y;
    }
}

__device__ __forceinline__ void dev_gather_nf(int bid, const float4* __restrict__ P,
                                              const int* __restrict__ tok,
                                              float4* __restrict__ nf) {
    int g = bid * 256 + threadIdx.x;
    if (g >= N_NODES * 16) return;
    int n = g >> 4, p = g & 15;
    nf[g] = P[((size_t)tok[n] << 4) + p];
}

// MFMA GEMM: C[M,64] = A[M,K](f32->bf16) @ Bt[64,K](bf16) (+bias for f32 out)
template <int BF16_OUT>
__device__ __forceinline__ void dev_mfma_gemm(int bid, char* smem,
                                              const float* __restrict__ A,
                                              const u16* __restrict__ Bt,
                                              const float* __restrict__ bias,
                                              void* __restrict__ C, int M, int K) {
    u16* Alds = (u16*)smem;
    int tid = threadIdx.x;
    int wave = tid >> 6, lane = tid & 63;
    int m16 = lane & 15, q = lane >> 4;
    int row0 = bid << 6;

    f32x4 acc0 = {0.f, 0.f, 0.f, 0.f};
    f32x4 acc1 = {0.f, 0.f, 0.f, 0.f};
    f32x4 acc2 = {0.f, 0.f, 0.f, 0.f};
    f32x4 acc3 = {0.f, 0.f, 0.f, 0.f};

    for (int kt = 0; kt < K; kt += 32) {
        #pragma unroll
        for (int it = 0; it < 2; ++it) {
            int l = tid + it * 256;
            int r = l >> 3, c4 = (l & 7) << 2;
            int gr = row0 + r;
            float4 av = make_float4(0.f, 0.f, 0.f, 0.f);
            if (gr < M)
                av = *reinterpret_cast<const float4*>(A + (size_t)gr * K + kt + c4);
            ushort4 u;
            u.x = f2bf(av.x); u.y = f2bf(av.y); u.z = f2bf(av.z); u.w = f2bf(av.w);
            *reinterpret_cast<ushort4*>(&Alds[r * 40 + c4]) = u;
        }
        __syncthreads();

        short8 a = *reinterpret_cast<const short8*>(&Alds[(wave * 16 + m16) * 40 + q * 8]);
        const u16* bp = Bt + (size_t)m16 * K + kt + q * 8;
        short8 b0 = *reinterpret_cast<const short8*>(bp);
        short8 b1 = *reinterpret_cast<const short8*>(bp + (size_t)16 * K);
        short8 b2 = *reinterpret_cast<const short8*>(bp + (size_t)32 * K);
        short8 b3 = *reinterpret_cast<const short8*>(bp + (size_t)48 * K);

        acc0 = __builtin_amdgcn_mfma_f32_16x16x32_bf16(a, b0, acc0, 0, 0, 0);
        acc1 = __builtin_amdgcn_mfma_f32_16x16x32_bf16(a, b1, acc1, 0, 0, 0);
        acc2 = __builtin_amdgcn_mfma_f32_16x16x32_bf16(a, b2, acc2, 0, 0, 0);
        acc3 = __builtin_amdgcn_mfma_f32_16x16x32_bf16(a, b3, acc3, 0, 0, 0);
        __syncthreads();
    }

    f32x4 accs[4] = {acc0, acc1, acc2, acc3};
    #pragma unroll
    for (int r = 0; r < 4; ++r) {
        int gr = row0 + wave * 16 + q * 4 + r;
        if (gr >= M) continue;
        #pragma unroll
        for (int j = 0; j < 4; ++j) {
            int col = j * 16 + m16;
            float v = accs[j][r];
            if (!BF16_OUT) v += bias[col];
            if (BF16_OUT)
                ((u16*)C)[(size_t)gr * 64 + col] = f2bf(v);
            else
                ((float*)C)[(size_t)gr * 64 + col] = v;
        }
    }
}

// ---------------------------------------------------------------------------
// hedge_sum: one 8-lane subgroup per hedge (8 hedges/wave, no cross-lane
// reduction). Each lane owns 8 columns (16 B); subgroup iterates its own
// adjacency serially with prefetched index.
// ---------------------------------------------------------------------------
__device__ __forceinline__ void dev_hedge_sum(int bid, const int* __restrict__ inc_node,
                                              const int* __restrict__ he_off,
                                              const u16* __restrict__ xt,
                                              u16* __restrict__ he) {
    int w = (bid * 256 + (int)threadIdx.x) >> 6;   // wave id
    int lane = threadIdx.x & 63;
    int sub = lane >> 3;            // subgroup 0..7 -> hedge
    int c8 = (lane & 7) << 3;       // 8 bf16 columns
    int hedge = w * 8 + sub;
    if (hedge >= N_HE) return;
    int s = he_off[hedge], e = he_off[hedge + 1];

    float a0 = 0.f, a1 = 0.f, a2 = 0.f, a3 = 0.f;
    float a4 = 0.f, a5 = 0.f, a6 = 0.f, a7 = 0.f;

    int idx = (s < e) ? inc_node[s] : 0;
    for (int j = s; j < e; ++j) {
        int cur = idx;
        if (j + 1 < e) idx = inc_node[j + 1];
        uint4 d = *reinterpret_cast<const uint4*>(xt + (((size_t)cur) << 6) + c8);
        a0 += lo_bf(d.x); a1 += hi_bf(d.x);
        a2 += lo_bf(d.y); a3 += hi_bf(d.y);
        a4 += lo_bf(d.z); a5 += hi_bf(d.z);
        a6 += lo_bf(d.w); a7 += hi_bf(d.w);
    }

    float inv = (e > s) ? 1.f / (float)(e - s) : 0.f;
    uint4 o;
    o.x = pack_bf2(a0 * inv, a1 * inv);
    o.y = pack_bf2(a2 * inv, a3 * inv);
    o.z = pack_bf2(a4 * inv, a5 * inv);
    o.w = pack_bf2(a6 * inv, a7 * inv);
    *reinterpret_cast<uint4*>(he + (((size_t)hedge) << 6) + c8) = o;
}

// node_sum: same subgroup-per-node mapping (8 nodes/wave)
__device__ __forceinline__ void dev_node_sum(int bid, const int* __restrict__ csr,
                                             const int* __restrict__ node_off,
                                             const u16* __restrict__ he,
                                             const float* __restrict__ bias,
                                             const float* __restrict__ nf,
                                             float* __restrict__ out) {
    int w = (bid * 256 + (int)threadIdx.x) >> 6;
    int lane = threadIdx.x & 63;
    int sub = lane >> 3;
    int c8 = (lane & 7) << 3;
    int node = w * 8 + sub;
    if (node >= N_NODES) return;
    int s = node_off[node], e = node_off[node + 1];

    float a0 = 0.f, a1 = 0.f, a2 = 0.f, a3 = 0.f;
    float a4 = 0.f, a5 = 0.f, a6 = 0.f, a7 = 0.f;

    int idx = (s < e) ? csr[s] : 0;
    for (int j = s; j < e; ++j) {
        int cur = idx;
        if (j + 1 < e) idx = csr[j + 1];
        uint4 d = *reinterpret_cast<const uint4*>(he + (((size_t)cur) << 6) + c8);
        a0 += lo_bf(d.x); a1 += hi_bf(d.x);
        a2 += lo_bf(d.y); a3 += hi_bf(d.y);
        a4 += lo_bf(d.z); a5 += hi_bf(d.z);
        a6 += lo_bf(d.w); a7 += hi_bf(d.w);
    }

    float inv = (e > s) ? 1.f / (float)(e - s) : 0.f;
    const float* nfp = nf + (((size_t)node) << 6) + c8;
    float4 nv0 = *reinterpret_cast<const float4*>(nfp);
    float4 nv1 = *reinterpret_cast<const float4*>(nfp + 4);
    float4 o0, o1;
    o0.x = fmaxf(fmaf(a0, inv, bias[c8 + 0]), 0.f) + nv0.x;
    o0.y = fmaxf(fmaf(a1, inv, bias[c8 + 1]), 0.f) + nv0.y;
    o0.z = fmaxf(fmaf(a2, inv, bias[c8 + 2]), 0.f) + nv0.z;
    o0.w = fmaxf(fmaf(a3, inv, bias[c8 + 3]), 0.f) + nv0.w;
    o1.x = fmaxf(fmaf(a4, inv, bias[c8 + 4]), 0.f) + nv1.x;
    o1.y = fmaxf(fmaf(a5, inv, bias[c8 + 5]), 0.f) + nv1.y;
    o1.z = fmaxf(fmaf(a6, inv, bias[c8 + 6]), 0.f) + nv1.z;
    o1.w = fmaxf(fmaf(a7, inv, bias[c8 + 7]), 0.f) + nv1.w;
    float* op = out + (((size_t)node) << 6) + c8;
    *reinterpret_cast<float4*>(op) = o0;
    *reinterpret_cast<float4*>(op + 4) = o1;
}

// ---------------------------------------------------------------------------
// phase mega-kernels
// ---------------------------------------------------------------------------
__global__ __launch_bounds__(256) void k_p1(const int* __restrict__ inc_hedge,
                                            const int* __restrict__ node2cell,
                                            const int* __restrict__ inc_node,
                                            int* __restrict__ he_off, int* __restrict__ cell_off,
                                            int* __restrict__ counts,
                                            const float* __restrict__ fhi_w, const float* __restrict__ fin_w,
                                            const float* __restrict__ th1, const float* __restrict__ th2,
                                            u16* __restrict__ Bt_fhi, u16* __restrict__ Bt_fin,
                                            u16* __restrict__ Bt_th1, u16* __restrict__ Bt_th2) {
    __shared__ int lds[256];
    int bid = blockIdx.x;
    if (bid < G_OFF_HE) { dev_offsets(bid, inc_hedge, N_INC, N_HE, he_off); return; }
    bid -= G_OFF_HE;
    if (bid < G_KA) { dev_ka(bid, inc_node, counts, lds); return; }
    bid -= G_KA;
    if (bid < G_OFF_CELL) { dev_offsets(bid, node2cell, N_NODES, N_CELLS, cell_off); return; }
    bid -= G_OFF_CELL;
    if (bid < G_CONV_BIG) { dev_convT(bid, fhi_w, Bt_fhi, D_IN); return; }
    bid -= G_CONV_BIG;
    if (bid < G_CONV_BIG) { dev_convT(bid, fin_w, Bt_fin, D_IN); return; }
    bid -= G_CONV_BIG;
    if (bid < G_CONV_SM) { dev_convT(bid, th1, Bt_th1, 64); return; }
    bid -= G_CONV_SM;
    dev_convT(bid, th2, Bt_th2, 64);
}

__global__ __launch_bounds__(256) void k_p2(const int* __restrict__ counts,
                                            int* __restrict__ chunk_off, int* __restrict__ range_base,
                                            const float* __restrict__ vac_emb,
                                            const u16* __restrict__ Bt_fhi,
                                            const float* __restrict__ fhi_b, float* __restrict__ P) {
    __shared__ __align__(16) char smem[8192];
    int bid = blockIdx.x;
    if (bid < G_PGEMM) { dev_mfma_gemm<0>(bid, smem, vac_emb, Bt_fhi, fhi_b, P, VOCAB, D_IN); return; }
    dev_kb(counts, chunk_off, range_base, (int*)smem);
}

__global__ __launch_bounds__(256) void k_p3(const int* __restrict__ inc_node,
                                            const int* __restrict__ inc_hedge,
                                            const int* __restrict__ chunk_off,
                                            int2* __restrict__ bucket,
                                            const float4* __restrict__ P,
                                            const int* __restrict__ tok, float4* __restrict__ nf) {
    __shared__ int lds[256];
    int bid = blockIdx.x;
    if (bid < G_GATHER) { dev_gather_nf(bid, P, tok, nf); return; }
    bid -= G_GATHER;
    dev_kc(bid, inc_node, inc_hedge, chunk_off, bucket, lds);
}

__global__ __launch_bounds__(256) void k_p4(const int2* __restrict__ bucket,
                                            const int* __restrict__ range_base,
                                            int* __restrict__ node_off, int* __restrict__ csr,
                                            const float* __restrict__ nf, const u16* __restrict__ Bt_th1,
                                            u16* __restrict__ xt,
                                            const float* __restrict__ x, const u16* __restrict__ Bt_fin,
                                            const float* __restrict__ fin_b, float* __restrict__ x0) {
    __shared__ __align__(16) char smem[8192];
    int bid = blockIdx.x;
    if (bid < G_KD) { dev_kd(bid, bucket, range_base, node_off, csr, (int*)smem); return; }
    bid -= G_KD;
    if (bid < G_XTGEMM) { dev_mfma_gemm<1>(bid, smem, nf, Bt_th1, nullptr, xt, N_NODES, 64); return; }
    bid -= G_XTGEMM;
    dev_mfma_gemm<0>(bid, smem, x, Bt_fin, fin_b, x0, I_ * J_, D_IN);
}

// standalone wrappers
template <int BF16_OUT>
__global__ __launch_bounds__(256) void k_mfma_gemm(const float* __restrict__ A,
                                                   const u16* __restrict__ Bt,
                                                   const float* __restrict__ bias,
                                                   void* __restrict__ C, int M, int K) {
    __shared__ __align__(16) char smem[8192];
    dev_mfma_gemm<BF16_OUT>(blockIdx.x, smem, A, Bt, bias, C, M, K);
}

__global__ __launch_bounds__(256) void k_hedge_sum(const int* __restrict__ inc_node,
                                                   const int* __restrict__ he_off,
                                                   const u16* __restrict__ xt,
                                                   u16* __restrict__ he) {
    dev_hedge_sum(blockIdx.x, inc_node, he_off, xt, he);
}

__global__ __launch_bounds__(256) void k_node_sum(const int* __restrict__ csr,
                                                  const int* __restrict__ node_off,
                                                  const u16* __restrict__ he,
                                                  const float* __restrict__ bias,
                                                  const float* __restrict__ nf,
                                                  float* __restrict__ out) {
    dev_node_sum(blockIdx.x, csr, node_off, he, bias, nf, out);
}

// ---------------------------------------------------------------------------
// per-cell mean+max pooling, fused x_upd = x0 + 0.3*cell_emb
// ---------------------------------------------------------------------------
__global__ __launch_bounds__(256) void k_pool(const float* __restrict__ gx,
                                              const int* __restrict__ cell_off,
                                              const float* __restrict__ x0,
                                              float* __restrict__ out1) {
    __shared__ float ssum[4][64];
    __shared__ float smax[4][64];
    int c = blockIdx.x;
    int lane = threadIdx.x & 63;
    int w = threadIdx.x >> 6;
    int s = cell_off[c], e = cell_off[c + 1];
    float sum = 0.f, mx = -INFINITY;
    for (int n = s + w; n < e; n += 4) {
        float v = gx[((size_t)n << 6) + lane];
        sum += v;
        mx = fmaxf(mx, v);
    }
    ssum[w][lane] = sum;
    smax[w][lane] = mx;
    __syncthreads();
    if (w == 0) {
        sum = ssum[0][lane] + ssum[1][lane] + ssum[2][lane] + ssum[3][lane];
        mx = fmaxf(fmaxf(smax[0][lane], smax[1][lane]), fmaxf(smax[2][lane], smax[3][lane]));
        int cnt = e - s;
        float mean = (cnt > 0) ? sum / (float)cnt : 0.f;
        float mp = (cnt > 0) ? mx : 0.f;
        float ce = 0.5f * (mean + mp);
        out1[((size_t)c << 6) + lane] = x0[((size_t)c << 6) + lane] + 0.3f * ce;
    }
}

// ---------------------------------------------------------------------------
// fused TCN
// ---------------------------------------------------------------------------
__global__ __launch_bounds__(256) void k_tcn(
    const float* __restrict__ xu,
    const float* __restrict__ wc1, const float* __restrict__ bc1, const float* __restrict__ g1,
    const float* __restrict__ be1, const float* __restrict__ m1, const float* __restrict__ v1,
    const float* __restrict__ wc2, const float* __restrict__ bc2, const float* __restrict__ g2,
    const float* __restrict__ be2, const float* __restrict__ m2, const float* __restrict__ v2,
    const float* __restrict__ wc3, const float* __restrict__ bc3, const float* __restrict__ g3,
    const float* __restrict__ be3, const float* __restrict__ m3, const float* __restrict__ v3,
    const float* __restrict__ fct_w, const float* __restrict__ fct_b,
    float* __restrict__ out2) {
    __shared__ float w_lds[64 * 64 * 3];
    __shared__ float hA[64][10];
    __shared__ float hB[64][10];
    __shared__ float mo[64];

    int n = blockIdx.x, tid = threadIdx.x;

    if (tid < 64) {
        hA[tid][0] = 0.f; hA[tid][9] = 0.f;
        hB[tid][0] = 0.f; hB[tid][9] = 0.f;
    }
    #pragma unroll
    for (int l = tid; l < 512; l += 256) {
        int t = l >> 6, i = l & 63;
        hA[i][t + 1] = xu[(size_t)n * 512 + l];
    }

    const float* wcs[3] = {wc1, wc2, wc3};
    const float* bcs[3] = {bc1, bc2, bc3};
    const float* gs[3]  = {g1, g2, g3};
    const float* bes[3] = {be1, be2, be3};
    const float* ms[3]  = {m1, m2, m3};
    const float* vs[3]  = {v1, v2, v3};

    float (*hin)[10] = hA;
    float (*hout)[10] = hB;

    #pragma unroll
    for (int li = 0; li < 3; ++li) {
        for (int l = tid; l < 64 * 64 * 3; l += 256) w_lds[l] = wcs[li][l];
        __syncthreads();
        #pragma unroll
        for (int rep = 0; rep < 2; ++rep) {
            int idx = tid + rep * 256;
            int o = idx >> 3, t = idx & 7;
            float acc = bcs[li][o];
            #pragma unroll 8
            for (int i = 0; i < 64; ++i) {
                const float* wr = &w_lds[o * 192 + i * 3];
                acc = fmaf(hin[i][t + 0], wr[0], acc);
                acc = fmaf(hin[i][t + 1], wr[1], acc);
                acc = fmaf(hin[i][t + 2], wr[2], acc);
            }
            acc = fmaxf(acc, 0.f);
            float sc = gs[li][o] * rsqrtf(vs[li][o] + 1e-5f);
            acc = (acc - ms[li][o]) * sc + bes[li][o];
            hout[o][t + 1] = acc;
        }
        __syncthreads();
        float (*tmp)[10] = hin; hin = hout; hout = tmp;
    }

    if (tid < 64) {
        float s = 0.f;
        #pragma unroll
        for (int t = 0; t < 8; ++t) s += hin[tid][t + 1];
        mo[tid] = s * 0.125f;
    }
    __syncthreads();
    if (tid < 64) {
        float acc = fct_b[tid];
        #pragma unroll 8
        for (int o = 0; o < 64; ++o) acc = fmaf(mo[o], fct_w[o * 64 + tid], acc);
        out2[(size_t)n * 64 + tid] = acc;
    }
}

// ---------------------------------------------------------------------------
extern "C" void kernel_launch(void* const* d_in, const int* in_sizes, int n_in,
                              void* d_out, int out_size, void* d_ws, size_t ws_size,
                              hipStream_t stream) {
    (void)in_sizes; (void)n_in; (void)out_size; (void)ws_size;

    const float* x          = (const float*)d_in[0];
    const int*   node_tok   = (const int*)d_in[1];
    const int*   inc_node   = (const int*)d_in[2];
    const int*   inc_hedge  = (const int*)d_in[3];
    const int*   node2cell  = (const int*)d_in[4];
    const float* vac_emb    = (const float*)d_in[5];
    const float* fhi_w      = (const float*)d_in[6];
    const float* fhi_b      = (const float*)d_in[7];
    const float* fin_w      = (const float*)d_in[8];
    const float* fin_b      = (const float*)d_in[9];
    const float* th1        = (const float*)d_in[10];
    const float* b1         = (const float*)d_in[11];
    const float* th2        = (const float*)d_in[12];
    const float* b2         = (const float*)d_in[13];
    const float* fct_w      = (const float*)d_in[32];
    const float* fct_b      = (const float*)d_in[33];

    char* ws = (char*)d_ws;
    size_t off = 0;
    float* P        = (float*)(ws + off); off += (size_t)VOCAB * 64 * 4;
    float* nf       = (float*)(ws + off); off += (size_t)N_NODES * 64 * 4;
    float* hbuf     = (float*)(ws + off); off += (size_t)N_NODES * 64 * 4;
    u16*   xt       = (u16*)(ws + off);   off += (size_t)N_NODES * 64 * 2;
    u16*   he       = (u16*)(ws + off);   off += (size_t)N_HE * 64 * 2;
    float* x0       = (float*)(ws + off); off += (size_t)N_CELLS * 64 * 4;
    u16*   Bt_fhi   = (u16*)(ws + off);   off += (size_t)64 * D_IN * 2;
    u16*   Bt_fin   = (u16*)(ws + off);   off += (size_t)64 * D_IN * 2;
    u16*   Bt_th1   = (u16*)(ws + off);   off += (size_t)64 * 64 * 2;
    u16*   Bt_th2   = (u16*)(ws + off);   off += (size_t)64 * 64 * 2;
    int*   he_off   = (int*)(ws + off);   off += ((size_t)(N_HE + 1) * 4 + 255) / 256 * 256;
    int*   node_off = (int*)(ws + off);   off += ((size_t)(N_NODES + 1) * 4 + 255) / 256 * 256;
    int*   csr      = (int*)(ws + off);   off += (size_t)N_INC * 4;
    int*   cell_off = (int*)(ws + off);   off += ((size_t)(N_CELLS + 1) * 4 + 255) / 256 * 256;

    // aliases: bucket (12.8 MB) aliases he; counts/chunk_off/range_base alias hbuf
    int2* bucket     = (int2*)he;
    int*  counts     = (int*)hbuf;
    int*  chunk_off  = counts + 256 * 256;
    int*  range_base = chunk_off + 256 * 256;

    float* out1 = (float*)d_out;
    float* out2 = out1 + (size_t)I_ * J_ * D_H;

    // P1: offsets(hedge) + Ka + offsets(cell) + 4x convT
    k_p1<<<G_OFF_HE + G_KA + G_OFF_CELL + 2 * G_CONV_BIG + 2 * G_CONV_SM, 256, 0, stream>>>(
        inc_hedge, node2cell, inc_node, he_off, cell_off, counts,
        fhi_w, fin_w, th1, th2, Bt_fhi, Bt_fin, Bt_th1, Bt_th2);

    // P2: P-GEMM + Kb
    k_p2<<<G_PGEMM + 1, 256, 0, stream>>>(counts, chunk_off, range_base, vac_emb, Bt_fhi, fhi_b, P);

    // P3: gather_nf + Kc
    k_p3<<<G_GATHER + G_KC, 256, 0, stream>>>(inc_node, inc_hedge, chunk_off, bucket,
                                              (const float4*)P, node_tok, (float4*)nf);

    // P4: Kd (csr + node_off) + xt-GEMM L1 + x0-GEMM
    k_p4<<<G_KD + G_XTGEMM + G_X0GEMM, 256, 0, stream>>>(bucket, range_base, node_off, csr,
                                                         nf, Bt_th1, xt, x, Bt_fin, fin_b, x0);

    // P5: hedge_sum L1
    k_hedge_sum<<<G_HEDGE, 256, 0, stream>>>(inc_node, he_off, xt, he);

    // P6: node_sum L1 -> hbuf = h1
    k_node_sum<<<G_NODE, 256, 0, stream>>>(csr, node_off, he, b1, nf, hbuf);

    // P7: xt-GEMM L2
    k_mfma_gemm<1><<<G_XTGEMM, 256, 0, stream>>>(hbuf, Bt_th2, nullptr, xt, N_NODES, 64);

    // P8: hedge_sum L2
    k_hedge_sum<<<G_HEDGE, 256, 0, stream>>>(inc_node, he_off, xt, he);

    // P9: node_sum L2 -> hbuf = gx
    k_node_sum<<<G_NODE, 256, 0, stream>>>(csr, node_off, he, b2, nf, hbuf);

    // P10: pool + fuse -> out1
    k_pool<<<N_CELLS, 256, 0, stream>>>(hbuf, cell_off, x0, out1);

    // P11: TCN -> out2
    k_tcn<<<I_, 256, 0, stream>>>(out1,
        (const float*)d_in[14], (const float*)d_in[15], (const float*)d_in[16],
        (const float*)d_in[17], (const float*)d_in[18], (const float*)d_in[19],
        (const float*)d_in[20], (const float*)d_in[21], (const float*)d_in[22],
        (const float*)d_in[23], (const float*)d_in[24], (const float*)d_in[25],
        (const float*)d_in[26], (const float*)d_in[27], (const float*)d_in[28],
        (const float*)d_in[29], (const float*)d_in[30], (const float*)d_in[31],
        fct_w, fct_b, out2);
}

// Round 8
// 544.822 us; speedup vs baseline: 2.5860x; 1.1091x over previous
//
#include <hip/hip_runtime.h>
#include <hip/hip_bf16.h>
#include <cstdint>
#include <cstddef>

#define I_      100
#define J_      8
#define D_IN    768
#define D_H     64
#define N_NODES 160000
#define N_HE    320000
#define N_INC   1600000
#define N_CELLS 800
#define VOCAB   30000

#define NRANGE   256
#define NPR      625
#define EPB      (N_INC / 256)

typedef unsigned short u16;
using short8 = __attribute__((ext_vector_type(8))) short;
using f32x4  = __attribute__((ext_vector_type(4))) float;

__device__ __forceinline__ float bf2f(u16 u) {
    union { uint32_t i; float f; } x; x.i = ((uint32_t)u) << 16; return x.f;
}
__device__ __forceinline__ u16 f2bf(float f) {
    union { float f; uint32_t i; } x; x.f = f;
    uint32_t b = x.i;
    b += 0x7FFFu + ((b >> 16) & 1u);
    return (u16)(b >> 16);
}
__device__ __forceinline__ float lo_bf(uint32_t u) {
    union { uint32_t i; float f; } x; x.i = u << 16; return x.f;
}
__device__ __forceinline__ float hi_bf(uint32_t u) {
    union { uint32_t i; float f; } x; x.i = u & 0xFFFF0000u; return x.f;
}
__device__ __forceinline__ uint32_t pack_bf2(float a, float b) {
    return (uint32_t)f2bf(a) | ((uint32_t)f2bf(b) << 16);
}

// grid-partition constants
#define G_OFF_HE   (N_INC / 256)        // 6250
#define G_OFF_CELL (N_NODES / 256)      // 625
#define G_CONV_BIG ((D_IN * 64) / 256)  // 192
#define G_CONV_SM  ((64 * 64) / 256)    // 16
#define G_KA       256
#define G_KC       256
#define G_KD       256
#define G_PGEMM    ((VOCAB + 63) / 64)  // 469  (16 rows/wave, 4 waves/block)
#define G_XT       (N_NODES / 64)       // 2500
#define G_X0       ((I_ * J_ + 63) / 64)// 13
#define G_HEDGE    (N_HE / 32)          // 10000 (8 hedges/wave)
#define G_NODE     (N_NODES / 32)       // 5000

// ---------------------------------------------------------------------------
__device__ __forceinline__ void dev_offsets(int bid, const int* __restrict__ sorted,
                                            int n, int nbins, int* __restrict__ off) {
    int i = bid * 256 + threadIdx.x;
    if (i >= n) return;
    int cur = sorted[i];
    int prev = (i == 0) ? -1 : sorted[i - 1];
    for (int b = prev + 1; b <= cur; ++b) off[b] = i;
    if (i == n - 1) {
        for (int b = cur + 1; b <= nbins; ++b) off[b] = n;
    }
}

__device__ __forceinline__ void dev_convT(int bid, const float* __restrict__ B,
                                          u16* __restrict__ Bt, int K) {
    int g = bid * 256 + threadIdx.x;
    if (g >= K * 64) return;
    int k = g >> 6, n = g & 63;
    Bt[(size_t)n * K + k] = f2bf(B[g]);
}

// ---------------------------------------------------------------------------
// bucket-sort CSR build
// ---------------------------------------------------------------------------
__device__ __forceinline__ void dev_ka(int bid, const int* __restrict__ inc_node,
                                       int* __restrict__ counts, int* __restrict__ lds) {
    int tid = threadIdx.x;
    lds[tid] = 0;
    __syncthreads();
    int s = bid * EPB, e = s + EPB;
    for (int i = s + tid; i < e; i += 256)
        atomicAdd(&lds[(unsigned)inc_node[i] / NPR], 1);
    __syncthreads();
    counts[bid * NRANGE + tid] = lds[tid];
}

__device__ __forceinline__ void dev_kb(const int* __restrict__ counts,
                                       int* __restrict__ chunk_off,
                                       int* __restrict__ range_base,
                                       int* __restrict__ lds) {
    int r = threadIdx.x;
    int run = 0;
    for (int b = 0; b < 256; ++b) {
        chunk_off[b * NRANGE + r] = run;
        run += counts[b * NRANGE + r];
    }
    lds[r] = run;
    __syncthreads();
    int s = run;
    #pragma unroll
    for (int d = 1; d < 256; d <<= 1) {
        int t = (r >= d) ? lds[r - d] : 0;
        __syncthreads();
        lds[r] += t;
        __syncthreads();
    }
    int base = lds[r] - s;
    range_base[r] = base;
    if (r == 255) range_base[256] = lds[255];
    for (int b = 0; b < 256; ++b) chunk_off[b * NRANGE + r] += base;
}

__device__ __forceinline__ void dev_kc(int bid, const int* __restrict__ inc_node,
                                       const int* __restrict__ inc_hedge,
                                       const int* __restrict__ chunk_off,
                                       int2* __restrict__ bucket, int* __restrict__ lds) {
    int tid = threadIdx.x;
    lds[tid] = 0;
    __syncthreads();
    int s = bid * EPB, e = s + EPB;
    const int* co = chunk_off + bid * NRANGE;
    for (int i = s + tid; i < e; i += 256) {
        int v = inc_node[i];
        int h = inc_hedge[i];
        int rg = (unsigned)v / NPR;
        int rank = atomicAdd(&lds[rg], 1);
        bucket[co[rg] + rank] = make_int2(v, h);
    }
}

// lds layout: hist[768] | tsum[256] | cur[768]  (1792 ints)
__device__ __forceinline__ void dev_kd(int r, const int2* __restrict__ bucket,
                                       const int* __restrict__ range_base,
                                       int* __restrict__ node_off, int* __restrict__ csr,
                                       int* __restrict__ lds) {
    int tid = threadIdx.x;
    int* hist = lds;
    int* tsum = lds + 768;
    int* cur  = lds + 1024;
    for (int i = tid; i < 768; i += 256) { hist[i] = 0; cur[i] = 0; }
    __syncthreads();
    int lo = r * NPR;
    int pb = range_base[r], pe = range_base[r + 1];
    for (int i = pb + tid; i < pe; i += 256)
        atomicAdd(&hist[bucket[i].x - lo], 1);
    __syncthreads();
    int b3 = tid * 3;
    int a0 = hist[b3], a1 = hist[b3 + 1], a2 = hist[b3 + 2];
    int s = a0 + a1 + a2;
    tsum[tid] = s;
    __syncthreads();
    #pragma unroll
    for (int d = 1; d < 256; d <<= 1) {
        int t = (tid >= d) ? tsum[tid - d] : 0;
        __syncthreads();
        tsum[tid] += t;
        __syncthreads();
    }
    int excl = tsum[tid] - s;
    hist[b3]     = excl;
    hist[b3 + 1] = excl + a0;
    hist[b3 + 2] = excl + a0 + a1;
    __syncthreads();
    for (int v = tid; v < NPR; v += 256) node_off[lo + v] = pb + hist[v];
    if (r == NRANGE - 1 && tid == 0) node_off[N_NODES] = N_INC;
    for (int i = pb + tid; i < pe; i += 256) {
        int2 p = bucket[i];
        int l = p.x - lo;
        int k = atomicAdd(&cur[l], 1);
        csr[pb + hist[l] + k] = p.y;
    }
}

// ---------------------------------------------------------------------------
// barrier-free direct MFMA GEMM: one wave owns 16 rows; A-frag loaded straight
// from global (f32 -> bf16 in regs); B from L2-resident Bt[64][K].
// GATHER: A-row = A + (tok[row] << 6)  (K must be 64)
// ---------------------------------------------------------------------------
template <int BF16_OUT, int GATHER, int KK>
__device__ __forceinline__ void dev_gemm_direct(int wid, const float* __restrict__ A,
                                                const int* __restrict__ tok,
                                                const u16* __restrict__ Bt,
                                                const float* __restrict__ bias,
                                                void* __restrict__ C, int M) {
    int lane = threadIdx.x & 63;
    int m16 = lane & 15, q = lane >> 4;
    int base = wid << 4;
    if (base >= M) return;            // M is a multiple of 16 for all call sites
    int row = base + m16;
    const float* arow = GATHER ? (A + ((size_t)tok[row] << 6))
                               : (A + (size_t)row * KK);

    f32x4 acc0 = {0.f, 0.f, 0.f, 0.f};
    f32x4 acc1 = {0.f, 0.f, 0.f, 0.f};
    f32x4 acc2 = {0.f, 0.f, 0.f, 0.f};
    f32x4 acc3 = {0.f, 0.f, 0.f, 0.f};

    #pragma unroll 2
    for (int kt = 0; kt < KK; kt += 32) {
        const float* ap = arow + kt + q * 8;
        float4 av0 = *reinterpret_cast<const float4*>(ap);
        float4 av1 = *reinterpret_cast<const float4*>(ap + 4);
        short8 a;
        a[0] = (short)f2bf(av0.x); a[1] = (short)f2bf(av0.y);
        a[2] = (short)f2bf(av0.z); a[3] = (short)f2bf(av0.w);
        a[4] = (short)f2bf(av1.x); a[5] = (short)f2bf(av1.y);
        a[6] = (short)f2bf(av1.z); a[7] = (short)f2bf(av1.w);
        const u16* bp = Bt + (size_t)m16 * KK + kt + q * 8;
        short8 b0 = *reinterpret_cast<const short8*>(bp);
        short8 b1 = *reinterpret_cast<const short8*>(bp + (size_t)16 * KK);
        short8 b2 = *reinterpret_cast<const short8*>(bp + (size_t)32 * KK);
        short8 b3 = *reinterpret_cast<const short8*>(bp + (size_t)48 * KK);
        acc0 = __builtin_amdgcn_mfma_f32_16x16x32_bf16(a, b0, acc0, 0, 0, 0);
        acc1 = __builtin_amdgcn_mfma_f32_16x16x32_bf16(a, b1, acc1, 0, 0, 0);
        acc2 = __builtin_amdgcn_mfma_f32_16x16x32_bf16(a, b2, acc2, 0, 0, 0);
        acc3 = __builtin_amdgcn_mfma_f32_16x16x32_bf16(a, b3, acc3, 0, 0, 0);
    }

    f32x4 accs[4] = {acc0, acc1, acc2, acc3};
    #pragma unroll
    for (int r = 0; r < 4; ++r) {
        int gr = base + q * 4 + r;
        #pragma unroll
        for (int j = 0; j < 4; ++j) {
            int col = j * 16 + m16;
            float v = accs[j][r];
            if (!BF16_OUT) v += bias[col];
            if (BF16_OUT)
                ((u16*)C)[(size_t)gr * 64 + col] = f2bf(v);
            else
                ((float*)C)[(size_t)gr * 64 + col] = v;
        }
    }
}

// ---------------------------------------------------------------------------
// hedge_sum: one 8-lane subgroup per hedge (8 hedges/wave)
// ---------------------------------------------------------------------------
__device__ __forceinline__ void dev_hedge_sum(int bid, const int* __restrict__ inc_node,
                                              const int* __restrict__ he_off,
                                              const u16* __restrict__ xt,
                                              u16* __restrict__ he) {
    int w = (bid * 256 + (int)threadIdx.x) >> 6;
    int lane = threadIdx.x & 63;
    int sub = lane >> 3;
    int c8 = (lane & 7) << 3;
    int hedge = w * 8 + sub;
    if (hedge >= N_HE) return;
    int s = he_off[hedge], e = he_off[hedge + 1];

    float a0 = 0.f, a1 = 0.f, a2 = 0.f, a3 = 0.f;
    float a4 = 0.f, a5 = 0.f, a6 = 0.f, a7 = 0.f;

    int idx = (s < e) ? inc_node[s] : 0;
    for (int j = s; j < e; ++j) {
        int cur = idx;
        if (j + 1 < e) idx = inc_node[j + 1];
        uint4 d = *reinterpret_cast<const uint4*>(xt + (((size_t)cur) << 6) + c8);
        a0 += lo_bf(d.x); a1 += hi_bf(d.x);
        a2 += lo_bf(d.y); a3 += hi_bf(d.y);
        a4 += lo_bf(d.z); a5 += hi_bf(d.z);
        a6 += lo_bf(d.w); a7 += hi_bf(d.w);
    }

    float inv = (e > s) ? 1.f / (float)(e - s) : 0.f;
    uint4 o;
    o.x = pack_bf2(a0 * inv, a1 * inv);
    o.y = pack_bf2(a2 * inv, a3 * inv);
    o.z = pack_bf2(a4 * inv, a5 * inv);
    o.w = pack_bf2(a6 * inv, a7 * inv);
    *reinterpret_cast<uint4*>(he + (((size_t)hedge) << 6) + c8) = o;
}

// node_sum with residual gathered from P[tok[node]] (nf eliminated)
__device__ __forceinline__ void dev_node_sum(int bid, const int* __restrict__ csr,
                                             const int* __restrict__ node_off,
                                             const u16* __restrict__ he,
                                             const float* __restrict__ bias,
                                             const float* __restrict__ P,
                                             const int* __restrict__ tok,
                                             float* __restrict__ out) {
    int w = (bid * 256 + (int)threadIdx.x) >> 6;
    int lane = threadIdx.x & 63;
    int sub = lane >> 3;
    int c8 = (lane & 7) << 3;
    int node = w * 8 + sub;
    if (node >= N_NODES) return;
    int s = node_off[node], e = node_off[node + 1];

    float a0 = 0.f, a1 = 0.f, a2 = 0.f, a3 = 0.f;
    float a4 = 0.f, a5 = 0.f, a6 = 0.f, a7 = 0.f;

    int idx = (s < e) ? csr[s] : 0;
    for (int j = s; j < e; ++j) {
        int cur = idx;
        if (j + 1 < e) idx = csr[j + 1];
        uint4 d = *reinterpret_cast<const uint4*>(he + (((size_t)cur) << 6) + c8);
        a0 += lo_bf(d.x); a1 += hi_bf(d.x);
        a2 += lo_bf(d.y); a3 += hi_bf(d.y);
        a4 += lo_bf(d.z); a5 += hi_bf(d.z);
        a6 += lo_bf(d.w); a7 += hi_bf(d.w);
    }

    float inv = (e > s) ? 1.f / (float)(e - s) : 0.f;
    const float* nfp = P + (((size_t)tok[node]) << 6) + c8;   // residual from P
    float4 nv0 = *reinterpret_cast<const float4*>(nfp);
    float4 nv1 = *reinterpret_cast<const float4*>(nfp + 4);
    float4 o0, o1;
    o0.x = fmaxf(fmaf(a0, inv, bias[c8 + 0]), 0.f) + nv0.x;
    o0.y = fmaxf(fmaf(a1, inv, bias[c8 + 1]), 0.f) + nv0.y;
    o0.z = fmaxf(fmaf(a2, inv, bias[c8 + 2]), 0.f) + nv0.z;
    o0.w = fmaxf(fmaf(a3, inv, bias[c8 + 3]), 0.f) + nv0.w;
    o1.x = fmaxf(fmaf(a4, inv, bias[c8 + 4]), 0.f) + nv1.x;
    o1.y = fmaxf(fmaf(a5, inv, bias[c8 + 5]), 0.f) + nv1.y;
    o1.z = fmaxf(fmaf(a6, inv, bias[c8 + 6]), 0.f) + nv1.z;
    o1.w = fmaxf(fmaf(a7, inv, bias[c8 + 7]), 0.f) + nv1.w;
    float* op = out + (((size_t)node) << 6) + c8;
    *reinterpret_cast<float4*>(op) = o0;
    *reinterpret_cast<float4*>(op + 4) = o1;
}

// ---------------------------------------------------------------------------
// phase mega-kernels
// ---------------------------------------------------------------------------
__global__ __launch_bounds__(256) void k_p1(const int* __restrict__ inc_hedge,
                                            const int* __restrict__ node2cell,
                                            const int* __restrict__ inc_node,
                                            int* __restrict__ he_off, int* __restrict__ cell_off,
                                            int* __restrict__ counts,
                                            const float* __restrict__ fhi_w, const float* __restrict__ fin_w,
                                            const float* __restrict__ th1, const float* __restrict__ th2,
                                            u16* __restrict__ Bt_fhi, u16* __restrict__ Bt_fin,
                                            u16* __restrict__ Bt_th1, u16* __restrict__ Bt_th2) {
    __shared__ int lds[256];
    int bid = blockIdx.x;
    if (bid < G_OFF_HE) { dev_offsets(bid, inc_hedge, N_INC, N_HE, he_off); return; }
    bid -= G_OFF_HE;
    if (bid < G_KA) { dev_ka(bid, inc_node, counts, lds); return; }
    bid -= G_KA;
    if (bid < G_OFF_CELL) { dev_offsets(bid, node2cell, N_NODES, N_CELLS, cell_off); return; }
    bid -= G_OFF_CELL;
    if (bid < G_CONV_BIG) { dev_convT(bid, fhi_w, Bt_fhi, D_IN); return; }
    bid -= G_CONV_BIG;
    if (bid < G_CONV_BIG) { dev_convT(bid, fin_w, Bt_fin, D_IN); return; }
    bid -= G_CONV_BIG;
    if (bid < G_CONV_SM) { dev_convT(bid, th1, Bt_th1, 64); return; }
    bid -= G_CONV_SM;
    dev_convT(bid, th2, Bt_th2, 64);
}

// P2: P-GEMM (direct) + Kb
__global__ __launch_bounds__(256) void k_p2(const int* __restrict__ counts,
                                            int* __restrict__ chunk_off, int* __restrict__ range_base,
                                            const float* __restrict__ vac_emb,
                                            const u16* __restrict__ Bt_fhi,
                                            const float* __restrict__ fhi_b, float* __restrict__ P) {
    __shared__ int lds[256];
    int bid = blockIdx.x;
    if (bid < G_PGEMM) {
        int wid = bid * 4 + ((int)threadIdx.x >> 6);
        dev_gemm_direct<0, 0, D_IN>(wid, vac_emb, nullptr, Bt_fhi, fhi_b, P, VOCAB);
        return;
    }
    dev_kb(counts, chunk_off, range_base, lds);
}

// P3: xt-GEMM L1 (A gathered from P via tok) + Kc + x0-GEMM
__global__ __launch_bounds__(256) void k_p3(const float* __restrict__ P,
                                            const int* __restrict__ tok,
                                            const u16* __restrict__ Bt_th1, u16* __restrict__ xt,
                                            const int* __restrict__ inc_node,
                                            const int* __restrict__ inc_hedge,
                                            const int* __restrict__ chunk_off,
                                            int2* __restrict__ bucket,
                                            const float* __restrict__ x, const u16* __restrict__ Bt_fin,
                                            const float* __restrict__ fin_b, float* __restrict__ x0) {
    __shared__ int lds[256];
    int bid = blockIdx.x;
    if (bid < G_XT) {
        int wid = bid * 4 + ((int)threadIdx.x >> 6);
        dev_gemm_direct<1, 1, 64>(wid, P, tok, Bt_th1, nullptr, xt, N_NODES);
        return;
    }
    bid -= G_XT;
    if (bid < G_KC) { dev_kc(bid, inc_node, inc_hedge, chunk_off, bucket, lds); return; }
    bid -= G_KC;
    {
        int wid = bid * 4 + ((int)threadIdx.x >> 6);
        dev_gemm_direct<0, 0, D_IN>(wid, x, nullptr, Bt_fin, fin_b, x0, I_ * J_);
    }
}

// P4: hedge_sum L1 + Kd
__global__ __launch_bounds__(256) void k_p4(const int* __restrict__ inc_node,
                                            const int* __restrict__ he_off,
                                            const u16* __restrict__ xt, u16* __restrict__ he,
                                            const int2* __restrict__ bucket,
                                            const int* __restrict__ range_base,
                                            int* __restrict__ node_off, int* __restrict__ csr) {
    __shared__ int lds[1792];
    int bid = blockIdx.x;
    if (bid < G_HEDGE) { dev_hedge_sum(bid, inc_node, he_off, xt, he); return; }
    bid -= G_HEDGE;
    dev_kd(bid, bucket, range_base, node_off, csr, lds);
}

// standalone wrappers
__global__ __launch_bounds__(256) void k_xt2(const float* __restrict__ A,
                                             const u16* __restrict__ Bt,
                                             u16* __restrict__ xt) {
    int wid = blockIdx.x * 4 + ((int)threadIdx.x >> 6);
    dev_gemm_direct<1, 0, 64>(wid, A, nullptr, Bt, nullptr, xt, N_NODES);
}

__global__ __launch_bounds__(256) void k_hedge_sum(const int* __restrict__ inc_node,
                                                   const int* __restrict__ he_off,
                                                   const u16* __restrict__ xt,
                                                   u16* __restrict__ he) {
    dev_hedge_sum(blockIdx.x, inc_node, he_off, xt, he);
}

__global__ __launch_bounds__(256) void k_node_sum(const int* __restrict__ csr,
                                                  const int* __restrict__ node_off,
                                                  const u16* __restrict__ he,
                                                  const float* __restrict__ bias,
                                                  const float* __restrict__ P,
                                                  const int* __restrict__ tok,
                                                  float* __restrict__ out) {
    dev_node_sum(blockIdx.x, csr, node_off, he, bias, P, tok, out);
}

// ---------------------------------------------------------------------------
__global__ __launch_bounds__(256) void k_pool(const float* __restrict__ gx,
                                              const int* __restrict__ cell_off,
                                              const float* __restrict__ x0,
                                              float* __restrict__ out1) {
    __shared__ float ssum[4][64];
    __shared__ float smax[4][64];
    int c = blockIdx.x;
    int lane = threadIdx.x & 63;
    int w = threadIdx.x >> 6;
    int s = cell_off[c], e = cell_off[c + 1];
    float sum = 0.f, mx = -INFINITY;
    for (int n = s + w; n < e; n += 4) {
        float v = gx[((size_t)n << 6) + lane];
        sum += v;
        mx = fmaxf(mx, v);
    }
    ssum[w][lane] = sum;
    smax[w][lane] = mx;
    __syncthreads();
    if (w == 0) {
        sum = ssum[0][lane] + ssum[1][lane] + ssum[2][lane] + ssum[3][lane];
        mx = fmaxf(fmaxf(smax[0][lane], smax[1][lane]), fmaxf(smax[2][lane], smax[3][lane]));
        int cnt = e - s;
        float mean = (cnt > 0) ? sum / (float)cnt : 0.f;
        float mp = (cnt > 0) ? mx : 0.f;
        float ce = 0.5f * (mean + mp);
        out1[((size_t)c << 6) + lane] = x0[((size_t)c << 6) + lane] + 0.3f * ce;
    }
}

// ---------------------------------------------------------------------------
__global__ __launch_bounds__(256) void k_tcn(
    const float* __restrict__ xu,
    const float* __restrict__ wc1, const float* __restrict__ bc1, const float* __restrict__ g1,
    const float* __restrict__ be1, const float* __restrict__ m1, const float* __restrict__ v1,
    const float* __restrict__ wc2, const float* __restrict__ bc2, const float* __restrict__ g2,
    const float* __restrict__ be2, const float* __restrict__ m2, const float* __restrict__ v2,
    const float* __restrict__ wc3, const float* __restrict__ bc3, const float* __restrict__ g3,
    const float* __restrict__ be3, const float* __restrict__ m3, const float* __restrict__ v3,
    const float* __restrict__ fct_w, const float* __restrict__ fct_b,
    float* __restrict__ out2) {
    __shared__ float w_lds[64 * 64 * 3];
    __shared__ float hA[64][10];
    __shared__ float hB[64][10];
    __shared__ float mo[64];

    int n = blockIdx.x, tid = threadIdx.x;

    if (tid < 64) {
        hA[tid][0] = 0.f; hA[tid][9] = 0.f;
        hB[tid][0] = 0.f; hB[tid][9] = 0.f;
    }
    #pragma unroll
    for (int l = tid; l < 512; l += 256) {
        int t = l >> 6, i = l & 63;
        hA[i][t + 1] = xu[(size_t)n * 512 + l];
    }

    const float* wcs[3] = {wc1, wc2, wc3};
    const float* bcs[3] = {bc1, bc2, bc3};
    const float* gs[3]  = {g1, g2, g3};
    const float* bes[3] = {be1, be2, be3};
    const float* ms[3]  = {m1, m2, m3};
    const float* vs[3]  = {v1, v2, v3};

    float (*hin)[10] = hA;
    float (*hout)[10] = hB;

    #pragma unroll
    for (int li = 0; li < 3; ++li) {
        for (int l = tid; l < 64 * 64 * 3; l += 256) w_lds[l] = wcs[li][l];
        __syncthreads();
        #pragma unroll
        for (int rep = 0; rep < 2; ++rep) {
            int idx = tid + rep * 256;
            int o = idx >> 3, t = idx & 7;
            float acc = bcs[li][o];
            #pragma unroll 8
            for (int i = 0; i < 64; ++i) {
                const float* wr = &w_lds[o * 192 + i * 3];
                acc = fmaf(hin[i][t + 0], wr[0], acc);
                acc = fmaf(hin[i][t + 1], wr[1], acc);
                acc = fmaf(hin[i][t + 2], wr[2], acc);
            }
            acc = fmaxf(acc, 0.f);
            float sc = gs[li][o] * rsqrtf(vs[li][o] + 1e-5f);
            acc = (acc - ms[li][o]) * sc + bes[li][o];
            hout[o][t + 1] = acc;
        }
        __syncthreads();
        float (*tmp)[10] = hin; hin = hout; hout = tmp;
    }

    if (tid < 64) {
        float s = 0.f;
        #pragma unroll
        for (int t = 0; t < 8; ++t) s += hin[tid][t + 1];
        mo[tid] = s * 0.125f;
    }
    __syncthreads();
    if (tid < 64) {
        float acc = fct_b[tid];
        #pragma unroll 8
        for (int o = 0; o < 64; ++o) acc = fmaf(mo[o], fct_w[o * 64 + tid], acc);
        out2[(size_t)n * 64 + tid] = acc;
    }
}

// ---------------------------------------------------------------------------
extern "C" void kernel_launch(void* const* d_in, const int* in_sizes, int n_in,
                              void* d_out, int out_size, void* d_ws, size_t ws_size,
                              hipStream_t stream) {
    (void)in_sizes; (void)n_in; (void)out_size; (void)ws_size;

    const float* x          = (const float*)d_in[0];
    const int*   node_tok   = (const int*)d_in[1];
    const int*   inc_node   = (const int*)d_in[2];
    const int*   inc_hedge  = (const int*)d_in[3];
    const int*   node2cell  = (const int*)d_in[4];
    const float* vac_emb    = (const float*)d_in[5];
    const float* fhi_w      = (const float*)d_in[6];
    const float* fhi_b      = (const float*)d_in[7];
    const float* fin_w      = (const float*)d_in[8];
    const float* fin_b      = (const float*)d_in[9];
    const float* th1        = (const float*)d_in[10];
    const float* b1         = (const float*)d_in[11];
    const float* th2        = (const float*)d_in[12];
    const float* b2         = (const float*)d_in[13];
    const float* fct_w      = (const float*)d_in[32];
    const float* fct_b      = (const float*)d_in[33];

    char* ws = (char*)d_ws;
    size_t off = 0;
    float* P        = (float*)(ws + off); off += (size_t)VOCAB * 64 * 4;
    float* hbuf     = (float*)(ws + off); off += (size_t)N_NODES * 64 * 4;
    u16*   xt       = (u16*)(ws + off);   off += (size_t)N_NODES * 64 * 2;
    u16*   he       = (u16*)(ws + off);   off += (size_t)N_HE * 64 * 2;
    int2*  bucket   = (int2*)(ws + off);  off += (size_t)N_INC * 8;
    float* x0       = (float*)(ws + off); off += (size_t)N_CELLS * 64 * 4;
    u16*   Bt_fhi   = (u16*)(ws + off);   off += (size_t)64 * D_IN * 2;
    u16*   Bt_fin   = (u16*)(ws + off);   off += (size_t)64 * D_IN * 2;
    u16*   Bt_th1   = (u16*)(ws + off);   off += (size_t)64 * 64 * 2;
    u16*   Bt_th2   = (u16*)(ws + off);   off += (size_t)64 * 64 * 2;
    int*   he_off   = (int*)(ws + off);   off += ((size_t)(N_HE + 1) * 4 + 255) / 256 * 256;
    int*   node_off = (int*)(ws + off);   off += ((size_t)(N_NODES + 1) * 4 + 255) / 256 * 256;
    int*   csr      = (int*)(ws + off);   off += (size_t)N_INC * 4;
    int*   cell_off = (int*)(ws + off);   off += ((size_t)(N_CELLS + 1) * 4 + 255) / 256 * 256;

    // counts/chunk_off/range_base alias hbuf (hbuf first written in node_sum L1,
    // after Kd has consumed them)
    int*  counts     = (int*)hbuf;
    int*  chunk_off  = counts + 256 * 256;
    int*  range_base = chunk_off + 256 * 256;

    float* out1 = (float*)d_out;
    float* out2 = out1 + (size_t)I_ * J_ * D_H;

    // P1: offsets(hedge) + Ka + offsets(cell) + 4x convT
    k_p1<<<G_OFF_HE + G_KA + G_OFF_CELL + 2 * G_CONV_BIG + 2 * G_CONV_SM, 256, 0, stream>>>(
        inc_hedge, node2cell, inc_node, he_off, cell_off, counts,
        fhi_w, fin_w, th1, th2, Bt_fhi, Bt_fin, Bt_th1, Bt_th2);

    // P2: P-GEMM (direct) + Kb
    k_p2<<<G_PGEMM + 1, 256, 0, stream>>>(counts, chunk_off, range_base,
                                          vac_emb, Bt_fhi, fhi_b, P);

    // P3: xt-GEMM L1 (gather-A) + Kc + x0-GEMM
    k_p3<<<G_XT + G_KC + G_X0, 256, 0, stream>>>(P, node_tok, Bt_th1, xt,
                                                 inc_node, inc_hedge, chunk_off, bucket,
                                                 x, Bt_fin, fin_b, x0);

    // P4: hedge_sum L1 + Kd
    k_p4<<<G_HEDGE + G_KD, 256, 0, stream>>>(inc_node, he_off, xt, he,
                                             bucket, range_base, node_off, csr);

    // P5: node_sum L1 -> hbuf = h1
    k_node_sum<<<G_NODE, 256, 0, stream>>>(csr, node_off, he, b1, P, node_tok, hbuf);

    // P6: xt-GEMM L2 (dense A = hbuf)
    k_xt2<<<G_XT, 256, 0, stream>>>(hbuf, Bt_th2, xt);

    // P7: hedge_sum L2
    k_hedge_sum<<<G_HEDGE, 256, 0, stream>>>(inc_node, he_off, xt, he);

    // P8: node_sum L2 -> hbuf = gx
    k_node_sum<<<G_NODE, 256, 0, stream>>>(csr, node_off, he, b2, P, node_tok, hbuf);

    // P9: pool + fuse -> out1
    k_pool<<<N_CELLS, 256, 0, stream>>>(hbuf, cell_off, x0, out1);

    // P10: TCN -> out2
    k_tcn<<<I_, 256, 0, stream>>>(out1,
        (const float*)d_in[14], (const float*)d_in[15], (const float*)d_in[16],
        (const float*)d_in[17], (const float*)d_in[18], (const float*)d_in[19],
        (const float*)d_in[20], (const float*)d_in[21], (const float*)d_in[22],
        (const float*)d_in[23], (const float*)d_in[24], (const float*)d_in[25],
        (const float*)d_in[26], (const float*)d_in[27], (const float*)d_in[28],
        (const float*)d_in[29], (const float*)d_in[30], (const float*)d_in[31],
        fct_w, fct_b, out2);
}